// Round 1
// baseline (12376.956 us; speedup 1.0000x reference)
//
#include <hip/hip_runtime.h>

#define NL   6
#define NH   16
#define HID  1024
#define HD   64
#define FFW  4096
#define VOC  32000
#define WINN 512
#define EMB  128
#define NB   4
#define TT   1024   // WIN + WIN

// ---------------------------------------------------------------------------
// Embed: h0[r,c] = sum_e (W_emb[x[r],e] * HIDDEN^-0.5) * W_lin[e,c]
// one block per row (2048 rows), 256 threads
// ---------------------------------------------------------------------------
__global__ __launch_bounds__(256) void embed_kernel(
    const int* __restrict__ xin, const float* __restrict__ Wemb,
    const float* __restrict__ Wlin, float* __restrict__ h0)
{
    int row = blockIdx.x;            // 0..2047  (b*512 + t)
    int tok = xin[row];
    __shared__ float tk[EMB];
    if (threadIdx.x < EMB) tk[threadIdx.x] = Wemb[tok * EMB + threadIdx.x] * 0.03125f;
    __syncthreads();
    for (int j = 0; j < 4; ++j) {
        int c = threadIdx.x + 256 * j;
        float acc = 0.f;
        for (int e = 0; e < EMB; ++e) acc += tk[e] * Wlin[e * HID + c];
        h0[(long)row * HID + c] = acc;
    }
}

// ---------------------------------------------------------------------------
// x[b,t,:] = pos[t,:] + (t<512 ? prev[b,t,:] : cur[b,t-512,:])
// ---------------------------------------------------------------------------
__global__ __launch_bounds__(256) void build_x_kernel(
    const float* __restrict__ pos, const float* __restrict__ prev,
    const float* __restrict__ cur, float* __restrict__ x)
{
    int i4 = blockIdx.x * blockDim.x + threadIdx.x;   // over NB*TT*HID/4
    if (i4 >= NB * TT * HID / 4) return;
    int h4 = i4 % (HID / 4);
    int bt = i4 / (HID / 4);
    int t = bt % TT, b = bt / TT;
    float4 p = ((const float4*)pos)[t * (HID / 4) + h4];
    float4 s;
    if (t < WINN) s = ((const float4*)prev)[(long)(b * WINN + t) * (HID / 4) + h4];
    else          s = ((const float4*)cur)[(long)(b * WINN + (t - WINN)) * (HID / 4) + h4];
    float4 r; r.x = p.x + s.x; r.y = p.y + s.y; r.z = p.z + s.z; r.w = p.w + s.w;
    ((float4*)x)[i4] = r;
}

// ---------------------------------------------------------------------------
// SGEMM: C[M,N] = act(scale*(A@W) + bias). A row-major [M,K] (amap=1 remaps
// row r -> (r>>9)*1024 + 512 + (r&511), i.e. top half of each 1024-block).
// 64x64 tile, 256 threads, 4x4 microtile, BK=16. M%64==N%64==K%16==0.
// ---------------------------------------------------------------------------
__global__ __launch_bounds__(256) void sgemm_kernel(
    const float* __restrict__ A, const float* __restrict__ W, float* __restrict__ C,
    int M, int N, int K, float scale, const float* __restrict__ bias, int relu, int amap)
{
    __shared__ float As[16][68];   // pad to 68 -> 16B-aligned float4 rows
    __shared__ float Ws[16][64];
    const int tid = threadIdx.x;
    const int tx = tid & 15;          // col group 0..15
    const int ty = tid >> 4;          // row group 0..15
    const long cb = (long)blockIdx.x * 64;
    const int  rb = blockIdx.y * 64;

    const int arow = tid >> 2;                // 0..63
    const int akc  = (tid & 3) << 2;          // 0,4,8,12
    int r = rb + arow;
    long ar = amap ? (long)((r >> 9) * 1024 + 512 + (r & 511)) : (long)r;
    const float* Ap = A + ar * K + akc;
    const int wr = tid >> 4;                  // 0..15
    const int wc = (tid & 15) << 2;           // 0..60
    const float* Wp = W + (long)wr * N + cb + wc;

    float acc[4][4] = {};
    for (int k0 = 0; k0 < K; k0 += 16) {
        float4 av = *(const float4*)(Ap + k0);
        float4 wv = *(const float4*)(Wp + (long)k0 * N);
        As[akc + 0][arow] = av.x;
        As[akc + 1][arow] = av.y;
        As[akc + 2][arow] = av.z;
        As[akc + 3][arow] = av.w;
        *(float4*)&Ws[wr][wc] = wv;
        __syncthreads();
#pragma unroll
        for (int kk = 0; kk < 16; ++kk) {
            float4 a = *(const float4*)&As[kk][ty << 2];
            float4 b = *(const float4*)&Ws[kk][tx << 2];
            acc[0][0] += a.x * b.x; acc[0][1] += a.x * b.y; acc[0][2] += a.x * b.z; acc[0][3] += a.x * b.w;
            acc[1][0] += a.y * b.x; acc[1][1] += a.y * b.y; acc[1][2] += a.y * b.z; acc[1][3] += a.y * b.w;
            acc[2][0] += a.z * b.x; acc[2][1] += a.z * b.y; acc[2][2] += a.z * b.z; acc[2][3] += a.z * b.w;
            acc[3][0] += a.w * b.x; acc[3][1] += a.w * b.y; acc[3][2] += a.w * b.z; acc[3][3] += a.w * b.w;
        }
        __syncthreads();
    }
#pragma unroll
    for (int i = 0; i < 4; ++i) {
        long row = rb + (ty << 2) + i;
        long col = cb + (tx << 2);
        float4 v;
        v.x = acc[i][0] * scale; v.y = acc[i][1] * scale;
        v.z = acc[i][2] * scale; v.w = acc[i][3] * scale;
        if (bias) {
            float4 b4 = *(const float4*)&bias[col];
            v.x += b4.x; v.y += b4.y; v.z += b4.z; v.w += b4.w;
        }
        if (relu) {
            v.x = fmaxf(v.x, 0.f); v.y = fmaxf(v.y, 0.f);
            v.z = fmaxf(v.z, 0.f); v.w = fmaxf(v.w, 0.f);
        }
        *(float4*)&C[row * N + col] = v;
    }
}

// ---------------------------------------------------------------------------
// Attention: block = (qt, h, b), 8 q-rows per block, full scores row in LDS.
// q is compact [B*WIN, HID] (already scaled by HEAD^-0.5); k,v are [B*TT, HID].
// o compact [B*WIN, HID]. Causal: q global index qi = 512 + qt*8 + qr.
// ---------------------------------------------------------------------------
#define QR 8
__global__ __launch_bounds__(256) void attn_kernel(
    const float* __restrict__ q, const float* __restrict__ kbuf,
    const float* __restrict__ vbuf, float* __restrict__ o)
{
    int qt = blockIdx.x, h = blockIdx.y, b = blockIdx.z;
    int tid = threadIdx.x;
    __shared__ float qs[QR][HD];
    __shared__ float sc[QR][TT];      // 32 KB
    __shared__ float kv[64][HD + 1];  // +1 pad: kills column-read bank conflict
    __shared__ float red[QR][33];

    int qbase = b * WINN + qt * QR;
    for (int i = tid; i < QR * HD; i += 256) {
        int qr = i >> 6, d = i & 63;
        qs[qr][d] = q[(long)(qbase + qr) * HID + h * HD + d];
    }
    __syncthreads();

    // scores
    for (int kt = 0; kt < TT / 64; ++kt) {
        for (int i = tid; i < 64 * HD; i += 256) {
            int kr = i >> 6, d = i & 63;
            kv[kr][d] = kbuf[(long)(b * TT + kt * 64 + kr) * HID + h * HD + d];
        }
        __syncthreads();
        for (int i = tid; i < QR * 64; i += 256) {
            int qr = i >> 6, kr = i & 63;
            int kg = kt * 64 + kr;
            int qi = WINN + qt * QR + qr;
            float s;
            if (kg <= qi) {
                float acc = 0.f;
                for (int d = 0; d < HD; ++d) acc += qs[qr][d] * kv[kr][d];
                s = acc;
            } else s = -1e9f;
            sc[qr][kg] = s;
        }
        __syncthreads();
    }

    // softmax: 32 threads per row
    int row = tid >> 5, j = tid & 31;
    float m = -1e30f;
    for (int c = j; c < TT; c += 32) m = fmaxf(m, sc[row][c]);
    red[row][j] = m;
    __syncthreads();
    if (j == 0) {
        float mm = red[row][0];
        for (int t2 = 1; t2 < 32; ++t2) mm = fmaxf(mm, red[row][t2]);
        red[row][32] = mm;
    }
    __syncthreads();
    float mm = red[row][32];
    float ssum = 0.f;
    for (int c = j; c < TT; c += 32) {
        float e = __expf(sc[row][c] - mm);
        sc[row][c] = e;
        ssum += e;
    }
    __syncthreads();
    red[row][j] = ssum;
    __syncthreads();
    if (j == 0) {
        float s = 0.f;
        for (int t2 = 0; t2 < 32; ++t2) s += red[row][t2];
        red[row][32] = s;
    }
    __syncthreads();
    float inv = 1.f / red[row][32];
    for (int c = j; c < TT; c += 32) sc[row][c] *= inv;
    __syncthreads();

    // PV: thread owns (qr0,d0) and (qr1,d1)
    float out0 = 0.f, out1 = 0.f;
    int qr0 = tid >> 6, d0 = tid & 63;          // qr 0..3
    int qr1 = (tid + 256) >> 6, d1 = tid & 63;  // qr 4..7
    for (int kt = 0; kt < TT / 64; ++kt) {
        for (int i = tid; i < 64 * HD; i += 256) {
            int kr = i >> 6, d = i & 63;
            kv[kr][d] = vbuf[(long)(b * TT + kt * 64 + kr) * HID + h * HD + d];
        }
        __syncthreads();
        for (int kr = 0; kr < 64; ++kr) {
            out0 += sc[qr0][kt * 64 + kr] * kv[kr][d0];
            out1 += sc[qr1][kt * 64 + kr] * kv[kr][d1];
        }
        __syncthreads();
    }
    o[(long)(qbase + qr0) * HID + h * HD + d0] = out0;
    o[(long)(qbase + qr1) * HID + h * HD + d1] = out1;
}

// ---------------------------------------------------------------------------
// out[r] = res[r'] + LN(t[r])*scale + bias ; one block per row, 256 threads.
// res_map=1: res row r' = (r>>9)*1024 + 512 + (r&511) (top half of x).
// ---------------------------------------------------------------------------
__global__ __launch_bounds__(256) void ln_res_kernel(
    const float* __restrict__ t, const float* __restrict__ res, float* __restrict__ out,
    const float* __restrict__ bias, const float* __restrict__ scale, int res_map)
{
    int r = blockIdx.x;
    int tid = threadIdx.x;
    long rr = res_map ? (long)((r >> 9) * 1024 + 512 + (r & 511)) : (long)r;
    float4 v = ((const float4*)(t + (long)r * HID))[tid];
    __shared__ float red[4];
    float s = v.x + v.y + v.z + v.w;
    for (int off = 32; off > 0; off >>= 1) s += __shfl_xor(s, off);
    if ((tid & 63) == 0) red[tid >> 6] = s;
    __syncthreads();
    float mean = (red[0] + red[1] + red[2] + red[3]) * (1.f / HID);
    __syncthreads();
    float dx = v.x - mean, dy = v.y - mean, dz = v.z - mean, dw = v.w - mean;
    float qs = dx * dx + dy * dy + dz * dz + dw * dw;
    for (int off = 32; off > 0; off >>= 1) qs += __shfl_xor(qs, off);
    if ((tid & 63) == 0) red[tid >> 6] = qs;
    __syncthreads();
    float var = (red[0] + red[1] + red[2] + red[3]) * (1.f / HID);
    float rs = rsqrtf(var + 1e-6f);
    float4 rv = ((const float4*)(res + rr * HID))[tid];
    float4 sc4 = ((const float4*)scale)[tid];
    float4 b4  = ((const float4*)bias)[tid];
    float4 o4;
    o4.x = rv.x + dx * rs * sc4.x + b4.x;
    o4.y = rv.y + dy * rs * sc4.y + b4.y;
    o4.z = rv.z + dz * rs * sc4.z + b4.z;
    o4.w = rv.w + dw * rs * sc4.w + b4.w;
    ((float4*)(out + (long)r * HID))[tid] = o4;
}

// ---------------------------------------------------------------------------
extern "C" void kernel_launch(void* const* d_in, const int* in_sizes, int n_in,
                              void* d_out, int out_size, void* d_ws, size_t ws_size,
                              hipStream_t stream)
{
    const int*   x_input = (const int*)  d_in[0];
    const float* prev    = (const float*)d_in[1];
    const float* Wemb    = (const float*)d_in[2];
    const float* Wlin    = (const float*)d_in[3];
    const float* pdec    = (const float*)d_in[4];
    const float* pq      = (const float*)d_in[5];
    const float* pk      = (const float*)d_in[6];
    const float* pv      = (const float*)d_in[7];
    const float* pc      = (const float*)d_in[8];
    const float* pf1     = (const float*)d_in[9];
    const float* pf2     = (const float*)d_in[10];
    const float* bf1     = (const float*)d_in[11];
    const float* bf2     = (const float*)d_in[12];
    const float* b1      = (const float*)d_in[13];
    const float* b2      = (const float*)d_in[14];
    const float* s1      = (const float*)d_in[15];
    const float* s2      = (const float*)d_in[16];
    const float* pos     = (const float*)d_in[17];

    float* outp   = (float*)d_out;
    float* logits = outp;                             // [2048, 32000]
    float* dec    = outp + (long)2048 * VOC;          // [6][2048, 1024]

    float* ws  = (float*)d_ws;
    float* x   = ws;                    // 4,194,304  [B*TT, HID]
    float* kb  = x   + 4194304;         // 4,194,304
    float* vb  = kb  + 4194304;         // 4,194,304
    float* qb  = vb  + 4194304;         // 2,097,152  [B*WIN, HID]
    float* ob  = qb  + 2097152;         // 2,097,152
    float* t0  = ob  + 2097152;         // 2,097,152
    float* xs  = t0  + 2097152;         // 2,097,152
    float* ff1 = xs  + 2097152;         // 8,388,608  [B*WIN, FFW]
    float* h0  = ff1 + 8388608;         // 2,097,152

    embed_kernel<<<NB * WINN, 256, 0, stream>>>(x_input, Wemb, Wlin, h0);

    for (int l = 0; l < NL; ++l) {
        const float* cur = (l == 0) ? h0 : (dec + (long)(l - 1) * 2097152);
        build_x_kernel<<<(NB * TT * HID / 4) / 256, 256, 0, stream>>>(
            pos + (long)l * TT * HID, prev + (long)l * NB * WINN * HID, cur, x);

        dim3 gKV(HID / 64, (NB * TT) / 64);
        sgemm_kernel<<<gKV, 256, 0, stream>>>(x, pk + (long)l * HID * HID, kb,
                                              NB * TT, HID, HID, 1.f, nullptr, 0, 0);
        sgemm_kernel<<<gKV, 256, 0, stream>>>(x, pv + (long)l * HID * HID, vb,
                                              NB * TT, HID, HID, 1.f, nullptr, 0, 0);
        dim3 gQ(HID / 64, (NB * WINN) / 64);
        sgemm_kernel<<<gQ, 256, 0, stream>>>(x, pq + (long)l * HID * HID, qb,
                                             NB * WINN, HID, HID, 0.125f, nullptr, 0, 1);

        dim3 gA(WINN / QR, NH, NB);
        attn_kernel<<<gA, 256, 0, stream>>>(qb, kb, vb, ob);

        sgemm_kernel<<<gQ, 256, 0, stream>>>(ob, pc + (long)l * HID * HID, t0,
                                             NB * WINN, HID, HID, 1.f, nullptr, 0, 0);
        ln_res_kernel<<<NB * WINN, 256, 0, stream>>>(t0, x, xs, b1 + l * HID, s1 + l * HID, 1);

        dim3 gF1(FFW / 64, (NB * WINN) / 64);
        sgemm_kernel<<<gF1, 256, 0, stream>>>(xs, pf1 + (long)l * HID * FFW, ff1,
                                              NB * WINN, FFW, HID, 1.f, bf1 + l * FFW, 1, 0);
        dim3 gF2(HID / 64, (NB * WINN) / 64);
        sgemm_kernel<<<gF2, 256, 0, stream>>>(ff1, pf2 + (long)l * FFW * HID, t0,
                                              NB * WINN, HID, FFW, 1.f, bf2 + l * HID, 0, 0);
        ln_res_kernel<<<NB * WINN, 256, 0, stream>>>(t0, xs, dec + (long)l * 2097152,
                                                     b2 + l * HID, s2 + l * HID, 0);
    }

    dim3 gL(VOC / 64, (NB * WINN) / 64);
    sgemm_kernel<<<gL, 256, 0, stream>>>(dec + (long)5 * 2097152, pdec, logits,
                                         NB * WINN, VOC, HID, 1.f, nullptr, 0, 0);
}

// Round 5
// 9959.402 us; speedup vs baseline: 1.2427x; 1.2427x over previous
//
#include <hip/hip_runtime.h>
#include <hip/hip_bf16.h>

#define NL   6
#define NH   16
#define HID  1024
#define HD   64
#define FFW  4096
#define VOC  32000
#define WINN 512
#define EMB  128
#define NB   4
#define TT   1024   // WIN + WIN

typedef __attribute__((ext_vector_type(8))) short b16x8;
typedef __attribute__((ext_vector_type(4))) float f32x4;

__device__ __forceinline__ ushort f2b(float f) {
    __hip_bfloat16 h = __float2bfloat16(f);
    return *reinterpret_cast<ushort*>(&h);
}

// ---------------------------------------------------------------------------
// Embed (f32)
// ---------------------------------------------------------------------------
__global__ __launch_bounds__(256) void embed_kernel(
    const int* __restrict__ xin, const float* __restrict__ Wemb,
    const float* __restrict__ Wlin, float* __restrict__ h0)
{
    int row = blockIdx.x;
    int tok = xin[row];
    __shared__ float tk[EMB];
    if (threadIdx.x < EMB) tk[threadIdx.x] = Wemb[tok * EMB + threadIdx.x] * 0.03125f;
    __syncthreads();
    for (int j = 0; j < 4; ++j) {
        int c = threadIdx.x + 256 * j;
        float acc = 0.f;
        for (int e = 0; e < EMB; ++e) acc += tk[e] * Wlin[e * HID + c];
        h0[(long)row * HID + c] = acc;
    }
}

// ---------------------------------------------------------------------------
// x[b,t,:] = pos[t,:] + (t<512 ? prev[b,t,:] : cur[b,t-512,:])  (f32 only)
// ---------------------------------------------------------------------------
__global__ __launch_bounds__(256) void build_x_kernel(
    const float* __restrict__ pos, const float* __restrict__ prev,
    const float* __restrict__ cur, float* __restrict__ x)
{
    int i4 = blockIdx.x * blockDim.x + threadIdx.x;
    if (i4 >= NB * TT * HID / 4) return;
    int h4 = i4 % (HID / 4);
    int bt = i4 / (HID / 4);
    int t = bt % TT, b = bt / TT;
    float4 p = ((const float4*)pos)[t * (HID / 4) + h4];
    float4 s;
    if (t < WINN) s = ((const float4*)prev)[(long)(b * WINN + t) * (HID / 4) + h4];
    else          s = ((const float4*)cur)[(long)(b * WINN + (t - WINN)) * (HID / 4) + h4];
    float4 r; r.x = p.x + s.x; r.y = p.y + s.y; r.z = p.z + s.z; r.w = p.w + s.w;
    ((float4*)x)[i4] = r;
}

// ---------------------------------------------------------------------------
// f32 SGEMM v2: 128x128 tile, 256 threads, 8x8 microtile, BK=16, double-buf.
// C = act(scale*(A@W) + bias). amap: row r -> (r>>9)*1024 + 512 + (r&511).
// ---------------------------------------------------------------------------
__global__ __launch_bounds__(256) void sgemm128(
    const float* __restrict__ A, const float* __restrict__ W, float* __restrict__ C,
    int M, int N, int K, float scale, const float* __restrict__ bias, int relu, int amap)
{
    __shared__ float As[2][16][132];   // [k][row], A transposed
    __shared__ float Bs[2][16][132];   // [k][col]
    const int tid = threadIdx.x;
    const int tx = tid & 15, ty = tid >> 4;
    const int rb = blockIdx.y * 128;
    const long cb = (long)blockIdx.x * 128;

    // A staging: thread covers rows {lr, lr+64}, k-span ak..ak+3
    const int lr = tid >> 2;
    const int ak = (tid & 3) << 2;
    int gr0 = rb + lr, gr1 = gr0 + 64;
    long m0 = amap ? (long)((gr0 >> 9) * 1024 + 512 + (gr0 & 511)) : (long)gr0;
    long m1 = amap ? (long)((gr1 >> 9) * 1024 + 512 + (gr1 & 511)) : (long)gr1;
    const float* Ap0 = A + m0 * K + ak;
    const float* Ap1 = A + m1 * K + ak;
    // B staging: thread covers k-rows {br, br+8}, cols bc..bc+3
    const int br = tid >> 5;
    const int bc = (tid & 31) << 2;
    const float* Wp = W + (long)br * N + cb + bc;

    float4 a0 = *(const float4*)(Ap0);
    float4 a1 = *(const float4*)(Ap1);
    float4 b0 = *(const float4*)(Wp);
    float4 b1 = *(const float4*)(Wp + (long)8 * N);

    As[0][ak + 0][lr] = a0.x; As[0][ak + 1][lr] = a0.y;
    As[0][ak + 2][lr] = a0.z; As[0][ak + 3][lr] = a0.w;
    As[0][ak + 0][64 + lr] = a1.x; As[0][ak + 1][64 + lr] = a1.y;
    As[0][ak + 2][64 + lr] = a1.z; As[0][ak + 3][64 + lr] = a1.w;
    *(float4*)&Bs[0][br][bc] = b0;
    *(float4*)&Bs[0][br + 8][bc] = b1;
    __syncthreads();

    float ac[8][8] = {};
    const int nk = K >> 4;
    for (int t = 0; t < nk; ++t) {
        const int cur = t & 1;
        const bool more = (t + 1 < nk);
        if (more) {
            int k0 = (t + 1) << 4;
            a0 = *(const float4*)(Ap0 + k0);
            a1 = *(const float4*)(Ap1 + k0);
            b0 = *(const float4*)(Wp + (long)k0 * N);
            b1 = *(const float4*)(Wp + (long)(k0 + 8) * N);
        }
#pragma unroll
        for (int kk = 0; kk < 16; ++kk) {
            float4 x0 = *(const float4*)&As[cur][kk][ty << 2];
            float4 x1 = *(const float4*)&As[cur][kk][64 + (ty << 2)];
            float4 y0 = *(const float4*)&Bs[cur][kk][tx << 2];
            float4 y1 = *(const float4*)&Bs[cur][kk][64 + (tx << 2)];
            float xa[8] = {x0.x, x0.y, x0.z, x0.w, x1.x, x1.y, x1.z, x1.w};
            float yb[8] = {y0.x, y0.y, y0.z, y0.w, y1.x, y1.y, y1.z, y1.w};
#pragma unroll
            for (int i = 0; i < 8; ++i)
#pragma unroll
                for (int j = 0; j < 8; ++j)
                    ac[i][j] += xa[i] * yb[j];
        }
        if (more) {
            const int nxt = cur ^ 1;
            As[nxt][ak + 0][lr] = a0.x; As[nxt][ak + 1][lr] = a0.y;
            As[nxt][ak + 2][lr] = a0.z; As[nxt][ak + 3][lr] = a0.w;
            As[nxt][ak + 0][64 + lr] = a1.x; As[nxt][ak + 1][64 + lr] = a1.y;
            As[nxt][ak + 2][64 + lr] = a1.z; As[nxt][ak + 3][64 + lr] = a1.w;
            *(float4*)&Bs[nxt][br][bc] = b0;
            *(float4*)&Bs[nxt][br + 8][bc] = b1;
            __syncthreads();
        }
    }

#pragma unroll
    for (int i = 0; i < 8; ++i) {
        long row = rb + ((i >> 2) * 64) + (ty << 2) + (i & 3);
#pragma unroll
        for (int jq = 0; jq < 2; ++jq) {
            long col = cb + jq * 64 + (tx << 2);
            float4 v;
            v.x = ac[i][jq * 4 + 0] * scale; v.y = ac[i][jq * 4 + 1] * scale;
            v.z = ac[i][jq * 4 + 2] * scale; v.w = ac[i][jq * 4 + 3] * scale;
            if (bias) {
                float4 b4 = *(const float4*)&bias[col];
                v.x += b4.x; v.y += b4.y; v.z += b4.z; v.w += b4.w;
            }
            if (relu) {
                v.x = fmaxf(v.x, 0.f); v.y = fmaxf(v.y, 0.f);
                v.z = fmaxf(v.z, 0.f); v.w = fmaxf(v.w, 0.f);
            }
            *(float4*)&C[row * N + col] = v;
        }
    }
}

// ---------------------------------------------------------------------------
// Flash attention, f32, online softmax. Block = (qt, h, b): 64 q-rows.
// 256 threads = 16x16, thread computes 4x4 of S and 4x4 of O.
// K-tile LDS is XOR-swizzled (col4 ^= row>>2) to kill stride conflicts.
// Causal: q global = 512 + qt*64 + r; tiles 0..8+qt, last one masked.
// ---------------------------------------------------------------------------
__global__ __launch_bounds__(256) void fattn_kernel(
    const float* __restrict__ q, const float* __restrict__ k,
    const float* __restrict__ v, float* __restrict__ o)
{
    __shared__ float qs[64][68];
    __shared__ float ks[64][68];
    __shared__ float vs[64][68];
    __shared__ float ps[64][68];
    const int qt = blockIdx.x, h = blockIdx.y, b = blockIdx.z;
    const int tid = threadIdx.x, tx = tid & 15, ty = tid >> 4;
    const int qbase = b * WINN + qt * 64;

#pragma unroll
    for (int j = 0; j < 4; ++j) {
        int p = tid + 256 * j;
        int row = p >> 4, c4 = (p & 15) << 2;
        *(float4*)&qs[row][c4] =
            *(const float4*)&q[(long)(qbase + row) * HID + h * HD + c4];
    }

    float O[4][4] = {};
    float mrow[4], lrow[4];
#pragma unroll
    for (int i = 0; i < 4; ++i) { mrow[i] = -3.0e38f; lrow[i] = 0.f; }

    const int ktmax = 9 + qt;
    for (int kt = 0; kt < ktmax; ++kt) {
        __syncthreads();   // protects qs on first iter; ks/vs/ps on later iters
#pragma unroll
        for (int j = 0; j < 4; ++j) {
            int p = tid + 256 * j;
            int row = p >> 4, c4 = p & 15;
            long g = (long)(b * TT + kt * 64 + row) * HID + h * HD + (c4 << 2);
            *(float4*)&ks[row][((c4 ^ (row >> 2)) & 15) << 2] = *(const float4*)&k[g];
            *(float4*)&vs[row][c4 << 2] = *(const float4*)&v[g];
        }
        __syncthreads();

        // S = q @ k^T  (rows ty*4+i, k-cols tx*4+j)
        float S[4][4] = {};
#pragma unroll
        for (int d4 = 0; d4 < 16; ++d4) {
            float4 qa[4], ka[4];
#pragma unroll
            for (int i = 0; i < 4; ++i)
                qa[i] = *(const float4*)&qs[(ty << 2) + i][d4 << 2];
#pragma unroll
            for (int j = 0; j < 4; ++j)
                ka[j] = *(const float4*)&ks[(tx << 2) + j][((d4 ^ tx) & 15) << 2];
#pragma unroll
            for (int i = 0; i < 4; ++i)
#pragma unroll
                for (int j = 0; j < 4; ++j)
                    S[i][j] += qa[i].x * ka[j].x + qa[i].y * ka[j].y
                             + qa[i].z * ka[j].z + qa[i].w * ka[j].w;
        }

        if (kt == ktmax - 1) {   // diagonal tile: causal mask
#pragma unroll
            for (int i = 0; i < 4; ++i) {
                int qi = WINN + qt * 64 + (ty << 2) + i;
#pragma unroll
                for (int j = 0; j < 4; ++j) {
                    int kg = kt * 64 + (tx << 2) + j;
                    if (kg > qi) S[i][j] = -1e9f;
                }
            }
        }

        // online softmax update (per q-row, reduced across the 16 tx lanes)
#pragma unroll
        for (int i = 0; i < 4; ++i) {
            float mx = fmaxf(fmaxf(S[i][0], S[i][1]), fmaxf(S[i][2], S[i][3]));
            mx = fmaxf(mx, __shfl_xor(mx, 1));
            mx = fmaxf(mx, __shfl_xor(mx, 2));
            mx = fmaxf(mx, __shfl_xor(mx, 4));
            mx = fmaxf(mx, __shfl_xor(mx, 8));
            float mnew = fmaxf(mrow[i], mx);
            float alpha = __expf(mrow[i] - mnew);
            float rs = 0.f;
#pragma unroll
            for (int j = 0; j < 4; ++j) { S[i][j] = __expf(S[i][j] - mnew); rs += S[i][j]; }
            rs += __shfl_xor(rs, 1);
            rs += __shfl_xor(rs, 2);
            rs += __shfl_xor(rs, 4);
            rs += __shfl_xor(rs, 8);
            lrow[i] = lrow[i] * alpha + rs;
            mrow[i] = mnew;
#pragma unroll
            for (int j = 0; j < 4; ++j) O[i][j] *= alpha;
        }

        // P -> LDS, then O += P @ V
#pragma unroll
        for (int i = 0; i < 4; ++i) {
            float4 pv; pv.x = S[i][0]; pv.y = S[i][1]; pv.z = S[i][2]; pv.w = S[i][3];
            *(float4*)&ps[(ty << 2) + i][tx << 2] = pv;
        }
        __syncthreads();
#pragma unroll
        for (int k4 = 0; k4 < 16; ++k4) {
            float4 pa[4], va[4];
#pragma unroll
            for (int i = 0; i < 4; ++i)
                pa[i] = *(const float4*)&ps[(ty << 2) + i][k4 << 2];
#pragma unroll
            for (int j = 0; j < 4; ++j)
                va[j] = *(const float4*)&vs[(k4 << 2) + j][tx << 2];
#pragma unroll
            for (int i = 0; i < 4; ++i) {
                O[i][0] += pa[i].x * va[0].x + pa[i].y * va[1].x + pa[i].z * va[2].x + pa[i].w * va[3].x;
                O[i][1] += pa[i].x * va[0].y + pa[i].y * va[1].y + pa[i].z * va[2].y + pa[i].w * va[3].y;
                O[i][2] += pa[i].x * va[0].z + pa[i].y * va[1].z + pa[i].z * va[2].z + pa[i].w * va[3].z;
                O[i][3] += pa[i].x * va[0].w + pa[i].y * va[1].w + pa[i].z * va[2].w + pa[i].w * va[3].w;
            }
        }
    }

#pragma unroll
    for (int i = 0; i < 4; ++i) {
        float inv = 1.f / lrow[i];
        float4 vv;
        vv.x = O[i][0] * inv; vv.y = O[i][1] * inv;
        vv.z = O[i][2] * inv; vv.w = O[i][3] * inv;
        *(float4*)&o[(long)(qbase + (ty << 2) + i) * HID + h * HD + (tx << 2)] = vv;
    }
}

// ---------------------------------------------------------------------------
// Transpose+convert: Wt[n][k] = bf16(W[k][n]).
// ---------------------------------------------------------------------------
__global__ __launch_bounds__(256) void transp_kernel(
    const float* __restrict__ W, ushort* __restrict__ Wt, int K, int N)
{
    __shared__ float ts[32][33];
    int n0 = blockIdx.x * 32, k0 = blockIdx.y * 32;
    int tr = threadIdx.x >> 5, tc = threadIdx.x & 31;
#pragma unroll
    for (int j = 0; j < 4; ++j)
        ts[tr + j * 8][tc] = W[(long)(k0 + tr + j * 8) * N + n0 + tc];
    __syncthreads();
#pragma unroll
    for (int j = 0; j < 4; ++j) {
        int n = tr + j * 8;
        Wt[(long)(n0 + n) * K + k0 + tc] = f2b(ts[tc][n]);
    }
}

// ---------------------------------------------------------------------------
// bf16 MFMA GEMM (logits only). Padded-linear LDS [128][40] ushort.
// ---------------------------------------------------------------------------
__global__ __launch_bounds__(256) void mfma_gemm(
    const ushort* __restrict__ A, const ushort* __restrict__ Bt,
    float* __restrict__ Cf, int M, int N, int K)
{
    __shared__ ushort As[128 * 40];
    __shared__ ushort Bs[128 * 40];
    const int tid  = threadIdx.x;
    const int rb   = blockIdx.y * 128;
    const int cb   = blockIdx.x * 128;
    const int wave = tid >> 6, lane = tid & 63;
    const int wr   = (wave >> 1) * 64;
    const int wc   = (wave & 1) * 64;
    const int lr   = lane & 15;
    const int kh   = lane >> 4;

    const int srow = tid >> 1;
    const int kc0  = (tid & 1) * 2;
    const ushort* aptr = A + (long)(rb + srow) * K + kc0 * 8;
    const ushort* bptr = Bt + (long)(cb + srow) * K + kc0 * 8;
    const int woff0 = srow * 40 + kc0 * 8;
    const int woff1 = srow * 40 + (kc0 + 1) * 8;

    int aoff[4], boff[4];
#pragma unroll
    for (int m = 0; m < 4; ++m) aoff[m] = (wr + m * 16 + lr) * 40 + kh * 8;
#pragma unroll
    for (int n = 0; n < 4; ++n) boff[n] = (wc + n * 16 + lr) * 40 + kh * 8;

    f32x4 acc[4][4];
#pragma unroll
    for (int m = 0; m < 4; ++m)
#pragma unroll
        for (int n = 0; n < 4; ++n)
            acc[m][n] = (f32x4){0.f, 0.f, 0.f, 0.f};

    for (int k0 = 0; k0 < K; k0 += 32) {
        uint4 a0 = *(const uint4*)(aptr + k0);
        uint4 a1 = *(const uint4*)(aptr + k0 + 8);
        uint4 b0 = *(const uint4*)(bptr + k0);
        uint4 b1 = *(const uint4*)(bptr + k0 + 8);
        __syncthreads();
        *(uint4*)(As + woff0) = a0;
        *(uint4*)(As + woff1) = a1;
        *(uint4*)(Bs + woff0) = b0;
        *(uint4*)(Bs + woff1) = b1;
        __syncthreads();
        b16x8 af[4], bfr[4];
#pragma unroll
        for (int m = 0; m < 4; ++m) af[m] = *(const b16x8*)(As + aoff[m]);
#pragma unroll
        for (int n = 0; n < 4; ++n) bfr[n] = *(const b16x8*)(Bs + boff[n]);
#pragma unroll
        for (int m = 0; m < 4; ++m)
#pragma unroll
            for (int n = 0; n < 4; ++n)
                acc[m][n] = __builtin_amdgcn_mfma_f32_16x16x32_bf16(af[m], bfr[n], acc[m][n], 0, 0, 0);
    }

#pragma unroll
    for (int m = 0; m < 4; ++m) {
        int row0 = rb + wr + m * 16 + kh * 4;
#pragma unroll
        for (int n = 0; n < 4; ++n) {
            int col = cb + wc + n * 16 + lr;
#pragma unroll
            for (int r = 0; r < 4; ++r)
                Cf[(long)(row0 + r) * N + col] = acc[m][n][r];
        }
    }
}

// ---------------------------------------------------------------------------
// out[r] = res[r'] + LN(t[r])*scale + bias ; f32 out + optional bf16 mirror.
// ---------------------------------------------------------------------------
__global__ __launch_bounds__(256) void ln_res_kernel(
    const float* __restrict__ t, const float* __restrict__ res, float* __restrict__ out,
    ushort* __restrict__ outb,
    const float* __restrict__ bias, const float* __restrict__ scale, int res_map)
{
    int r = blockIdx.x;
    int tid = threadIdx.x;
    long rr = res_map ? (long)((r >> 9) * 1024 + 512 + (r & 511)) : (long)r;
    float4 v = ((const float4*)(t + (long)r * HID))[tid];
    __shared__ float red[4];
    float s = v.x + v.y + v.z + v.w;
    for (int off = 32; off > 0; off >>= 1) s += __shfl_xor(s, off);
    if ((tid & 63) == 0) red[tid >> 6] = s;
    __syncthreads();
    float mean = (red[0] + red[1] + red[2] + red[3]) * (1.f / HID);
    __syncthreads();
    float dx = v.x - mean, dy = v.y - mean, dz = v.z - mean, dw = v.w - mean;
    float qs = dx * dx + dy * dy + dz * dz + dw * dw;
    for (int off = 32; off > 0; off >>= 1) qs += __shfl_xor(qs, off);
    if ((tid & 63) == 0) red[tid >> 6] = qs;
    __syncthreads();
    float var = (red[0] + red[1] + red[2] + red[3]) * (1.f / HID);
    float rs = rsqrtf(var + 1e-6f);
    float4 rv = ((const float4*)(res + rr * HID))[tid];
    float4 sc4 = ((const float4*)scale)[tid];
    float4 b4  = ((const float4*)bias)[tid];
    float4 o4;
    o4.x = rv.x + dx * rs * sc4.x + b4.x;
    o4.y = rv.y + dy * rs * sc4.y + b4.y;
    o4.z = rv.z + dz * rs * sc4.z + b4.z;
    o4.w = rv.w + dw * rs * sc4.w + b4.w;
    ((float4*)(out + (long)r * HID))[tid] = o4;
    if (outb) {
        ushort4 u; u.x = f2b(o4.x); u.y = f2b(o4.y); u.z = f2b(o4.z); u.w = f2b(o4.w);
        ((ushort4*)(outb + (long)r * HID))[tid] = u;
    }
}

// ---------------------------------------------------------------------------
// Workspace (121,634,816 B total, < R1-proven 125,829,120):
//  [0,16M)    x_f          (f32 [4096,1024])
//  [16,32M)   kb_f
//  [32,48M)   vb_f
//  [48,56M)   qb_f         (f32 [2048,1024])
//  [56,64M)   ob_f
//  [64,72M)   t0 (=h0)
//  [72,80M)   xs
//  [80,84M)   decb         (bf16 [2048,1024], written at l==5)
//  [84,116M)  ff1          (f32 [2048,4096])
//  wdect overlay [0, 62.5MB): written AFTER the loop (transients dead).
// ---------------------------------------------------------------------------
extern "C" void kernel_launch(void* const* d_in, const int* in_sizes, int n_in,
                              void* d_out, int out_size, void* d_ws, size_t ws_size,
                              hipStream_t stream)
{
    const int*   x_input = (const int*)  d_in[0];
    const float* prev    = (const float*)d_in[1];
    const float* Wemb    = (const float*)d_in[2];
    const float* Wlin    = (const float*)d_in[3];
    const float* pdec    = (const float*)d_in[4];
    const float* pq      = (const float*)d_in[5];
    const float* pk      = (const float*)d_in[6];
    const float* pv      = (const float*)d_in[7];
    const float* pc      = (const float*)d_in[8];
    const float* pf1     = (const float*)d_in[9];
    const float* pf2     = (const float*)d_in[10];
    const float* bf1     = (const float*)d_in[11];
    const float* bf2     = (const float*)d_in[12];
    const float* b1      = (const float*)d_in[13];
    const float* b2      = (const float*)d_in[14];
    const float* s1      = (const float*)d_in[15];
    const float* s2      = (const float*)d_in[16];
    const float* pos     = (const float*)d_in[17];

    float* outp   = (float*)d_out;
    float* logits = outp;
    float* dec    = outp + (long)2048 * VOC;

    char* base = (char*)d_ws;
    float*  x_f  = (float*) (base + 0);
    float*  kb_f = (float*) (base + 16777216);
    float*  vb_f = (float*) (base + 33554432);
    float*  qb_f = (float*) (base + 50331648);
    float*  ob_f = (float*) (base + 58720256);
    float*  t0   = (float*) (base + 67108864);
    float*  h0   = t0;
    float*  xs   = (float*) (base + 75497472);
    ushort* decb = (ushort*)(base + 83886080);
    float*  ff1  = (float*) (base + 88080384);   // ends 121,634,816
    ushort* wdect= (ushort*)(base + 0);          // post-loop overlay

    embed_kernel<<<NB * WINN, 256, 0, stream>>>(x_input, Wemb, Wlin, h0);

    for (int l = 0; l < NL; ++l) {
        const float* cur = (l == 0) ? h0 : (dec + (long)(l - 1) * 2097152);
        build_x_kernel<<<(NB * TT * HID / 4) / 256, 256, 0, stream>>>(
            pos + (long)l * TT * HID, prev + (long)l * NB * WINN * HID, cur, x_f);

        sgemm128<<<dim3(HID / 128, (NB * TT) / 128), 256, 0, stream>>>(
            x_f, pk + (long)l * HID * HID, kb_f, NB * TT, HID, HID, 1.f, nullptr, 0, 0);
        sgemm128<<<dim3(HID / 128, (NB * TT) / 128), 256, 0, stream>>>(
            x_f, pv + (long)l * HID * HID, vb_f, NB * TT, HID, HID, 1.f, nullptr, 0, 0);
        sgemm128<<<dim3(HID / 128, (NB * WINN) / 128), 256, 0, stream>>>(
            x_f, pq + (long)l * HID * HID, qb_f, NB * WINN, HID, HID, 0.125f, nullptr, 0, 1);

        fattn_kernel<<<dim3(WINN / 64, NH, NB), 256, 0, stream>>>(qb_f, kb_f, vb_f, ob_f);

        sgemm128<<<dim3(HID / 128, (NB * WINN) / 128), 256, 0, stream>>>(
            ob_f, pc + (long)l * HID * HID, t0, NB * WINN, HID, HID, 1.f, nullptr, 0, 0);
        ln_res_kernel<<<NB * WINN, 256, 0, stream>>>(
            t0, x_f, xs, nullptr, b1 + l * HID, s1 + l * HID, 1);

        sgemm128<<<dim3(FFW / 128, (NB * WINN) / 128), 256, 0, stream>>>(
            xs, pf1 + (long)l * HID * FFW, ff1, NB * WINN, FFW, HID, 1.f, bf1 + l * FFW, 1, 0);
        sgemm128<<<dim3(HID / 128, (NB * WINN) / 128), 256, 0, stream>>>(
            ff1, pf2 + (long)l * FFW * HID, t0, NB * WINN, HID, FFW, 1.f, bf2 + l * HID, 0, 0);
        ln_res_kernel<<<NB * WINN, 256, 0, stream>>>(
            t0, xs, dec + (long)l * 2097152, (l == NL - 1) ? decb : nullptr,
            b2 + l * HID, s2 + l * HID, 0);
    }

    transp_kernel<<<dim3(VOC / 32, HID / 32), 256, 0, stream>>>(pdec, wdect, HID, VOC);
    mfma_gemm<<<dim3(VOC / 128, (NB * WINN) / 128), 256, 0, stream>>>(
        decb, wdect, logits, NB * WINN, VOC, HID);
}

// Round 6
// 8356.554 us; speedup vs baseline: 1.4811x; 1.1918x over previous
//
#include <hip/hip_runtime.h>
#include <hip/hip_bf16.h>

#define NL   6
#define NH   16
#define HID  1024
#define HD   64
#define FFW  4096
#define VOC  32000
#define WINN 512
#define EMB  128
#define NB   4
#define TT   1024   // WIN + WIN

typedef __attribute__((ext_vector_type(8))) short b16x8;
typedef __attribute__((ext_vector_type(4))) float f32x4;

__device__ __forceinline__ ushort f2b(float f) {
    __hip_bfloat16 h = __float2bfloat16(f);
    return *reinterpret_cast<ushort*>(&h);
}

// ---------------------------------------------------------------------------
// Embed (f32)
// ---------------------------------------------------------------------------
__global__ __launch_bounds__(256) void embed_kernel(
    const int* __restrict__ xin, const float* __restrict__ Wemb,
    const float* __restrict__ Wlin, float* __restrict__ h0)
{
    int row = blockIdx.x;
    int tok = xin[row];
    __shared__ float tk[EMB];
    if (threadIdx.x < EMB) tk[threadIdx.x] = Wemb[tok * EMB + threadIdx.x] * 0.03125f;
    __syncthreads();
    for (int j = 0; j < 4; ++j) {
        int c = threadIdx.x + 256 * j;
        float acc = 0.f;
        for (int e = 0; e < EMB; ++e) acc += tk[e] * Wlin[e * HID + c];
        h0[(long)row * HID + c] = acc;
    }
}

// ---------------------------------------------------------------------------
// x[b,t,:] = pos[t,:] + (t<512 ? prev[b,t,:] : cur[b,t-512,:])
// ---------------------------------------------------------------------------
__global__ __launch_bounds__(256) void build_x_kernel(
    const float* __restrict__ pos, const float* __restrict__ prev,
    const float* __restrict__ cur, float* __restrict__ x)
{
    int i4 = blockIdx.x * blockDim.x + threadIdx.x;
    if (i4 >= NB * TT * HID / 4) return;
    int h4 = i4 % (HID / 4);
    int bt = i4 / (HID / 4);
    int t = bt % TT, b = bt / TT;
    float4 p = ((const float4*)pos)[t * (HID / 4) + h4];
    float4 s;
    if (t < WINN) s = ((const float4*)prev)[(long)(b * WINN + t) * (HID / 4) + h4];
    else          s = ((const float4*)cur)[(long)(b * WINN + (t - WINN)) * (HID / 4) + h4];
    float4 r; r.x = p.x + s.x; r.y = p.y + s.y; r.z = p.z + s.z; r.w = p.w + s.w;
    ((float4*)x)[i4] = r;
}

// ---------------------------------------------------------------------------
// f32 SGEMM v3: 128x64 tile, 256 threads, 8x4 microtile, BK=16, double-buf.
// C = act(scale*(A[:,k_off:k_off+Ksub] @ W[k_off:,:]) + bias).
// amap: row r -> (r>>9)*1024 + 512 + (r&511).
// Grid: (N/64, M/128).
// ---------------------------------------------------------------------------
__global__ __launch_bounds__(256) void sgemm_v3(
    const float* __restrict__ A, const float* __restrict__ W, float* __restrict__ C,
    int M, int N, int K_stride, int k_off, int Ksub,
    float scale, const float* __restrict__ bias, int relu, int amap)
{
    __shared__ float As[2][16][132];   // [k][row] (A transposed in LDS)
    __shared__ float Bs[2][16][68];    // [k][col]
    const int tid = threadIdx.x;
    const int tx = tid & 15, ty = tid >> 4;
    const int rb = blockIdx.y * 128;
    const long cb = (long)blockIdx.x * 64;

    // A staging: thread -> row lr, k-span ak..ak+7 (two float4)
    const int lr = tid >> 1;            // 0..127
    const int ak = (tid & 1) * 8;       // 0 or 8
    int gr = rb + lr;
    long mrow = amap ? (long)((gr >> 9) * 1024 + 512 + (gr & 511)) : (long)gr;
    const float* Ap = A + mrow * K_stride + k_off + ak;
    // B staging: thread -> k-row br, cols bc..bc+3 (one float4)
    const int br = tid >> 4;            // 0..15
    const int bc = (tid & 15) << 2;     // 0..60
    const float* Wp = W + (long)(k_off + br) * N + cb + bc;

    float4 a0 = *(const float4*)(Ap);
    float4 a1 = *(const float4*)(Ap + 4);
    float4 b0 = *(const float4*)(Wp);

    As[0][ak + 0][lr] = a0.x; As[0][ak + 1][lr] = a0.y;
    As[0][ak + 2][lr] = a0.z; As[0][ak + 3][lr] = a0.w;
    As[0][ak + 4][lr] = a1.x; As[0][ak + 5][lr] = a1.y;
    As[0][ak + 6][lr] = a1.z; As[0][ak + 7][lr] = a1.w;
    *(float4*)&Bs[0][br][bc] = b0;
    __syncthreads();

    float ac[8][4] = {};
    const int nk = Ksub >> 4;
    for (int t = 0; t < nk; ++t) {
        const int cur = t & 1;
        const bool more = (t + 1 < nk);
        if (more) {
            int k0 = (t + 1) << 4;
            a0 = *(const float4*)(Ap + k0);
            a1 = *(const float4*)(Ap + k0 + 4);
            b0 = *(const float4*)(Wp + (long)k0 * N);
        }
#pragma unroll
        for (int kk = 0; kk < 16; ++kk) {
            float4 x0 = *(const float4*)&As[cur][kk][ty << 2];
            float4 x1 = *(const float4*)&As[cur][kk][64 + (ty << 2)];
            float4 y0 = *(const float4*)&Bs[cur][kk][tx << 2];
            float xa[8] = {x0.x, x0.y, x0.z, x0.w, x1.x, x1.y, x1.z, x1.w};
            float yb[4] = {y0.x, y0.y, y0.z, y0.w};
#pragma unroll
            for (int i = 0; i < 8; ++i)
#pragma unroll
                for (int j = 0; j < 4; ++j)
                    ac[i][j] += xa[i] * yb[j];
        }
        if (more) {
            const int nxt = cur ^ 1;
            As[nxt][ak + 0][lr] = a0.x; As[nxt][ak + 1][lr] = a0.y;
            As[nxt][ak + 2][lr] = a0.z; As[nxt][ak + 3][lr] = a0.w;
            As[nxt][ak + 4][lr] = a1.x; As[nxt][ak + 5][lr] = a1.y;
            As[nxt][ak + 6][lr] = a1.z; As[nxt][ak + 7][lr] = a1.w;
            *(float4*)&Bs[nxt][br][bc] = b0;
            __syncthreads();
        }
    }

#pragma unroll
    for (int i = 0; i < 8; ++i) {
        long row = rb + ((i >> 2) * 64) + (ty << 2) + (i & 3);
        long col = cb + (tx << 2);
        float4 v;
        v.x = ac[i][0] * scale; v.y = ac[i][1] * scale;
        v.z = ac[i][2] * scale; v.w = ac[i][3] * scale;
        if (bias) {
            float4 b4 = *(const float4*)&bias[col];
            v.x += b4.x; v.y += b4.y; v.z += b4.z; v.w += b4.w;
        }
        if (relu) {
            v.x = fmaxf(v.x, 0.f); v.y = fmaxf(v.y, 0.f);
            v.z = fmaxf(v.z, 0.f); v.w = fmaxf(v.w, 0.f);
        }
        *(float4*)&C[row * N + col] = v;
    }
}

// ---------------------------------------------------------------------------
// Flash attention, f32, online softmax. Block = (qt, h, b): 64 q-rows.
// ---------------------------------------------------------------------------
__global__ __launch_bounds__(256) void fattn_kernel(
    const float* __restrict__ q, const float* __restrict__ k,
    const float* __restrict__ v, float* __restrict__ o)
{
    __shared__ float qs[64][68];
    __shared__ float ks[64][68];
    __shared__ float vs[64][68];
    __shared__ float ps[64][68];
    const int qt = blockIdx.x, h = blockIdx.y, b = blockIdx.z;
    const int tid = threadIdx.x, tx = tid & 15, ty = tid >> 4;
    const int qbase = b * WINN + qt * 64;

#pragma unroll
    for (int j = 0; j < 4; ++j) {
        int p = tid + 256 * j;
        int row = p >> 4, c4 = (p & 15) << 2;
        *(float4*)&qs[row][c4] =
            *(const float4*)&q[(long)(qbase + row) * HID + h * HD + c4];
    }

    float O[4][4] = {};
    float mrow[4], lrow[4];
#pragma unroll
    for (int i = 0; i < 4; ++i) { mrow[i] = -3.0e38f; lrow[i] = 0.f; }

    const int ktmax = 9 + qt;
    for (int kt = 0; kt < ktmax; ++kt) {
        __syncthreads();
#pragma unroll
        for (int j = 0; j < 4; ++j) {
            int p = tid + 256 * j;
            int row = p >> 4, c4 = p & 15;
            long g = (long)(b * TT + kt * 64 + row) * HID + h * HD + (c4 << 2);
            *(float4*)&ks[row][((c4 ^ (row >> 2)) & 15) << 2] = *(const float4*)&k[g];
            *(float4*)&vs[row][c4 << 2] = *(const float4*)&v[g];
        }
        __syncthreads();

        float S[4][4] = {};
#pragma unroll
        for (int d4 = 0; d4 < 16; ++d4) {
            float4 qa[4], ka[4];
#pragma unroll
            for (int i = 0; i < 4; ++i)
                qa[i] = *(const float4*)&qs[(ty << 2) + i][d4 << 2];
#pragma unroll
            for (int j = 0; j < 4; ++j)
                ka[j] = *(const float4*)&ks[(tx << 2) + j][((d4 ^ tx) & 15) << 2];
#pragma unroll
            for (int i = 0; i < 4; ++i)
#pragma unroll
                for (int j = 0; j < 4; ++j)
                    S[i][j] += qa[i].x * ka[j].x + qa[i].y * ka[j].y
                             + qa[i].z * ka[j].z + qa[i].w * ka[j].w;
        }

        if (kt == ktmax - 1) {
#pragma unroll
            for (int i = 0; i < 4; ++i) {
                int qi = WINN + qt * 64 + (ty << 2) + i;
#pragma unroll
                for (int j = 0; j < 4; ++j) {
                    int kg = kt * 64 + (tx << 2) + j;
                    if (kg > qi) S[i][j] = -1e9f;
                }
            }
        }

#pragma unroll
        for (int i = 0; i < 4; ++i) {
            float mx = fmaxf(fmaxf(S[i][0], S[i][1]), fmaxf(S[i][2], S[i][3]));
            mx = fmaxf(mx, __shfl_xor(mx, 1));
            mx = fmaxf(mx, __shfl_xor(mx, 2));
            mx = fmaxf(mx, __shfl_xor(mx, 4));
            mx = fmaxf(mx, __shfl_xor(mx, 8));
            float mnew = fmaxf(mrow[i], mx);
            float alpha = __expf(mrow[i] - mnew);
            float rs = 0.f;
#pragma unroll
            for (int j = 0; j < 4; ++j) { S[i][j] = __expf(S[i][j] - mnew); rs += S[i][j]; }
            rs += __shfl_xor(rs, 1);
            rs += __shfl_xor(rs, 2);
            rs += __shfl_xor(rs, 4);
            rs += __shfl_xor(rs, 8);
            lrow[i] = lrow[i] * alpha + rs;
            mrow[i] = mnew;
#pragma unroll
            for (int j = 0; j < 4; ++j) O[i][j] *= alpha;
        }

#pragma unroll
        for (int i = 0; i < 4; ++i) {
            float4 pv; pv.x = S[i][0]; pv.y = S[i][1]; pv.z = S[i][2]; pv.w = S[i][3];
            *(float4*)&ps[(ty << 2) + i][tx << 2] = pv;
        }
        __syncthreads();
#pragma unroll
        for (int k4 = 0; k4 < 16; ++k4) {
            float4 pa[4], va[4];
#pragma unroll
            for (int i = 0; i < 4; ++i)
                pa[i] = *(const float4*)&ps[(ty << 2) + i][k4 << 2];
#pragma unroll
            for (int j = 0; j < 4; ++j)
                va[j] = *(const float4*)&vs[(k4 << 2) + j][tx << 2];
#pragma unroll
            for (int i = 0; i < 4; ++i) {
                O[i][0] += pa[i].x * va[0].x + pa[i].y * va[1].x + pa[i].z * va[2].x + pa[i].w * va[3].x;
                O[i][1] += pa[i].x * va[0].y + pa[i].y * va[1].y + pa[i].z * va[2].y + pa[i].w * va[3].y;
                O[i][2] += pa[i].x * va[0].z + pa[i].y * va[1].z + pa[i].z * va[2].z + pa[i].w * va[3].z;
                O[i][3] += pa[i].x * va[0].w + pa[i].y * va[1].w + pa[i].z * va[2].w + pa[i].w * va[3].w;
            }
        }
    }

#pragma unroll
    for (int i = 0; i < 4; ++i) {
        float inv = 1.f / lrow[i];
        float4 vv;
        vv.x = O[i][0] * inv; vv.y = O[i][1] * inv;
        vv.z = O[i][2] * inv; vv.w = O[i][3] * inv;
        *(float4*)&o[(long)(qbase + (ty << 2) + i) * HID + h * HD + (tx << 2)] = vv;
    }
}

// ---------------------------------------------------------------------------
// Transpose+convert: Wt[n][k] = bf16(W[k][n]).
// ---------------------------------------------------------------------------
__global__ __launch_bounds__(256) void transp_kernel(
    const float* __restrict__ W, ushort* __restrict__ Wt, int K, int N)
{
    __shared__ float ts[32][33];
    int n0 = blockIdx.x * 32, k0 = blockIdx.y * 32;
    int tr = threadIdx.x >> 5, tc = threadIdx.x & 31;
#pragma unroll
    for (int j = 0; j < 4; ++j)
        ts[tr + j * 8][tc] = W[(long)(k0 + tr + j * 8) * N + n0 + tc];
    __syncthreads();
#pragma unroll
    for (int j = 0; j < 4; ++j) {
        int n = tr + j * 8;
        Wt[(long)(n0 + n) * K + k0 + tc] = f2b(ts[tc][n]);
    }
}

// ---------------------------------------------------------------------------
// bf16 MFMA GEMM (logits only). Padded-linear LDS [128][40] ushort.
// ---------------------------------------------------------------------------
__global__ __launch_bounds__(256) void mfma_gemm(
    const ushort* __restrict__ A, const ushort* __restrict__ Bt,
    float* __restrict__ Cf, int M, int N, int K)
{
    __shared__ ushort As[128 * 40];
    __shared__ ushort Bs[128 * 40];
    const int tid  = threadIdx.x;
    const int rb   = blockIdx.y * 128;
    const int cb   = blockIdx.x * 128;
    const int wave = tid >> 6, lane = tid & 63;
    const int wr   = (wave >> 1) * 64;
    const int wc   = (wave & 1) * 64;
    const int lr   = lane & 15;
    const int kh   = lane >> 4;

    const int srow = tid >> 1;
    const int kc0  = (tid & 1) * 2;
    const ushort* aptr = A + (long)(rb + srow) * K + kc0 * 8;
    const ushort* bptr = Bt + (long)(cb + srow) * K + kc0 * 8;
    const int woff0 = srow * 40 + kc0 * 8;
    const int woff1 = srow * 40 + (kc0 + 1) * 8;

    int aoff[4], boff[4];
#pragma unroll
    for (int m = 0; m < 4; ++m) aoff[m] = (wr + m * 16 + lr) * 40 + kh * 8;
#pragma unroll
    for (int n = 0; n < 4; ++n) boff[n] = (wc + n * 16 + lr) * 40 + kh * 8;

    f32x4 acc[4][4];
#pragma unroll
    for (int m = 0; m < 4; ++m)
#pragma unroll
        for (int n = 0; n < 4; ++n)
            acc[m][n] = (f32x4){0.f, 0.f, 0.f, 0.f};

    for (int k0 = 0; k0 < K; k0 += 32) {
        uint4 a0 = *(const uint4*)(aptr + k0);
        uint4 a1 = *(const uint4*)(aptr + k0 + 8);
        uint4 b0 = *(const uint4*)(bptr + k0);
        uint4 b1 = *(const uint4*)(bptr + k0 + 8);
        __syncthreads();
        *(uint4*)(As + woff0) = a0;
        *(uint4*)(As + woff1) = a1;
        *(uint4*)(Bs + woff0) = b0;
        *(uint4*)(Bs + woff1) = b1;
        __syncthreads();
        b16x8 af[4], bfr[4];
#pragma unroll
        for (int m = 0; m < 4; ++m) af[m] = *(const b16x8*)(As + aoff[m]);
#pragma unroll
        for (int n = 0; n < 4; ++n) bfr[n] = *(const b16x8*)(Bs + boff[n]);
#pragma unroll
        for (int m = 0; m < 4; ++m)
#pragma unroll
            for (int n = 0; n < 4; ++n)
                acc[m][n] = __builtin_amdgcn_mfma_f32_16x16x32_bf16(af[m], bfr[n], acc[m][n], 0, 0, 0);
    }

#pragma unroll
    for (int m = 0; m < 4; ++m) {
        int row0 = rb + wr + m * 16 + kh * 4;
#pragma unroll
        for (int n = 0; n < 4; ++n) {
            int col = cb + wc + n * 16 + lr;
#pragma unroll
            for (int r = 0; r < 4; ++r)
                Cf[(long)(row0 + r) * N + col] = acc[m][n][r];
        }
    }
}

// ---------------------------------------------------------------------------
// out[r] = res[r'] + LN(t[r] (+ t2[r]))*scale + bias ; optional bf16 mirror.
// ---------------------------------------------------------------------------
__global__ __launch_bounds__(256) void ln_res_kernel(
    const float* __restrict__ t, const float* __restrict__ t2,
    const float* __restrict__ res, float* __restrict__ out,
    ushort* __restrict__ outb,
    const float* __restrict__ bias, const float* __restrict__ scale, int res_map)
{
    int r = blockIdx.x;
    int tid = threadIdx.x;
    long rr = res_map ? (long)((r >> 9) * 1024 + 512 + (r & 511)) : (long)r;
    float4 v = ((const float4*)(t + (long)r * HID))[tid];
    if (t2) {
        float4 w = ((const float4*)(t2 + (long)r * HID))[tid];
        v.x += w.x; v.y += w.y; v.z += w.z; v.w += w.w;
    }
    __shared__ float red[4];
    float s = v.x + v.y + v.z + v.w;
    for (int off = 32; off > 0; off >>= 1) s += __shfl_xor(s, off);
    if ((tid & 63) == 0) red[tid >> 6] = s;
    __syncthreads();
    float mean = (red[0] + red[1] + red[2] + red[3]) * (1.f / HID);
    __syncthreads();
    float dx = v.x - mean, dy = v.y - mean, dz = v.z - mean, dw = v.w - mean;
    float qs = dx * dx + dy * dy + dz * dz + dw * dw;
    for (int off = 32; off > 0; off >>= 1) qs += __shfl_xor(qs, off);
    if ((tid & 63) == 0) red[tid >> 6] = qs;
    __syncthreads();
    float var = (red[0] + red[1] + red[2] + red[3]) * (1.f / HID);
    float rs = rsqrtf(var + 1e-6f);
    float4 rv = ((const float4*)(res + rr * HID))[tid];
    float4 sc4 = ((const float4*)scale)[tid];
    float4 b4  = ((const float4*)bias)[tid];
    float4 o4;
    o4.x = rv.x + dx * rs * sc4.x + b4.x;
    o4.y = rv.y + dy * rs * sc4.y + b4.y;
    o4.z = rv.z + dz * rs * sc4.z + b4.z;
    o4.w = rv.w + dw * rs * sc4.w + b4.w;
    ((float4*)(out + (long)r * HID))[tid] = o4;
    if (outb) {
        ushort4 u; u.x = f2b(o4.x); u.y = f2b(o4.y); u.z = f2b(o4.z); u.w = f2b(o4.w);
        ((ushort4*)(outb + (long)r * HID))[tid] = u;
    }
}

// ---------------------------------------------------------------------------
// Workspace (max offset 92 MiB, < proven-safe 120 MiB):
//  [0,16M)   x_f    --+
//  [16,32M)  kb_f     +-- ff1 (32MB) overlays [0,32M) after ln1 (both dead)
//  [32,48M)  vb_f
//  [48,56M)  qb_f
//  [56,64M)  ob_f
//  [64,72M)  t0a (=h0)
//  [72,80M)  t0b
//  [80,88M)  xs
//  [88,92M)  decb
//  wdect overlay [0,62.5M): post-loop only (all transients dead).
// ---------------------------------------------------------------------------
extern "C" void kernel_launch(void* const* d_in, const int* in_sizes, int n_in,
                              void* d_out, int out_size, void* d_ws, size_t ws_size,
                              hipStream_t stream)
{
    const int*   x_input = (const int*)  d_in[0];
    const float* prev    = (const float*)d_in[1];
    const float* Wemb    = (const float*)d_in[2];
    const float* Wlin    = (const float*)d_in[3];
    const float* pdec    = (const float*)d_in[4];
    const float* pq      = (const float*)d_in[5];
    const float* pk      = (const float*)d_in[6];
    const float* pv      = (const float*)d_in[7];
    const float* pc      = (const float*)d_in[8];
    const float* pf1     = (const float*)d_in[9];
    const float* pf2     = (const float*)d_in[10];
    const float* bf1     = (const float*)d_in[11];
    const float* bf2     = (const float*)d_in[12];
    const float* b1      = (const float*)d_in[13];
    const float* b2      = (const float*)d_in[14];
    const float* s1      = (const float*)d_in[15];
    const float* s2      = (const float*)d_in[16];
    const float* pos     = (const float*)d_in[17];

    float* outp   = (float*)d_out;
    float* logits = outp;
    float* dec    = outp + (long)2048 * VOC;

    char* base = (char*)d_ws;
    float*  x_f  = (float*) (base + 0);
    float*  kb_f = (float*) (base + 16777216);
    float*  vb_f = (float*) (base + 33554432);
    float*  qb_f = (float*) (base + 50331648);
    float*  ob_f = (float*) (base + 58720256);
    float*  t0a  = (float*) (base + 67108864);
    float*  h0   = t0a;
    float*  t0b  = (float*) (base + 75497472);
    float*  xs   = (float*) (base + 83886080);
    ushort* decb = (ushort*)(base + 92274688);   // ends 96,468,992
    float*  ff1  = (float*) (base + 0);          // overlays x_f+kb_f after ln1
    ushort* wdect= (ushort*)(base + 0);          // post-loop overlay

    embed_kernel<<<NB * WINN, 256, 0, stream>>>(x_input, Wemb, Wlin, h0);

    for (int l = 0; l < NL; ++l) {
        const float* cur = (l == 0) ? h0 : (dec + (long)(l - 1) * 2097152);
        build_x_kernel<<<(NB * TT * HID / 4) / 256, 256, 0, stream>>>(
            pos + (long)l * TT * HID, prev + (long)l * NB * WINN * HID, cur, x_f);

        sgemm_v3<<<dim3(HID / 64, (NB * TT) / 128), 256, 0, stream>>>(
            x_f, pk + (long)l * HID * HID, kb_f, NB * TT, HID, HID, 0, HID, 1.f, nullptr, 0, 0);
        sgemm_v3<<<dim3(HID / 64, (NB * TT) / 128), 256, 0, stream>>>(
            x_f, pv + (long)l * HID * HID, vb_f, NB * TT, HID, HID, 0, HID, 1.f, nullptr, 0, 0);
        sgemm_v3<<<dim3(HID / 64, (NB * WINN) / 128), 256, 0, stream>>>(
            x_f, pq + (long)l * HID * HID, qb_f, NB * WINN, HID, HID, 0, HID, 0.125f, nullptr, 0, 1);

        fattn_kernel<<<dim3(WINN / 64, NH, NB), 256, 0, stream>>>(qb_f, kb_f, vb_f, ob_f);

        sgemm_v3<<<dim3(HID / 64, (NB * WINN) / 128), 256, 0, stream>>>(
            ob_f, pc + (long)l * HID * HID, t0a, NB * WINN, HID, HID, 0, HID, 1.f, nullptr, 0, 0);
        ln_res_kernel<<<NB * WINN, 256, 0, stream>>>(
            t0a, nullptr, x_f, xs, nullptr, b1 + l * HID, s1 + l * HID, 1);

        sgemm_v3<<<dim3(FFW / 64, (NB * WINN) / 128), 256, 0, stream>>>(
            xs, pf1 + (long)l * HID * FFW, ff1, NB * WINN, FFW, HID, 0, HID, 1.f, bf1 + l * FFW, 1, 0);
        // FF2 split-K: halves into t0a / t0b
        sgemm_v3<<<dim3(HID / 64, (NB * WINN) / 128), 256, 0, stream>>>(
            ff1, pf2 + (long)l * FFW * HID, t0a, NB * WINN, HID, FFW, 0, FFW / 2, 1.f, bf2 + l * HID, 0, 0);
        sgemm_v3<<<dim3(HID / 64, (NB * WINN) / 128), 256, 0, stream>>>(
            ff1, pf2 + (long)l * FFW * HID, t0b, NB * WINN, HID, FFW, FFW / 2, FFW / 2, 1.f, nullptr, 0, 0);
        ln_res_kernel<<<NB * WINN, 256, 0, stream>>>(
            t0a, t0b, xs, dec + (long)l * 2097152, (l == NL - 1) ? decb : nullptr,
            b2 + l * HID, s2 + l * HID, 0);
    }

    transp_kernel<<<dim3(VOC / 32, HID / 32), 256, 0, stream>>>(pdec, wdect, HID, VOC);
    mfma_gemm<<<dim3(VOC / 128, (NB * WINN) / 128), 256, 0, stream>>>(
        decb, wdect, logits, NB * WINN, VOC, HID);
}

// Round 7
// 4199.097 us; speedup vs baseline: 2.9475x; 1.9901x over previous
//
#include <hip/hip_runtime.h>
#include <hip/hip_bf16.h>

#define NL   6
#define NH   16
#define HID  1024
#define HD   64
#define FFW  4096
#define VOC  32000
#define WINN 512
#define EMB  128
#define NB   4
#define TT   1024   // WIN + WIN

typedef __attribute__((ext_vector_type(8))) _Float16 f16x8;
typedef __attribute__((ext_vector_type(8))) short    b16x8;
typedef __attribute__((ext_vector_type(4))) float    f32x4;

__device__ __forceinline__ ushort f2b(float f) {
    __hip_bfloat16 h = __float2bfloat16(f);
    return *reinterpret_cast<ushort*>(&h);
}
// split f32 into fp16 hi/lo:  f ~= hi + lo * 2^-11  (error ~ |f|*2^-22)
__device__ __forceinline__ void split16(float f, ushort& hb, ushort& lb) {
    _Float16 h = (_Float16)f;
    _Float16 l = (_Float16)((f - (float)h) * 2048.0f);
    hb = __builtin_bit_cast(ushort, h);
    lb = __builtin_bit_cast(ushort, l);
}

// ---------------------------------------------------------------------------
// Embed (f32)
// ---------------------------------------------------------------------------
__global__ __launch_bounds__(256) void embed_kernel(
    const int* __restrict__ xin, const float* __restrict__ Wemb,
    const float* __restrict__ Wlin, float* __restrict__ h0)
{
    int row = blockIdx.x;
    int tok = xin[row];
    __shared__ float tk[EMB];
    if (threadIdx.x < EMB) tk[threadIdx.x] = Wemb[tok * EMB + threadIdx.x] * 0.03125f;
    __syncthreads();
    for (int j = 0; j < 4; ++j) {
        int c = threadIdx.x + 256 * j;
        float acc = 0.f;
        for (int e = 0; e < EMB; ++e) acc += tk[e] * Wlin[e * HID + c];
        h0[(long)row * HID + c] = acc;
    }
}

// ---------------------------------------------------------------------------
// x = pos + concat(prev, cur); outputs f32 + fp16 hi/lo split
// ---------------------------------------------------------------------------
__global__ __launch_bounds__(256) void build_x_kernel(
    const float* __restrict__ pos, const float* __restrict__ prev,
    const float* __restrict__ cur, float* __restrict__ x,
    ushort* __restrict__ xh, ushort* __restrict__ xl)
{
    int i4 = blockIdx.x * blockDim.x + threadIdx.x;
    if (i4 >= NB * TT * HID / 4) return;
    int h4 = i4 % (HID / 4);
    int bt = i4 / (HID / 4);
    int t = bt % TT, b = bt / TT;
    float4 p = ((const float4*)pos)[t * (HID / 4) + h4];
    float4 s;
    if (t < WINN) s = ((const float4*)prev)[(long)(b * WINN + t) * (HID / 4) + h4];
    else          s = ((const float4*)cur)[(long)(b * WINN + (t - WINN)) * (HID / 4) + h4];
    float4 r; r.x = p.x + s.x; r.y = p.y + s.y; r.z = p.z + s.z; r.w = p.w + s.w;
    ((float4*)x)[i4] = r;
    ushort4 uh, ul;
    split16(r.x, uh.x, ul.x); split16(r.y, uh.y, ul.y);
    split16(r.z, uh.z, ul.z); split16(r.w, uh.w, ul.w);
    ((ushort4*)xh)[i4] = uh;
    ((ushort4*)xl)[i4] = ul;
}

// ---------------------------------------------------------------------------
// Weight transpose + fp16 split: W f32 [K,N] -> Wt_hi/Wt_lo fp16 [N,K]
// ---------------------------------------------------------------------------
__global__ __launch_bounds__(256) void wsplit_kernel(
    const float* __restrict__ W, ushort* __restrict__ Wth, ushort* __restrict__ Wtl,
    int K, int N)
{
    __shared__ float ts[32][33];
    int n0 = blockIdx.x * 32, k0 = blockIdx.y * 32;
    int tr = threadIdx.x >> 5, tc = threadIdx.x & 31;
#pragma unroll
    for (int j = 0; j < 4; ++j)
        ts[tr + j * 8][tc] = W[(long)(k0 + tr + j * 8) * N + n0 + tc];
    __syncthreads();
#pragma unroll
    for (int j = 0; j < 4; ++j) {
        int n = tr + j * 8;
        ushort hb, lb;
        split16(ts[tc][n], hb, lb);
        long idx = (long)(n0 + n) * K + k0 + tc;
        Wth[idx] = hb;
        Wtl[idx] = lb;
    }
}

// ---------------------------------------------------------------------------
// Split-fp16 MFMA GEMM ("Markidis"): C = act(scale*(A@B) + bias) with
// A ~= Ah + Al*2^-11 (fp16 [M,K] row-major), B^T ~= Bh + Bl*2^-11 ([N,K]).
// acc = Ah*Bh + (Ah*Bl + Al*Bh)*2^-11 -> ~f32 precision.
// Tile 128x64, 4 waves (2x2), wave = 64x32 (4x2 16x16 frags), BK=32.
// Grid (N/64, M/128). k_off/Ksub for split-K. amap remaps A rows.
// Outputs: Cf f32 and/or (Chh,Cll) fp16 split, any may be null.
// ---------------------------------------------------------------------------
__global__ __launch_bounds__(256) void hgemm(
    const ushort* __restrict__ Ah, const ushort* __restrict__ Al,
    const ushort* __restrict__ Bh, const ushort* __restrict__ Bl,
    float* __restrict__ Cf, ushort* __restrict__ Chh, ushort* __restrict__ Cll,
    int M, int N, int K_stride, int k_off, int Ksub,
    float scale, const float* __restrict__ bias, int relu, int amap)
{
    __shared__ ushort Ash[128 * 40];
    __shared__ ushort Asl[128 * 40];
    __shared__ ushort Bsh[64 * 40];
    __shared__ ushort Bsl[64 * 40];
    const int tid  = threadIdx.x;
    const int rb   = blockIdx.y * 128;
    const int cb   = blockIdx.x * 64;
    const int wave = tid >> 6, lane = tid & 63;
    const int wr   = (wave >> 1) * 64;
    const int wc   = (wave & 1) * 32;
    const int lr   = lane & 15;
    const int kh   = lane >> 4;

    // A staging: row = tid>>1 (0..127), k-halfs (tid&1)*16 + {0,8}
    const int sar = tid >> 1;
    const int sak = (tid & 1) * 16;
    int gra = rb + sar;
    long marow = amap ? (long)((gra >> 9) * 1024 + 512 + (gra & 511)) : (long)gra;
    const ushort* pAh = Ah + marow * K_stride + k_off + sak;
    const ushort* pAl = Al + marow * K_stride + k_off + sak;
    const int wA0 = sar * 40 + sak, wA1 = wA0 + 8;
    // B staging: row = tid>>2 (0..63), k-halfs (tid&3)*8
    const int sbr = tid >> 2;
    const int sbk = (tid & 3) * 8;
    const ushort* pBh = Bh + (long)(cb + sbr) * K_stride + k_off + sbk;
    const ushort* pBl = Bl + (long)(cb + sbr) * K_stride + k_off + sbk;
    const int wB0 = sbr * 40 + sbk;

    int aoff[4], boff[2];
#pragma unroll
    for (int m = 0; m < 4; ++m) aoff[m] = (wr + m * 16 + lr) * 40 + kh * 8;
#pragma unroll
    for (int n = 0; n < 2; ++n) boff[n] = (wc + n * 16 + lr) * 40 + kh * 8;

    f32x4 accH[4][2], accL[4][2];
#pragma unroll
    for (int m = 0; m < 4; ++m)
#pragma unroll
        for (int n = 0; n < 2; ++n) {
            accH[m][n] = (f32x4){0.f, 0.f, 0.f, 0.f};
            accL[m][n] = (f32x4){0.f, 0.f, 0.f, 0.f};
        }

    for (int k0 = 0; k0 < Ksub; k0 += 32) {
        uint4 ah0 = *(const uint4*)(pAh + k0);
        uint4 ah1 = *(const uint4*)(pAh + k0 + 8);
        uint4 al0 = *(const uint4*)(pAl + k0);
        uint4 al1 = *(const uint4*)(pAl + k0 + 8);
        uint4 bh0 = *(const uint4*)(pBh + k0);
        uint4 bl0 = *(const uint4*)(pBl + k0);
        __syncthreads();
        *(uint4*)(Ash + wA0) = ah0; *(uint4*)(Ash + wA1) = ah1;
        *(uint4*)(Asl + wA0) = al0; *(uint4*)(Asl + wA1) = al1;
        *(uint4*)(Bsh + wB0) = bh0;
        *(uint4*)(Bsl + wB0) = bl0;
        __syncthreads();
        f16x8 afh[4], afl[4], bfh[2], bfl[2];
#pragma unroll
        for (int m = 0; m < 4; ++m) {
            afh[m] = *(const f16x8*)(Ash + aoff[m]);
            afl[m] = *(const f16x8*)(Asl + aoff[m]);
        }
#pragma unroll
        for (int n = 0; n < 2; ++n) {
            bfh[n] = *(const f16x8*)(Bsh + boff[n]);
            bfl[n] = *(const f16x8*)(Bsl + boff[n]);
        }
#pragma unroll
        for (int m = 0; m < 4; ++m)
#pragma unroll
            for (int n = 0; n < 2; ++n) {
                accH[m][n] = __builtin_amdgcn_mfma_f32_16x16x32_f16(afh[m], bfh[n], accH[m][n], 0, 0, 0);
                accL[m][n] = __builtin_amdgcn_mfma_f32_16x16x32_f16(afh[m], bfl[n], accL[m][n], 0, 0, 0);
                accL[m][n] = __builtin_amdgcn_mfma_f32_16x16x32_f16(afl[m], bfh[n], accL[m][n], 0, 0, 0);
            }
    }

    // C/D layout: col = lane&15, row = (lane>>4)*4 + reg   [verified R5 logits]
#pragma unroll
    for (int m = 0; m < 4; ++m) {
        int row0 = rb + wr + m * 16 + kh * 4;
#pragma unroll
        for (int n = 0; n < 2; ++n) {
            int col = cb + wc + n * 16 + lr;
            float bv = bias ? bias[col] : 0.f;
#pragma unroll
            for (int r = 0; r < 4; ++r) {
                float v = (accH[m][n][r] + accL[m][n][r] * (1.f / 2048.f)) * scale + bv;
                if (relu) v = fmaxf(v, 0.f);
                long idx = (long)(row0 + r) * N + col;
                if (Cf) Cf[idx] = v;
                if (Chh) { ushort hb, lb; split16(v, hb, lb); Chh[idx] = hb; Cll[idx] = lb; }
            }
        }
    }
}

// ---------------------------------------------------------------------------
// Flash attention, f32, online softmax. Block = (qt, h, b): 64 q-rows.
// Writes o as fp16 hi/lo split (feeds C-proj hgemm).
// ---------------------------------------------------------------------------
__global__ __launch_bounds__(256) void fattn_kernel(
    const float* __restrict__ q, const float* __restrict__ k,
    const float* __restrict__ v, ushort* __restrict__ oh, ushort* __restrict__ ol)
{
    __shared__ float qs[64][68];
    __shared__ float ks[64][68];
    __shared__ float vs[64][68];
    __shared__ float ps[64][68];
    const int qt = blockIdx.x, h = blockIdx.y, b = blockIdx.z;
    const int tid = threadIdx.x, tx = tid & 15, ty = tid >> 4;
    const int qbase = b * WINN + qt * 64;

#pragma unroll
    for (int j = 0; j < 4; ++j) {
        int p = tid + 256 * j;
        int row = p >> 4, c4 = (p & 15) << 2;
        *(float4*)&qs[row][c4] =
            *(const float4*)&q[(long)(qbase + row) * HID + h * HD + c4];
    }

    float O[4][4] = {};
    float mrow[4], lrow[4];
#pragma unroll
    for (int i = 0; i < 4; ++i) { mrow[i] = -3.0e38f; lrow[i] = 0.f; }

    const int ktmax = 9 + qt;
    for (int kt = 0; kt < ktmax; ++kt) {
        __syncthreads();
#pragma unroll
        for (int j = 0; j < 4; ++j) {
            int p = tid + 256 * j;
            int row = p >> 4, c4 = p & 15;
            long g = (long)(b * TT + kt * 64 + row) * HID + h * HD + (c4 << 2);
            *(float4*)&ks[row][((c4 ^ (row >> 2)) & 15) << 2] = *(const float4*)&k[g];
            *(float4*)&vs[row][c4 << 2] = *(const float4*)&v[g];
        }
        __syncthreads();

        float S[4][4] = {};
#pragma unroll
        for (int d4 = 0; d4 < 16; ++d4) {
            float4 qa[4], ka[4];
#pragma unroll
            for (int i = 0; i < 4; ++i)
                qa[i] = *(const float4*)&qs[(ty << 2) + i][d4 << 2];
#pragma unroll
            for (int j = 0; j < 4; ++j)
                ka[j] = *(const float4*)&ks[(tx << 2) + j][((d4 ^ tx) & 15) << 2];
#pragma unroll
            for (int i = 0; i < 4; ++i)
#pragma unroll
                for (int j = 0; j < 4; ++j)
                    S[i][j] += qa[i].x * ka[j].x + qa[i].y * ka[j].y
                             + qa[i].z * ka[j].z + qa[i].w * ka[j].w;
        }

        if (kt == ktmax - 1) {
#pragma unroll
            for (int i = 0; i < 4; ++i) {
                int qi = WINN + qt * 64 + (ty << 2) + i;
#pragma unroll
                for (int j = 0; j < 4; ++j) {
                    int kg = kt * 64 + (tx << 2) + j;
                    if (kg > qi) S[i][j] = -1e9f;
                }
            }
        }

#pragma unroll
        for (int i = 0; i < 4; ++i) {
            float mx = fmaxf(fmaxf(S[i][0], S[i][1]), fmaxf(S[i][2], S[i][3]));
            mx = fmaxf(mx, __shfl_xor(mx, 1));
            mx = fmaxf(mx, __shfl_xor(mx, 2));
            mx = fmaxf(mx, __shfl_xor(mx, 4));
            mx = fmaxf(mx, __shfl_xor(mx, 8));
            float mnew = fmaxf(mrow[i], mx);
            float alpha = __expf(mrow[i] - mnew);
            float rs = 0.f;
#pragma unroll
            for (int j = 0; j < 4; ++j) { S[i][j] = __expf(S[i][j] - mnew); rs += S[i][j]; }
            rs += __shfl_xor(rs, 1);
            rs += __shfl_xor(rs, 2);
            rs += __shfl_xor(rs, 4);
            rs += __shfl_xor(rs, 8);
            lrow[i] = lrow[i] * alpha + rs;
            mrow[i] = mnew;
#pragma unroll
            for (int j = 0; j < 4; ++j) O[i][j] *= alpha;
        }

#pragma unroll
        for (int i = 0; i < 4; ++i) {
            float4 pv; pv.x = S[i][0]; pv.y = S[i][1]; pv.z = S[i][2]; pv.w = S[i][3];
            *(float4*)&ps[(ty << 2) + i][tx << 2] = pv;
        }
        __syncthreads();
#pragma unroll
        for (int k4 = 0; k4 < 16; ++k4) {
            float4 pa[4], va[4];
#pragma unroll
            for (int i = 0; i < 4; ++i)
                pa[i] = *(const float4*)&ps[(ty << 2) + i][k4 << 2];
#pragma unroll
            for (int j = 0; j < 4; ++j)
                va[j] = *(const float4*)&vs[(k4 << 2) + j][tx << 2];
#pragma unroll
            for (int i = 0; i < 4; ++i) {
                O[i][0] += pa[i].x * va[0].x + pa[i].y * va[1].x + pa[i].z * va[2].x + pa[i].w * va[3].x;
                O[i][1] += pa[i].x * va[0].y + pa[i].y * va[1].y + pa[i].z * va[2].y + pa[i].w * va[3].y;
                O[i][2] += pa[i].x * va[0].z + pa[i].y * va[1].z + pa[i].z * va[2].z + pa[i].w * va[3].z;
                O[i][3] += pa[i].x * va[0].w + pa[i].y * va[1].w + pa[i].z * va[2].w + pa[i].w * va[3].w;
            }
        }
    }

#pragma unroll
    for (int i = 0; i < 4; ++i) {
        float inv = 1.f / lrow[i];
        ushort4 uh, ul;
        split16(O[i][0] * inv, uh.x, ul.x);
        split16(O[i][1] * inv, uh.y, ul.y);
        split16(O[i][2] * inv, uh.z, ul.z);
        split16(O[i][3] * inv, uh.w, ul.w);
        long idx = (long)(qbase + (ty << 2) + i) * HID + h * HD + (tx << 2);
        *(ushort4*)&oh[idx] = uh;
        *(ushort4*)&ol[idx] = ul;
    }
}

// ---------------------------------------------------------------------------
// Transpose+convert (bf16, for logits W): Wt[n][k] = bf16(W[k][n]).
// ---------------------------------------------------------------------------
__global__ __launch_bounds__(256) void transp_kernel(
    const float* __restrict__ W, ushort* __restrict__ Wt, int K, int N)
{
    __shared__ float ts[32][33];
    int n0 = blockIdx.x * 32, k0 = blockIdx.y * 32;
    int tr = threadIdx.x >> 5, tc = threadIdx.x & 31;
#pragma unroll
    for (int j = 0; j < 4; ++j)
        ts[tr + j * 8][tc] = W[(long)(k0 + tr + j * 8) * N + n0 + tc];
    __syncthreads();
#pragma unroll
    for (int j = 0; j < 4; ++j) {
        int n = tr + j * 8;
        Wt[(long)(n0 + n) * K + k0 + tc] = f2b(ts[tc][n]);
    }
}

// ---------------------------------------------------------------------------
// bf16 MFMA GEMM (logits only). Padded-linear LDS [128][40] ushort.
// ---------------------------------------------------------------------------
__global__ __launch_bounds__(256) void mfma_gemm(
    const ushort* __restrict__ A, const ushort* __restrict__ Bt,
    float* __restrict__ Cf, int M, int N, int K)
{
    __shared__ ushort As[128 * 40];
    __shared__ ushort Bs[128 * 40];
    const int tid  = threadIdx.x;
    const int rb   = blockIdx.y * 128;
    const int cb   = blockIdx.x * 128;
    const int wave = tid >> 6, lane = tid & 63;
    const int wr   = (wave >> 1) * 64;
    const int wc   = (wave & 1) * 64;
    const int lr   = lane & 15;
    const int kh   = lane >> 4;

    const int srow = tid >> 1;
    const int kc0  = (tid & 1) * 2;
    const ushort* aptr = A + (long)(rb + srow) * K + kc0 * 8;
    const ushort* bptr = Bt + (long)(cb + srow) * K + kc0 * 8;
    const int woff0 = srow * 40 + kc0 * 8;
    const int woff1 = srow * 40 + (kc0 + 1) * 8;

    int aoff[4], boff[4];
#pragma unroll
    for (int m = 0; m < 4; ++m) aoff[m] = (wr + m * 16 + lr) * 40 + kh * 8;
#pragma unroll
    for (int n = 0; n < 4; ++n) boff[n] = (wc + n * 16 + lr) * 40 + kh * 8;

    f32x4 acc[4][4];
#pragma unroll
    for (int m = 0; m < 4; ++m)
#pragma unroll
        for (int n = 0; n < 4; ++n)
            acc[m][n] = (f32x4){0.f, 0.f, 0.f, 0.f};

    for (int k0 = 0; k0 < K; k0 += 32) {
        uint4 a0 = *(const uint4*)(aptr + k0);
        uint4 a1 = *(const uint4*)(aptr + k0 + 8);
        uint4 b0 = *(const uint4*)(bptr + k0);
        uint4 b1 = *(const uint4*)(bptr + k0 + 8);
        __syncthreads();
        *(uint4*)(As + woff0) = a0;
        *(uint4*)(As + woff1) = a1;
        *(uint4*)(Bs + woff0) = b0;
        *(uint4*)(Bs + woff1) = b1;
        __syncthreads();
        b16x8 af[4], bfr[4];
#pragma unroll
        for (int m = 0; m < 4; ++m) af[m] = *(const b16x8*)(As + aoff[m]);
#pragma unroll
        for (int n = 0; n < 4; ++n) bfr[n] = *(const b16x8*)(Bs + boff[n]);
#pragma unroll
        for (int m = 0; m < 4; ++m)
#pragma unroll
            for (int n = 0; n < 4; ++n)
                acc[m][n] = __builtin_amdgcn_mfma_f32_16x16x32_bf16(af[m], bfr[n], acc[m][n], 0, 0, 0);
    }

#pragma unroll
    for (int m = 0; m < 4; ++m) {
        int row0 = rb + wr + m * 16 + kh * 4;
#pragma unroll
        for (int n = 0; n < 4; ++n) {
            int col = cb + wc + n * 16 + lr;
#pragma unroll
            for (int r = 0; r < 4; ++r)
                Cf[(long)(row0 + r) * N + col] = acc[m][n][r];
        }
    }
}

// ---------------------------------------------------------------------------
// out = res[r'] + LN(t (+t2))*scale + bias.
// Outputs: f32 out, optional fp16 hi/lo split, optional bf16 mirror.
// ---------------------------------------------------------------------------
__global__ __launch_bounds__(256) void ln_res_kernel(
    const float* __restrict__ t, const float* __restrict__ t2,
    const float* __restrict__ res, float* __restrict__ out,
    ushort* __restrict__ outh, ushort* __restrict__ outl, ushort* __restrict__ outb,
    const float* __restrict__ bias, const float* __restrict__ scale, int res_map)
{
    int r = blockIdx.x;
    int tid = threadIdx.x;
    long rr = res_map ? (long)((r >> 9) * 1024 + 512 + (r & 511)) : (long)r;
    float4 v = ((const float4*)(t + (long)r * HID))[tid];
    if (t2) {
        float4 w = ((const float4*)(t2 + (long)r * HID))[tid];
        v.x += w.x; v.y += w.y; v.z += w.z; v.w += w.w;
    }
    __shared__ float red[4];
    float s = v.x + v.y + v.z + v.w;
    for (int off = 32; off > 0; off >>= 1) s += __shfl_xor(s, off);
    if ((tid & 63) == 0) red[tid >> 6] = s;
    __syncthreads();
    float mean = (red[0] + red[1] + red[2] + red[3]) * (1.f / HID);
    __syncthreads();
    float dx = v.x - mean, dy = v.y - mean, dz = v.z - mean, dw = v.w - mean;
    float qs = dx * dx + dy * dy + dz * dz + dw * dw;
    for (int off = 32; off > 0; off >>= 1) qs += __shfl_xor(qs, off);
    if ((tid & 63) == 0) red[tid >> 6] = qs;
    __syncthreads();
    float var = (red[0] + red[1] + red[2] + red[3]) * (1.f / HID);
    float rs = rsqrtf(var + 1e-6f);
    float4 rv = ((const float4*)(res + rr * HID))[tid];
    float4 sc4 = ((const float4*)scale)[tid];
    float4 b4  = ((const float4*)bias)[tid];
    float4 o4;
    o4.x = rv.x + dx * rs * sc4.x + b4.x;
    o4.y = rv.y + dy * rs * sc4.y + b4.y;
    o4.z = rv.z + dz * rs * sc4.z + b4.z;
    o4.w = rv.w + dw * rs * sc4.w + b4.w;
    ((float4*)(out + (long)r * HID))[tid] = o4;
    if (outh) {
        ushort4 uh, ul;
        split16(o4.x, uh.x, ul.x); split16(o4.y, uh.y, ul.y);
        split16(o4.z, uh.z, ul.z); split16(o4.w, uh.w, ul.w);
        ((ushort4*)(outh + (long)r * HID))[tid] = uh;
        ((ushort4*)(outl + (long)r * HID))[tid] = ul;
    }
    if (outb) {
        ushort4 u; u.x = f2b(o4.x); u.y = f2b(o4.y); u.z = f2b(o4.z); u.w = f2b(o4.w);
        ((ushort4*)(outb + (long)r * HID))[tid] = u;
    }
}

// ---------------------------------------------------------------------------
// Workspace (160 MiB total; 191.4 MB proven safe in R2):
//  [0,16M)    x_f        [16,24M) x_hi      [24,32M) x_lo
//  [32,48M)   kb_f  (-> ff1_hi after fattn)
//  [48,64M)   vb_f  (-> ff1_lo after fattn)
//  [64,72M)   qb_f
//  [72,76M)   o_hi (-> decb after l5 C-proj)   [76,80M) o_lo
//  [80,88M)   t0a (=h0)   [88,96M) t0b
//  [96,104M)  xs          [104,108M) xs_hi    [108,112M) xs_lo
//  [112,160M) weight splits: wq/wk/wv/wc hi+lo (2M each), wf1 hi/lo (8M each),
//             wf2 hi/lo (8M each)
//  wdect overlay [0,62.5M): post-loop only.
// ---------------------------------------------------------------------------
extern "C" void kernel_launch(void* const* d_in, const int* in_sizes, int n_in,
                              void* d_out, int out_size, void* d_ws, size_t ws_size,
                              hipStream_t stream)
{
    const int*   x_input = (const int*)  d_in[0];
    const float* prev    = (const float*)d_in[1];
    const float* Wemb    = (const float*)d_in[2];
    const float* Wlin    = (const float*)d_in[3];
    const float* pdec    = (const float*)d_in[4];
    const float* pq      = (const float*)d_in[5];
    const float* pk      = (const float*)d_in[6];
    const float* pv      = (const float*)d_in[7];
    const float* pc      = (const float*)d_in[8];
    const float* pf1     = (const float*)d_in[9];
    const float* pf2     = (const float*)d_in[10];
    const float* bf1     = (const float*)d_in[11];
    const float* bf2     = (const float*)d_in[12];
    const float* b1      = (const float*)d_in[13];
    const float* b2      = (const float*)d_in[14];
    const float* s1      = (const float*)d_in[15];
    const float* s2      = (const float*)d_in[16];
    const float* pos     = (const float*)d_in[17];

    float* outp   = (float*)d_out;
    float* logits = outp;
    float* dec    = outp + (long)2048 * VOC;

    char* base = (char*)d_ws;
    float*  x_f   = (float*) (base + 0);
    ushort* x_hi  = (ushort*)(base + 16777216);
    ushort* x_lo  = (ushort*)(base + 25165824);
    float*  kb_f  = (float*) (base + 33554432);
    float*  vb_f  = (float*) (base + 50331648);
    float*  qb_f  = (float*) (base + 67108864);
    ushort* o_hi  = (ushort*)(base + 75497472);
    ushort* o_lo  = (ushort*)(base + 79691776);
    float*  t0a   = (float*) (base + 83886080);
    float*  h0    = t0a;
    float*  t0b   = (float*) (base + 92274688);
    float*  xs    = (float*) (base + 100663296);
    ushort* xs_hi = (ushort*)(base + 109051904);
    ushort* xs_lo = (ushort*)(base + 113246208);
    ushort* wq_hi = (ushort*)(base + 117440512);
    ushort* wq_lo = (ushort*)(base + 119537664);
    ushort* wk_hi = (ushort*)(base + 121634816);
    ushort* wk_lo = (ushort*)(base + 123731968);
    ushort* wv_hi = (ushort*)(base + 125829120);
    ushort* wv_lo = (ushort*)(base + 127926272);
    ushort* wc_hi = (ushort*)(base + 130023424);
    ushort* wc_lo = (ushort*)(base + 132120576);
    ushort* wf1_hi= (ushort*)(base + 134217728);
    ushort* wf1_lo= (ushort*)(base + 142606336);
    ushort* wf2_hi= (ushort*)(base + 150994944);
    ushort* wf2_lo= (ushort*)(base + 159383552);   // ends 167,772,160
    // overlays
    ushort* ff1_hi= (ushort*)(base + 33554432);    // kb_f region, post-fattn
    ushort* ff1_lo= (ushort*)(base + 50331648);    // vb_f region, post-fattn
    ushort* decb  = (ushort*)(base + 75497472);    // o_hi region, l5 ln2
    ushort* wdect = (ushort*)(base + 0);           // post-loop overlay

    embed_kernel<<<NB * WINN, 256, 0, stream>>>(x_input, Wemb, Wlin, h0);

    for (int l = 0; l < NL; ++l) {
        const float* cur = (l == 0) ? h0 : (dec + (long)(l - 1) * 2097152);
        build_x_kernel<<<(NB * TT * HID / 4) / 256, 256, 0, stream>>>(
            pos + (long)l * TT * HID, prev + (long)l * NB * WINN * HID, cur,
            x_f, x_hi, x_lo);

        wsplit_kernel<<<dim3(32, 32), 256, 0, stream>>>(pq + (long)l * HID * HID, wq_hi, wq_lo, HID, HID);
        wsplit_kernel<<<dim3(32, 32), 256, 0, stream>>>(pk + (long)l * HID * HID, wk_hi, wk_lo, HID, HID);
        wsplit_kernel<<<dim3(32, 32), 256, 0, stream>>>(pv + (long)l * HID * HID, wv_hi, wv_lo, HID, HID);
        wsplit_kernel<<<dim3(32, 32), 256, 0, stream>>>(pc + (long)l * HID * HID, wc_hi, wc_lo, HID, HID);
        wsplit_kernel<<<dim3(FFW / 32, HID / 32), 256, 0, stream>>>(
            pf1 + (long)l * HID * FFW, wf1_hi, wf1_lo, HID, FFW);
        wsplit_kernel<<<dim3(HID / 32, FFW / 32), 256, 0, stream>>>(
            pf2 + (long)l * FFW * HID, wf2_hi, wf2_lo, FFW, HID);

        hgemm<<<dim3(HID / 64, (NB * TT) / 128), 256, 0, stream>>>(
            x_hi, x_lo, wk_hi, wk_lo, kb_f, nullptr, nullptr,
            NB * TT, HID, HID, 0, HID, 1.f, nullptr, 0, 0);
        hgemm<<<dim3(HID / 64, (NB * TT) / 128), 256, 0, stream>>>(
            x_hi, x_lo, wv_hi, wv_lo, vb_f, nullptr, nullptr,
            NB * TT, HID, HID, 0, HID, 1.f, nullptr, 0, 0);
        hgemm<<<dim3(HID / 64, (NB * WINN) / 128), 256, 0, stream>>>(
            x_hi, x_lo, wq_hi, wq_lo, qb_f, nullptr, nullptr,
            NB * WINN, HID, HID, 0, HID, 0.125f, nullptr, 0, 1);

        fattn_kernel<<<dim3(WINN / 64, NH, NB), 256, 0, stream>>>(
            qb_f, kb_f, vb_f, o_hi, o_lo);

        hgemm<<<dim3(HID / 64, (NB * WINN) / 128), 256, 0, stream>>>(
            o_hi, o_lo, wc_hi, wc_lo, t0a, nullptr, nullptr,
            NB * WINN, HID, HID, 0, HID, 1.f, nullptr, 0, 0);
        ln_res_kernel<<<NB * WINN, 256, 0, stream>>>(
            t0a, nullptr, x_f, xs, xs_hi, xs_lo, nullptr,
            b1 + l * HID, s1 + l * HID, 1);

        hgemm<<<dim3(FFW / 64, (NB * WINN) / 128), 256, 0, stream>>>(
            xs_hi, xs_lo, wf1_hi, wf1_lo, nullptr, ff1_hi, ff1_lo,
            NB * WINN, FFW, HID, 0, HID, 1.f, bf1 + l * FFW, 1, 0);
        hgemm<<<dim3(HID / 64, (NB * WINN) / 128), 256, 0, stream>>>(
            ff1_hi, ff1_lo, wf2_hi, wf2_lo, t0a, nullptr, nullptr,
            NB * WINN, HID, FFW, 0, FFW / 2, 1.f, bf2 + l * HID, 0, 0);
        hgemm<<<dim3(HID / 64, (NB * WINN) / 128), 256, 0, stream>>>(
            ff1_hi, ff1_lo, wf2_hi, wf2_lo, t0b, nullptr, nullptr,
            NB * WINN, HID, FFW, FFW / 2, FFW / 2, 1.f, nullptr, 0, 0);
        ln_res_kernel<<<NB * WINN, 256, 0, stream>>>(
            t0a, t0b, xs, dec + (long)l * 2097152, nullptr, nullptr,
            (l == NL - 1) ? decb : nullptr, b2 + l * HID, s2 + l * HID, 0);
    }

    transp_kernel<<<dim3(VOC / 32, HID / 32), 256, 0, stream>>>(pdec, wdect, HID, VOC);
    mfma_gemm<<<dim3(VOC / 128, (NB * WINN) / 128), 256, 0, stream>>>(
        decb, wdect, logits, NB * WINN, VOC, HID);
}

// Round 8
// 3382.981 us; speedup vs baseline: 3.6586x; 1.2412x over previous
//
#include <hip/hip_runtime.h>
#include <hip/hip_bf16.h>

#define NL   6
#define NH   16
#define HID  1024
#define HD   64
#define FFW  4096
#define VOC  32000
#define WINN 512
#define EMB  128
#define NB   4
#define TT   1024   // WIN + WIN

typedef __attribute__((ext_vector_type(8))) _Float16 f16x8;
typedef __attribute__((ext_vector_type(8))) short    b16x8;
typedef __attribute__((ext_vector_type(4))) float    f32x4;

__device__ __forceinline__ ushort f2b(float f) {
    __hip_bfloat16 h = __float2bfloat16(f);
    return *reinterpret_cast<ushort*>(&h);
}
// split f32 into fp16 hi/lo:  f ~= hi + lo * 2^-11  (error ~ |f|*2^-22)
__device__ __forceinline__ void split16(float f, ushort& hb, ushort& lb) {
    _Float16 h = (_Float16)f;
    _Float16 l = (_Float16)((f - (float)h) * 2048.0f);
    hb = __builtin_bit_cast(ushort, h);
    lb = __builtin_bit_cast(ushort, l);
}

// ---------------------------------------------------------------------------
// Embed (f32)
// ---------------------------------------------------------------------------
__global__ __launch_bounds__(256) void embed_kernel(
    const int* __restrict__ xin, const float* __restrict__ Wemb,
    const float* __restrict__ Wlin, float* __restrict__ h0)
{
    int row = blockIdx.x;
    int tok = xin[row];
    __shared__ float tk[EMB];
    if (threadIdx.x < EMB) tk[threadIdx.x] = Wemb[tok * EMB + threadIdx.x] * 0.03125f;
    __syncthreads();
    for (int j = 0; j < 4; ++j) {
        int c = threadIdx.x + 256 * j;
        float acc = 0.f;
        for (int e = 0; e < EMB; ++e) acc += tk[e] * Wlin[e * HID + c];
        h0[(long)row * HID + c] = acc;
    }
}

// ---------------------------------------------------------------------------
// x = pos + concat(prev, cur); outputs f32 + fp16 hi/lo split
// ---------------------------------------------------------------------------
__global__ __launch_bounds__(256) void build_x_kernel(
    const float* __restrict__ pos, const float* __restrict__ prev,
    const float* __restrict__ cur, float* __restrict__ x,
    ushort* __restrict__ xh, ushort* __restrict__ xl)
{
    int i4 = blockIdx.x * blockDim.x + threadIdx.x;
    if (i4 >= NB * TT * HID / 4) return;
    int h4 = i4 % (HID / 4);
    int bt = i4 / (HID / 4);
    int t = bt % TT, b = bt / TT;
    float4 p = ((const float4*)pos)[t * (HID / 4) + h4];
    float4 s;
    if (t < WINN) s = ((const float4*)prev)[(long)(b * WINN + t) * (HID / 4) + h4];
    else          s = ((const float4*)cur)[(long)(b * WINN + (t - WINN)) * (HID / 4) + h4];
    float4 r; r.x = p.x + s.x; r.y = p.y + s.y; r.z = p.z + s.z; r.w = p.w + s.w;
    ((float4*)x)[i4] = r;
    ushort4 uh, ul;
    split16(r.x, uh.x, ul.x); split16(r.y, uh.y, ul.y);
    split16(r.z, uh.z, ul.z); split16(r.w, uh.w, ul.w);
    ((ushort4*)xh)[i4] = uh;
    ((ushort4*)xl)[i4] = ul;
}

// ---------------------------------------------------------------------------
// Weight transpose + fp16 split: W f32 [K,N] -> Wt_hi/Wt_lo fp16 [N,K]
// ---------------------------------------------------------------------------
__global__ __launch_bounds__(256) void wsplit_kernel(
    const float* __restrict__ W, ushort* __restrict__ Wth, ushort* __restrict__ Wtl,
    int K, int N)
{
    __shared__ float ts[32][33];
    int n0 = blockIdx.x * 32, k0 = blockIdx.y * 32;
    int tr = threadIdx.x >> 5, tc = threadIdx.x & 31;
#pragma unroll
    for (int j = 0; j < 4; ++j)
        ts[tr + j * 8][tc] = W[(long)(k0 + tr + j * 8) * N + n0 + tc];
    __syncthreads();
#pragma unroll
    for (int j = 0; j < 4; ++j) {
        int n = tr + j * 8;
        ushort hb, lb;
        split16(ts[tc][n], hb, lb);
        long idx = (long)(n0 + n) * K + k0 + tc;
        Wth[idx] = hb;
        Wtl[idx] = lb;
    }
}

// ---------------------------------------------------------------------------
// ushort-pair transpose: v [4096,1024] -> vt [1024,4096] (hi and lo arrays)
// ---------------------------------------------------------------------------
__global__ __launch_bounds__(256) void vtrans_kernel(
    const ushort* __restrict__ vh, const ushort* __restrict__ vl,
    ushort* __restrict__ vth, ushort* __restrict__ vtl)
{
    __shared__ ushort th[32][33], tl[32][33];
    int n0 = blockIdx.x * 32, r0 = blockIdx.y * 32;
    int tr = threadIdx.x >> 5, tc = threadIdx.x & 31;
#pragma unroll
    for (int j = 0; j < 4; ++j) {
        long g = (long)(r0 + tr + j * 8) * HID + n0 + tc;
        th[tr + j * 8][tc] = vh[g];
        tl[tr + j * 8][tc] = vl[g];
    }
    __syncthreads();
#pragma unroll
    for (int j = 0; j < 4; ++j) {
        long g = (long)(n0 + tr + j * 8) * (NB * TT) + r0 + tc;
        vth[g] = th[tc][tr + j * 8];
        vtl[g] = tl[tc][tr + j * 8];
    }
}

// ---------------------------------------------------------------------------
// Split-fp16 MFMA GEMM ("Markidis"): C = act(scale*(A@B) + bias).
// Tile 128x64, 4 waves, BK=32. Outputs: Cf f32 and/or (Chh,Cll) fp16 split.
// ---------------------------------------------------------------------------
__global__ __launch_bounds__(256) void hgemm(
    const ushort* __restrict__ Ah, const ushort* __restrict__ Al,
    const ushort* __restrict__ Bh, const ushort* __restrict__ Bl,
    float* __restrict__ Cf, ushort* __restrict__ Chh, ushort* __restrict__ Cll,
    int M, int N, int K_stride, int k_off, int Ksub,
    float scale, const float* __restrict__ bias, int relu, int amap)
{
    __shared__ ushort Ash[128 * 40];
    __shared__ ushort Asl[128 * 40];
    __shared__ ushort Bsh[64 * 40];
    __shared__ ushort Bsl[64 * 40];
    const int tid  = threadIdx.x;
    const int rb   = blockIdx.y * 128;
    const int cb   = blockIdx.x * 64;
    const int wave = tid >> 6, lane = tid & 63;
    const int wr   = (wave >> 1) * 64;
    const int wc   = (wave & 1) * 32;
    const int lr   = lane & 15;
    const int kh   = lane >> 4;

    const int sar = tid >> 1;
    const int sak = (tid & 1) * 16;
    int gra = rb + sar;
    long marow = amap ? (long)((gra >> 9) * 1024 + 512 + (gra & 511)) : (long)gra;
    const ushort* pAh = Ah + marow * K_stride + k_off + sak;
    const ushort* pAl = Al + marow * K_stride + k_off + sak;
    const int wA0 = sar * 40 + sak, wA1 = wA0 + 8;
    const int sbr = tid >> 2;
    const int sbk = (tid & 3) * 8;
    const ushort* pBh = Bh + (long)(cb + sbr) * K_stride + k_off + sbk;
    const ushort* pBl = Bl + (long)(cb + sbr) * K_stride + k_off + sbk;
    const int wB0 = sbr * 40 + sbk;

    int aoff[4], boff[2];
#pragma unroll
    for (int m = 0; m < 4; ++m) aoff[m] = (wr + m * 16 + lr) * 40 + kh * 8;
#pragma unroll
    for (int n = 0; n < 2; ++n) boff[n] = (wc + n * 16 + lr) * 40 + kh * 8;

    f32x4 accH[4][2], accL[4][2];
#pragma unroll
    for (int m = 0; m < 4; ++m)
#pragma unroll
        for (int n = 0; n < 2; ++n) {
            accH[m][n] = (f32x4){0.f, 0.f, 0.f, 0.f};
            accL[m][n] = (f32x4){0.f, 0.f, 0.f, 0.f};
        }

    for (int k0 = 0; k0 < Ksub; k0 += 32) {
        uint4 ah0 = *(const uint4*)(pAh + k0);
        uint4 ah1 = *(const uint4*)(pAh + k0 + 8);
        uint4 al0 = *(const uint4*)(pAl + k0);
        uint4 al1 = *(const uint4*)(pAl + k0 + 8);
        uint4 bh0 = *(const uint4*)(pBh + k0);
        uint4 bl0 = *(const uint4*)(pBl + k0);
        __syncthreads();
        *(uint4*)(Ash + wA0) = ah0; *(uint4*)(Ash + wA1) = ah1;
        *(uint4*)(Asl + wA0) = al0; *(uint4*)(Asl + wA1) = al1;
        *(uint4*)(Bsh + wB0) = bh0;
        *(uint4*)(Bsl + wB0) = bl0;
        __syncthreads();
        f16x8 afh[4], afl[4], bfh[2], bfl[2];
#pragma unroll
        for (int m = 0; m < 4; ++m) {
            afh[m] = *(const f16x8*)(Ash + aoff[m]);
            afl[m] = *(const f16x8*)(Asl + aoff[m]);
        }
#pragma unroll
        for (int n = 0; n < 2; ++n) {
            bfh[n] = *(const f16x8*)(Bsh + boff[n]);
            bfl[n] = *(const f16x8*)(Bsl + boff[n]);
        }
#pragma unroll
        for (int m = 0; m < 4; ++m)
#pragma unroll
            for (int n = 0; n < 2; ++n) {
                accH[m][n] = __builtin_amdgcn_mfma_f32_16x16x32_f16(afh[m], bfh[n], accH[m][n], 0, 0, 0);
                accL[m][n] = __builtin_amdgcn_mfma_f32_16x16x32_f16(afh[m], bfl[n], accL[m][n], 0, 0, 0);
                accL[m][n] = __builtin_amdgcn_mfma_f32_16x16x32_f16(afl[m], bfh[n], accL[m][n], 0, 0, 0);
            }
    }

#pragma unroll
    for (int m = 0; m < 4; ++m) {
        int row0 = rb + wr + m * 16 + kh * 4;
#pragma unroll
        for (int n = 0; n < 2; ++n) {
            int col = cb + wc + n * 16 + lr;
            float bv = bias ? bias[col] : 0.f;
#pragma unroll
            for (int r = 0; r < 4; ++r) {
                float v = (accH[m][n][r] + accL[m][n][r] * (1.f / 2048.f)) * scale + bv;
                if (relu) v = fmaxf(v, 0.f);
                long idx = (long)(row0 + r) * N + col;
                if (Cf) Cf[idx] = v;
                if (Chh) { ushort hb, lb; split16(v, hb, lb); Chh[idx] = hb; Cll[idx] = lb; }
            }
        }
    }
}

// ---------------------------------------------------------------------------
// MFMA flash attention, split-fp16 Q/K/V/P, f32 online softmax.
// Block = (qt, h, b): 64 q-rows, 4 waves x 16 rows. K tile + V^T tile in LDS
// (stride 72 ushorts = 144B, 16B-aligned rows); P overlays the K tile.
// q is pre-scaled by 0.125 at projection. Causal: qi = 512 + qt*64 + row.
// ---------------------------------------------------------------------------
__global__ __launch_bounds__(256) void fattn_mfma(
    const ushort* __restrict__ qh, const ushort* __restrict__ ql,
    const ushort* __restrict__ kbh, const ushort* __restrict__ kbl,
    const ushort* __restrict__ vth, const ushort* __restrict__ vtl,
    ushort* __restrict__ oh, ushort* __restrict__ ol)
{
    __shared__ __align__(16) ushort ksh[64 * 72];   // K tile / P_hi overlay
    __shared__ __align__(16) ushort ksl[64 * 72];   // K tile lo / P_lo overlay
    __shared__ __align__(16) ushort vsh[64 * 72];   // V^T tile hi  [d][krow]
    __shared__ __align__(16) ushort vsl[64 * 72];   // V^T tile lo
    const int qt = blockIdx.x, h = blockIdx.y, b = blockIdx.z;
    const int tid = threadIdx.x;
    const int wave = tid >> 6, lane = tid & 63;
    const int lr = lane & 15, kg4 = lane >> 4;
    const int qbase = b * WINN + qt * 64;

    // Q A-frags (row = lane&15, k-chunk = (lane>>4)*8), K-dim 64 -> 2 chunks
    f16x8 qfh[2], qfl[2];
#pragma unroll
    for (int c = 0; c < 2; ++c) {
        long ga = (long)(qbase + wave * 16 + lr) * HID + h * HD + c * 32 + kg4 * 8;
        qfh[c] = *(const f16x8*)(qh + ga);
        qfl[c] = *(const f16x8*)(ql + ga);
    }

    f32x4 accOH[4], accOL[4];
#pragma unroll
    for (int d = 0; d < 4; ++d) {
        accOH[d] = (f32x4){0.f, 0.f, 0.f, 0.f};
        accOL[d] = (f32x4){0.f, 0.f, 0.f, 0.f};
    }
    float mrow[4], lrow[4];
#pragma unroll
    for (int r = 0; r < 4; ++r) { mrow[r] = -3.0e38f; lrow[r] = 0.f; }

    const int sr = tid >> 2;          // staging row 0..63
    const int sd = (tid & 3) * 16;    // staging col chunk

    const int ktmax = 9 + qt;
    for (int kt = 0; kt < ktmax; ++kt) {
        __syncthreads();   // prev iteration's PV reads complete
        {
            long gk = (long)(b * TT + kt * 64 + sr) * HID + h * HD + sd;
            uint4 h0 = *(const uint4*)(kbh + gk);
            uint4 h1 = *(const uint4*)(kbh + gk + 8);
            uint4 l0 = *(const uint4*)(kbl + gk);
            uint4 l1 = *(const uint4*)(kbl + gk + 8);
            long gv = (long)(h * HD + sr) * (NB * TT) + b * TT + kt * 64 + sd;
            uint4 vh0 = *(const uint4*)(vth + gv);
            uint4 vh1 = *(const uint4*)(vth + gv + 8);
            uint4 vl0 = *(const uint4*)(vtl + gv);
            uint4 vl1 = *(const uint4*)(vtl + gv + 8);
            *(uint4*)(ksh + sr * 72 + sd) = h0;
            *(uint4*)(ksh + sr * 72 + sd + 8) = h1;
            *(uint4*)(ksl + sr * 72 + sd) = l0;
            *(uint4*)(ksl + sr * 72 + sd + 8) = l1;
            *(uint4*)(vsh + sr * 72 + sd) = vh0;
            *(uint4*)(vsh + sr * 72 + sd + 8) = vh1;
            *(uint4*)(vsl + sr * 72 + sd) = vl0;
            *(uint4*)(vsl + sr * 72 + sd + 8) = vl1;
        }
        __syncthreads();

        // S = Q @ K^T : per wave 16x64, 4 n-frags
        f32x4 sH[4], sL[4];
#pragma unroll
        for (int n = 0; n < 4; ++n) {
            sH[n] = (f32x4){0.f, 0.f, 0.f, 0.f};
            sL[n] = (f32x4){0.f, 0.f, 0.f, 0.f};
        }
#pragma unroll
        for (int c = 0; c < 2; ++c) {
#pragma unroll
            for (int n = 0; n < 4; ++n) {
                int ad = (n * 16 + lr) * 72 + c * 32 + kg4 * 8;
                f16x8 bh = *(const f16x8*)(ksh + ad);
                f16x8 bl = *(const f16x8*)(ksl + ad);
                sH[n] = __builtin_amdgcn_mfma_f32_16x16x32_f16(qfh[c], bh, sH[n], 0, 0, 0);
                sL[n] = __builtin_amdgcn_mfma_f32_16x16x32_f16(qfh[c], bl, sL[n], 0, 0, 0);
                sL[n] = __builtin_amdgcn_mfma_f32_16x16x32_f16(qfl[c], bh, sL[n], 0, 0, 0);
            }
        }
        float S[4][4];   // [n][reg]
#pragma unroll
        for (int n = 0; n < 4; ++n)
#pragma unroll
            for (int r = 0; r < 4; ++r)
                S[n][r] = sH[n][r] + sL[n][r] * (1.f / 2048.f);

        if (kt == ktmax - 1) {   // diagonal tile causal mask
#pragma unroll
            for (int r = 0; r < 4; ++r) {
                int qi = WINN + qt * 64 + wave * 16 + kg4 * 4 + r;
#pragma unroll
                for (int n = 0; n < 4; ++n) {
                    int kg = kt * 64 + n * 16 + lr;
                    if (kg > qi) S[n][r] = -1e9f;
                }
            }
        }

        // online softmax (row = kg4*4 + r; reduce across lane bits 0..3)
#pragma unroll
        for (int r = 0; r < 4; ++r) {
            float mx = fmaxf(fmaxf(S[0][r], S[1][r]), fmaxf(S[2][r], S[3][r]));
            mx = fmaxf(mx, __shfl_xor(mx, 1));
            mx = fmaxf(mx, __shfl_xor(mx, 2));
            mx = fmaxf(mx, __shfl_xor(mx, 4));
            mx = fmaxf(mx, __shfl_xor(mx, 8));
            float mnew = fmaxf(mrow[r], mx);
            float alpha = __expf(mrow[r] - mnew);
            float rs = 0.f;
#pragma unroll
            for (int n = 0; n < 4; ++n) { S[n][r] = __expf(S[n][r] - mnew); rs += S[n][r]; }
            rs += __shfl_xor(rs, 1);
            rs += __shfl_xor(rs, 2);
            rs += __shfl_xor(rs, 4);
            rs += __shfl_xor(rs, 8);
            lrow[r] = lrow[r] * alpha + rs;
            mrow[r] = mnew;
#pragma unroll
            for (int d = 0; d < 4; ++d) { accOH[d][r] *= alpha; accOL[d][r] *= alpha; }
        }

        __syncthreads();   // all waves done reading ksh/ksl as K
        // P (split) -> overlay K tile; wave writes only its own 16 rows
#pragma unroll
        for (int n = 0; n < 4; ++n)
#pragma unroll
            for (int r = 0; r < 4; ++r) {
                ushort hb, lb;
                split16(S[n][r], hb, lb);
                int ad = (wave * 16 + kg4 * 4 + r) * 72 + n * 16 + lr;
                ksh[ad] = hb;
                ksl[ad] = lb;
            }
        // PV: A = P (own rows; same-wave write->read, DS in-order), B = V^T
        f16x8 pfh[2], pfl[2];
#pragma unroll
        for (int c = 0; c < 2; ++c) {
            int ad = (wave * 16 + lr) * 72 + c * 32 + kg4 * 8;
            pfh[c] = *(const f16x8*)(ksh + ad);
            pfl[c] = *(const f16x8*)(ksl + ad);
        }
#pragma unroll
        for (int c = 0; c < 2; ++c) {
#pragma unroll
            for (int d = 0; d < 4; ++d) {
                int ad = (d * 16 + lr) * 72 + c * 32 + kg4 * 8;
                f16x8 vh = *(const f16x8*)(vsh + ad);
                f16x8 vl = *(const f16x8*)(vsl + ad);
                accOH[d] = __builtin_amdgcn_mfma_f32_16x16x32_f16(pfh[c], vh, accOH[d], 0, 0, 0);
                accOL[d] = __builtin_amdgcn_mfma_f32_16x16x32_f16(pfh[c], vl, accOL[d], 0, 0, 0);
                accOL[d] = __builtin_amdgcn_mfma_f32_16x16x32_f16(pfl[c], vh, accOL[d], 0, 0, 0);
            }
        }
    }

    // epilogue: O row = kg4*4 + r, col = d*16 + lr
#pragma unroll
    for (int r = 0; r < 4; ++r) {
        float inv = 1.f / lrow[r];
        long rowb = (long)(qbase + wave * 16 + kg4 * 4 + r) * HID + h * HD + lr;
#pragma unroll
        for (int d = 0; d < 4; ++d) {
            float v = (accOH[d][r] + accOL[d][r] * (1.f / 2048.f)) * inv;
            ushort hb, lb;
            split16(v, hb, lb);
            oh[rowb + d * 16] = hb;
            ol[rowb + d * 16] = lb;
        }
    }
}

// ---------------------------------------------------------------------------
// Transpose+convert (bf16, logits W)
// ---------------------------------------------------------------------------
__global__ __launch_bounds__(256) void transp_kernel(
    const float* __restrict__ W, ushort* __restrict__ Wt, int K, int N)
{
    __shared__ float ts[32][33];
    int n0 = blockIdx.x * 32, k0 = blockIdx.y * 32;
    int tr = threadIdx.x >> 5, tc = threadIdx.x & 31;
#pragma unroll
    for (int j = 0; j < 4; ++j)
        ts[tr + j * 8][tc] = W[(long)(k0 + tr + j * 8) * N + n0 + tc];
    __syncthreads();
#pragma unroll
    for (int j = 0; j < 4; ++j) {
        int n = tr + j * 8;
        Wt[(long)(n0 + n) * K + k0 + tc] = f2b(ts[tc][n]);
    }
}

// ---------------------------------------------------------------------------
// bf16 MFMA GEMM (logits only)
// ---------------------------------------------------------------------------
__global__ __launch_bounds__(256) void mfma_gemm(
    const ushort* __restrict__ A, const ushort* __restrict__ Bt,
    float* __restrict__ Cf, int M, int N, int K)
{
    __shared__ ushort As[128 * 40];
    __shared__ ushort Bs[128 * 40];
    const int tid  = threadIdx.x;
    const int rb   = blockIdx.y * 128;
    const int cb   = blockIdx.x * 128;
    const int wave = tid >> 6, lane = tid & 63;
    const int wr   = (wave >> 1) * 64;
    const int wc   = (wave & 1) * 64;
    const int lr   = lane & 15;
    const int kh   = lane >> 4;

    const int srow = tid >> 1;
    const int kc0  = (tid & 1) * 2;
    const ushort* aptr = A + (long)(rb + srow) * K + kc0 * 8;
    const ushort* bptr = Bt + (long)(cb + srow) * K + kc0 * 8;
    const int woff0 = srow * 40 + kc0 * 8;
    const int woff1 = srow * 40 + (kc0 + 1) * 8;

    int aoff[4], boff[4];
#pragma unroll
    for (int m = 0; m < 4; ++m) aoff[m] = (wr + m * 16 + lr) * 40 + kh * 8;
#pragma unroll
    for (int n = 0; n < 4; ++n) boff[n] = (wc + n * 16 + lr) * 40 + kh * 8;

    f32x4 acc[4][4];
#pragma unroll
    for (int m = 0; m < 4; ++m)
#pragma unroll
        for (int n = 0; n < 4; ++n)
            acc[m][n] = (f32x4){0.f, 0.f, 0.f, 0.f};

    for (int k0 = 0; k0 < K; k0 += 32) {
        uint4 a0 = *(const uint4*)(aptr + k0);
        uint4 a1 = *(const uint4*)(aptr + k0 + 8);
        uint4 b0 = *(const uint4*)(bptr + k0);
        uint4 b1 = *(const uint4*)(bptr + k0 + 8);
        __syncthreads();
        *(uint4*)(As + woff0) = a0;
        *(uint4*)(As + woff1) = a1;
        *(uint4*)(Bs + woff0) = b0;
        *(uint4*)(Bs + woff1) = b1;
        __syncthreads();
        b16x8 af[4], bfr[4];
#pragma unroll
        for (int m = 0; m < 4; ++m) af[m] = *(const b16x8*)(As + aoff[m]);
#pragma unroll
        for (int n = 0; n < 4; ++n) bfr[n] = *(const b16x8*)(Bs + boff[n]);
#pragma unroll
        for (int m = 0; m < 4; ++m)
#pragma unroll
            for (int n = 0; n < 4; ++n)
                acc[m][n] = __builtin_amdgcn_mfma_f32_16x16x32_bf16(af[m], bfr[n], acc[m][n], 0, 0, 0);
    }

#pragma unroll
    for (int m = 0; m < 4; ++m) {
        int row0 = rb + wr + m * 16 + kh * 4;
#pragma unroll
        for (int n = 0; n < 4; ++n) {
            int col = cb + wc + n * 16 + lr;
#pragma unroll
            for (int r = 0; r < 4; ++r)
                Cf[(long)(row0 + r) * N + col] = acc[m][n][r];
        }
    }
}

// ---------------------------------------------------------------------------
// out = res[r'] + LN(t (+t2))*scale + bias; outputs f32 / fp16-split / bf16
// ---------------------------------------------------------------------------
__global__ __launch_bounds__(256) void ln_res_kernel(
    const float* __restrict__ t, const float* __restrict__ t2,
    const float* __restrict__ res, float* __restrict__ out,
    ushort* __restrict__ outh, ushort* __restrict__ outl, ushort* __restrict__ outb,
    const float* __restrict__ bias, const float* __restrict__ scale, int res_map)
{
    int r = blockIdx.x;
    int tid = threadIdx.x;
    long rr = res_map ? (long)((r >> 9) * 1024 + 512 + (r & 511)) : (long)r;
    float4 v = ((const float4*)(t + (long)r * HID))[tid];
    if (t2) {
        float4 w = ((const float4*)(t2 + (long)r * HID))[tid];
        v.x += w.x; v.y += w.y; v.z += w.z; v.w += w.w;
    }
    __shared__ float red[4];
    float s = v.x + v.y + v.z + v.w;
    for (int off = 32; off > 0; off >>= 1) s += __shfl_xor(s, off);
    if ((tid & 63) == 0) red[tid >> 6] = s;
    __syncthreads();
    float mean = (red[0] + red[1] + red[2] + red[3]) * (1.f / HID);
    __syncthreads();
    float dx = v.x - mean, dy = v.y - mean, dz = v.z - mean, dw = v.w - mean;
    float qs = dx * dx + dy * dy + dz * dz + dw * dw;
    for (int off = 32; off > 0; off >>= 1) qs += __shfl_xor(qs, off);
    if ((tid & 63) == 0) red[tid >> 6] = qs;
    __syncthreads();
    float var = (red[0] + red[1] + red[2] + red[3]) * (1.f / HID);
    float rs = rsqrtf(var + 1e-6f);
    float4 rv = ((const float4*)(res + rr * HID))[tid];
    float4 sc4 = ((const float4*)scale)[tid];
    float4 b4  = ((const float4*)bias)[tid];
    float4 o4;
    o4.x = rv.x + dx * rs * sc4.x + b4.x;
    o4.y = rv.y + dy * rs * sc4.y + b4.y;
    o4.z = rv.z + dz * rs * sc4.z + b4.z;
    o4.w = rv.w + dw * rs * sc4.w + b4.w;
    ((float4*)(out + (long)r * HID))[tid] = o4;
    if (outh) {
        ushort4 uh, ul;
        split16(o4.x, uh.x, ul.x); split16(o4.y, uh.y, ul.y);
        split16(o4.z, uh.z, ul.z); split16(o4.w, uh.w, ul.w);
        ((ushort4*)(outh + (long)r * HID))[tid] = uh;
        ((ushort4*)(outl + (long)r * HID))[tid] = ul;
    }
    if (outb) {
        ushort4 u; u.x = f2b(o4.x); u.y = f2b(o4.y); u.z = f2b(o4.z); u.w = f2b(o4.w);
        ((ushort4*)(outb + (long)r * HID))[tid] = u;
    }
}

// ---------------------------------------------------------------------------
// Workspace (max 184,549,376 B; 191.4 MB proven written in R2):
//  [0,16M) x_f  [16,24M) x_hi [24,32M) x_lo
//  [32,40M) k_hi [40,48M) k_lo   (-> ff1_hi overlay post-fattn)
//  [48,56M) v_hi [56,64M) v_lo   (-> ff1_lo overlay post-fattn)
//  [64,72M) vt_hi [72,80M) vt_lo
//  [80,84M) q_hi [84,88M) q_lo
//  [88,92M) o_hi (-> decb at l5) [92,96M) o_lo
//  [96,104M) t0a(=h0) [104,112M) t0b
//  [112,120M) xs [120,124M) xs_hi [124,128M) xs_lo
//  [128M..176M) weight splits
//  wdect overlay [0,62.5M) post-loop.
// ---------------------------------------------------------------------------
extern "C" void kernel_launch(void* const* d_in, const int* in_sizes, int n_in,
                              void* d_out, int out_size, void* d_ws, size_t ws_size,
                              hipStream_t stream)
{
    const int*   x_input = (const int*)  d_in[0];
    const float* prev    = (const float*)d_in[1];
    const float* Wemb    = (const float*)d_in[2];
    const float* Wlin    = (const float*)d_in[3];
    const float* pdec    = (const float*)d_in[4];
    const float* pq      = (const float*)d_in[5];
    const float* pk      = (const float*)d_in[6];
    const float* pv      = (const float*)d_in[7];
    const float* pc      = (const float*)d_in[8];
    const float* pf1     = (const float*)d_in[9];
    const float* pf2     = (const float*)d_in[10];
    const float* bf1     = (const float*)d_in[11];
    const float* bf2     = (const float*)d_in[12];
    const float* b1      = (const float*)d_in[13];
    const float* b2      = (const float*)d_in[14];
    const float* s1      = (const float*)d_in[15];
    const float* s2      = (const float*)d_in[16];
    const float* pos     = (const float*)d_in[17];

    float* outp   = (float*)d_out;
    float* logits = outp;
    float* dec    = outp + (long)2048 * VOC;

    char* base = (char*)d_ws;
    float*  x_f   = (float*) (base + 0);
    ushort* x_hi  = (ushort*)(base + 16777216);
    ushort* x_lo  = (ushort*)(base + 25165824);
    ushort* k_hi  = (ushort*)(base + 33554432);
    ushort* k_lo  = (ushort*)(base + 41943040);
    ushort* v_hi  = (ushort*)(base + 50331648);
    ushort* v_lo  = (ushort*)(base + 58720256);
    ushort* vt_hi = (ushort*)(base + 67108864);
    ushort* vt_lo = (ushort*)(base + 75497472);
    ushort* q_hi  = (ushort*)(base + 83886080);
    ushort* q_lo  = (ushort*)(base + 88080384);
    ushort* o_hi  = (ushort*)(base + 92274688);
    ushort* o_lo  = (ushort*)(base + 96468992);
    float*  t0a   = (float*) (base + 100663296);
    float*  h0    = t0a;
    float*  t0b   = (float*) (base + 109051904);
    float*  xs    = (float*) (base + 117440512);
    ushort* xs_hi = (ushort*)(base + 125829120);
    ushort* xs_lo = (ushort*)(base + 130023424);
    ushort* wq_hi = (ushort*)(base + 134217728);
    ushort* wq_lo = (ushort*)(base + 136314880);
    ushort* wk_hi = (ushort*)(base + 138412032);
    ushort* wk_lo = (ushort*)(base + 140509184);
    ushort* wv_hi = (ushort*)(base + 142606336);
    ushort* wv_lo = (ushort*)(base + 144703488);
    ushort* wc_hi = (ushort*)(base + 146800640);
    ushort* wc_lo = (ushort*)(base + 148897792);
    ushort* wf1_hi= (ushort*)(base + 150994944);
    ushort* wf1_lo= (ushort*)(base + 159383552);
    ushort* wf2_hi= (ushort*)(base + 167772160);
    ushort* wf2_lo= (ushort*)(base + 176160768);   // ends 184,549,376
    // overlays
    ushort* ff1_hi= (ushort*)(base + 33554432);    // k_hi/k_lo region, post-fattn
    ushort* ff1_lo= (ushort*)(base + 50331648);    // v_hi/v_lo region, post-fattn
    ushort* decb  = (ushort*)(base + 92274688);    // o_hi region, l5 ln2
    ushort* wdect = (ushort*)(base + 0);           // post-loop overlay

    embed_kernel<<<NB * WINN, 256, 0, stream>>>(x_input, Wemb, Wlin, h0);

    for (int l = 0; l < NL; ++l) {
        const float* cur = (l == 0) ? h0 : (dec + (long)(l - 1) * 2097152);
        build_x_kernel<<<(NB * TT * HID / 4) / 256, 256, 0, stream>>>(
            pos + (long)l * TT * HID, prev + (long)l * NB * WINN * HID, cur,
            x_f, x_hi, x_lo);

        wsplit_kernel<<<dim3(32, 32), 256, 0, stream>>>(pq + (long)l * HID * HID, wq_hi, wq_lo, HID, HID);
        wsplit_kernel<<<dim3(32, 32), 256, 0, stream>>>(pk + (long)l * HID * HID, wk_hi, wk_lo, HID, HID);
        wsplit_kernel<<<dim3(32, 32), 256, 0, stream>>>(pv + (long)l * HID * HID, wv_hi, wv_lo, HID, HID);
        wsplit_kernel<<<dim3(32, 32), 256, 0, stream>>>(pc + (long)l * HID * HID, wc_hi, wc_lo, HID, HID);
        wsplit_kernel<<<dim3(FFW / 32, HID / 32), 256, 0, stream>>>(
            pf1 + (long)l * HID * FFW, wf1_hi, wf1_lo, HID, FFW);
        wsplit_kernel<<<dim3(HID / 32, FFW / 32), 256, 0, stream>>>(
            pf2 + (long)l * FFW * HID, wf2_hi, wf2_lo, FFW, HID);

        hgemm<<<dim3(HID / 64, (NB * TT) / 128), 256, 0, stream>>>(
            x_hi, x_lo, wk_hi, wk_lo, nullptr, k_hi, k_lo,
            NB * TT, HID, HID, 0, HID, 1.f, nullptr, 0, 0);
        hgemm<<<dim3(HID / 64, (NB * TT) / 128), 256, 0, stream>>>(
            x_hi, x_lo, wv_hi, wv_lo, nullptr, v_hi, v_lo,
            NB * TT, HID, HID, 0, HID, 1.f, nullptr, 0, 0);
        hgemm<<<dim3(HID / 64, (NB * WINN) / 128), 256, 0, stream>>>(
            x_hi, x_lo, wq_hi, wq_lo, nullptr, q_hi, q_lo,
            NB * WINN, HID, HID, 0, HID, 0.125f, nullptr, 0, 1);
        vtrans_kernel<<<dim3(HID / 32, (NB * TT) / 32), 256, 0, stream>>>(
            v_hi, v_lo, vt_hi, vt_lo);

        fattn_mfma<<<dim3(WINN / 64, NH, NB), 256, 0, stream>>>(
            q_hi, q_lo, k_hi, k_lo, vt_hi, vt_lo, o_hi, o_lo);

        hgemm<<<dim3(HID / 64, (NB * WINN) / 128), 256, 0, stream>>>(
            o_hi, o_lo, wc_hi, wc_lo, t0a, nullptr, nullptr,
            NB * WINN, HID, HID, 0, HID, 1.f, nullptr, 0, 0);
        ln_res_kernel<<<NB * WINN, 256, 0, stream>>>(
            t0a, nullptr, x_f, xs, xs_hi, xs_lo, nullptr,
            b1 + l * HID, s1 + l * HID, 1);

        hgemm<<<dim3(FFW / 64, (NB * WINN) / 128), 256, 0, stream>>>(
            xs_hi, xs_lo, wf1_hi, wf1_lo, nullptr, ff1_hi, ff1_lo,
            NB * WINN, FFW, HID, 0, HID, 1.f, bf1 + l * FFW, 1, 0);
        hgemm<<<dim3(HID / 64, (NB * WINN) / 128), 256, 0, stream>>>(
            ff1_hi, ff1_lo, wf2_hi, wf2_lo, t0a, nullptr, nullptr,
            NB * WINN, HID, FFW, 0, FFW / 2, 1.f, bf2 + l * HID, 0, 0);
        hgemm<<<dim3(HID / 64, (NB * WINN) / 128), 256, 0, stream>>>(
            ff1_hi, ff1_lo, wf2_hi, wf2_lo, t0b, nullptr, nullptr,
            NB * WINN, HID, FFW, FFW / 2, FFW / 2, 1.f, nullptr, 0, 0);
        ln_res_kernel<<<NB * WINN, 256, 0, stream>>>(
            t0a, t0b, xs, dec + (long)l * 2097152, nullptr, nullptr,
            (l == NL - 1) ? decb : nullptr, b2 + l * HID, s2 + l * HID, 0);
    }

    transp_kernel<<<dim3(VOC / 32, HID / 32), 256, 0, stream>>>(pdec, wdect, HID, VOC);
    mfma_gemm<<<dim3(VOC / 128, (NB * WINN) / 128), 256, 0, stream>>>(
        decb, wdect, logits, NB * WINN, VOC, HID);
}

// Round 9
// 2609.999 us; speedup vs baseline: 4.7421x; 1.2962x over previous
//
#include <hip/hip_runtime.h>
#include <hip/hip_bf16.h>

#define NL   6
#define NH   16
#define HID  1024
#define HD   64
#define FFW  4096
#define VOC  32000
#define WINN 512
#define EMB  128
#define NB   4
#define TT   1024   // WIN + WIN

typedef __attribute__((ext_vector_type(8))) _Float16 f16x8;
typedef __attribute__((ext_vector_type(8))) short    b16x8;
typedef __attribute__((ext_vector_type(4))) float    f32x4;

__device__ __forceinline__ ushort f2b(float f) {
    __hip_bfloat16 h = __float2bfloat16(f);
    return *reinterpret_cast<ushort*>(&h);
}
// split f32 into fp16 hi/lo:  f ~= hi + lo * 2^-11  (error ~ |f|*2^-22)
__device__ __forceinline__ void split16(float f, ushort& hb, ushort& lb) {
    _Float16 h = (_Float16)f;
    _Float16 l = (_Float16)((f - (float)h) * 2048.0f);
    hb = __builtin_bit_cast(ushort, h);
    lb = __builtin_bit_cast(ushort, l);
}

// ---------------------------------------------------------------------------
// Embed (f32)
// ---------------------------------------------------------------------------
__global__ __launch_bounds__(256) void embed_kernel(
    const int* __restrict__ xin, const float* __restrict__ Wemb,
    const float* __restrict__ Wlin, float* __restrict__ h0)
{
    int row = blockIdx.x;
    int tok = xin[row];
    __shared__ float tk[EMB];
    if (threadIdx.x < EMB) tk[threadIdx.x] = Wemb[tok * EMB + threadIdx.x] * 0.03125f;
    __syncthreads();
    for (int j = 0; j < 4; ++j) {
        int c = threadIdx.x + 256 * j;
        float acc = 0.f;
        for (int e = 0; e < EMB; ++e) acc += tk[e] * Wlin[e * HID + c];
        h0[(long)row * HID + c] = acc;
    }
}

// ---------------------------------------------------------------------------
// x = pos + concat(prev, cur); outputs f32 + fp16 hi/lo split
// ---------------------------------------------------------------------------
__global__ __launch_bounds__(256) void build_x_kernel(
    const float* __restrict__ pos, const float* __restrict__ prev,
    const float* __restrict__ cur, float* __restrict__ x,
    ushort* __restrict__ xh, ushort* __restrict__ xl)
{
    int i4 = blockIdx.x * blockDim.x + threadIdx.x;
    if (i4 >= NB * TT * HID / 4) return;
    int h4 = i4 % (HID / 4);
    int bt = i4 / (HID / 4);
    int t = bt % TT, b = bt / TT;
    float4 p = ((const float4*)pos)[t * (HID / 4) + h4];
    float4 s;
    if (t < WINN) s = ((const float4*)prev)[(long)(b * WINN + t) * (HID / 4) + h4];
    else          s = ((const float4*)cur)[(long)(b * WINN + (t - WINN)) * (HID / 4) + h4];
    float4 r; r.x = p.x + s.x; r.y = p.y + s.y; r.z = p.z + s.z; r.w = p.w + s.w;
    ((float4*)x)[i4] = r;
    ushort4 uh, ul;
    split16(r.x, uh.x, ul.x); split16(r.y, uh.y, ul.y);
    split16(r.z, uh.z, ul.z); split16(r.w, uh.w, ul.w);
    ((ushort4*)xh)[i4] = uh;
    ((ushort4*)xl)[i4] = ul;
}

// ---------------------------------------------------------------------------
// Weight transpose + fp16 split: W f32 [K,N] -> Wt_hi/Wt_lo fp16 [N,K]
// ---------------------------------------------------------------------------
__global__ __launch_bounds__(256) void wsplit_kernel(
    const float* __restrict__ W, ushort* __restrict__ Wth, ushort* __restrict__ Wtl,
    int K, int N)
{
    __shared__ float ts[32][33];
    int n0 = blockIdx.x * 32, k0 = blockIdx.y * 32;
    int tr = threadIdx.x >> 5, tc = threadIdx.x & 31;
#pragma unroll
    for (int j = 0; j < 4; ++j)
        ts[tr + j * 8][tc] = W[(long)(k0 + tr + j * 8) * N + n0 + tc];
    __syncthreads();
#pragma unroll
    for (int j = 0; j < 4; ++j) {
        int n = tr + j * 8;
        ushort hb, lb;
        split16(ts[tc][n], hb, lb);
        long idx = (long)(n0 + n) * K + k0 + tc;
        Wth[idx] = hb;
        Wtl[idx] = lb;
    }
}

// ---------------------------------------------------------------------------
// ushort-pair transpose with source row stride: v[r][c] (c<HID slice of a
// src_stride-wide row) -> vt [HID][NB*TT]
// ---------------------------------------------------------------------------
__global__ __launch_bounds__(256) void vtrans_kernel(
    const ushort* __restrict__ vh, const ushort* __restrict__ vl,
    ushort* __restrict__ vth, ushort* __restrict__ vtl, int src_stride)
{
    __shared__ ushort th[32][33], tl[32][33];
    int n0 = blockIdx.x * 32, r0 = blockIdx.y * 32;
    int tr = threadIdx.x >> 5, tc = threadIdx.x & 31;
#pragma unroll
    for (int j = 0; j < 4; ++j) {
        long g = (long)(r0 + tr + j * 8) * src_stride + n0 + tc;
        th[tr + j * 8][tc] = vh[g];
        tl[tr + j * 8][tc] = vl[g];
    }
    __syncthreads();
#pragma unroll
    for (int j = 0; j < 4; ++j) {
        long g = (long)(n0 + tr + j * 8) * (NB * TT) + r0 + tc;
        vth[g] = th[tc][tr + j * 8];
        vtl[g] = tl[tc][tr + j * 8];
    }
}

// ---------------------------------------------------------------------------
// Split-fp16 MFMA GEMM, 128x64 tile, 4 waves, f32 out, gridDim.z split-K:
// block z computes A[:, z*Ksub:(z+1)*Ksub] @ B-chunk into Cf(z) (Cf0/Cf1).
// bias applied only on z==0. amap remaps A rows (top half of 1024-blocks).
// ---------------------------------------------------------------------------
__global__ __launch_bounds__(256) void hgemm(
    const ushort* __restrict__ Ah, const ushort* __restrict__ Al,
    const ushort* __restrict__ Bh, const ushort* __restrict__ Bl,
    float* __restrict__ Cf0, float* __restrict__ Cf1,
    int M, int N, int K_stride, int Ksub,
    float scale, const float* __restrict__ bias, int relu, int amap)
{
    __shared__ ushort Ash[128 * 40];
    __shared__ ushort Asl[128 * 40];
    __shared__ ushort Bsh[64 * 40];
    __shared__ ushort Bsl[64 * 40];
    const int tid  = threadIdx.x;
    const int rb   = blockIdx.y * 128;
    const int cb   = blockIdx.x * 64;
    const int z    = blockIdx.z;
    const int k_off = z * Ksub;
    float* __restrict__ Cf = z ? Cf1 : Cf0;
    const float* bias_eff = (z == 0) ? bias : nullptr;
    const int wave = tid >> 6, lane = tid & 63;
    const int wr   = (wave >> 1) * 64;
    const int wc   = (wave & 1) * 32;
    const int lr   = lane & 15;
    const int kh   = lane >> 4;

    const int sar = tid >> 1;
    const int sak = (tid & 1) * 16;
    int gra = rb + sar;
    long marow = amap ? (long)((gra >> 9) * 1024 + 512 + (gra & 511)) : (long)gra;
    const ushort* pAh = Ah + marow * K_stride + k_off + sak;
    const ushort* pAl = Al + marow * K_stride + k_off + sak;
    const int wA0 = sar * 40 + sak, wA1 = wA0 + 8;
    const int sbr = tid >> 2;
    const int sbk = (tid & 3) * 8;
    const ushort* pBh = Bh + (long)(cb + sbr) * K_stride + k_off + sbk;
    const ushort* pBl = Bl + (long)(cb + sbr) * K_stride + k_off + sbk;
    const int wB0 = sbr * 40 + sbk;

    int aoff[4], boff[2];
#pragma unroll
    for (int m = 0; m < 4; ++m) aoff[m] = (wr + m * 16 + lr) * 40 + kh * 8;
#pragma unroll
    for (int n = 0; n < 2; ++n) boff[n] = (wc + n * 16 + lr) * 40 + kh * 8;

    f32x4 accH[4][2], accL[4][2];
#pragma unroll
    for (int m = 0; m < 4; ++m)
#pragma unroll
        for (int n = 0; n < 2; ++n) {
            accH[m][n] = (f32x4){0.f, 0.f, 0.f, 0.f};
            accL[m][n] = (f32x4){0.f, 0.f, 0.f, 0.f};
        }

    for (int k0 = 0; k0 < Ksub; k0 += 32) {
        uint4 ah0 = *(const uint4*)(pAh + k0);
        uint4 ah1 = *(const uint4*)(pAh + k0 + 8);
        uint4 al0 = *(const uint4*)(pAl + k0);
        uint4 al1 = *(const uint4*)(pAl + k0 + 8);
        uint4 bh0 = *(const uint4*)(pBh + k0);
        uint4 bl0 = *(const uint4*)(pBl + k0);
        __syncthreads();
        *(uint4*)(Ash + wA0) = ah0; *(uint4*)(Ash + wA1) = ah1;
        *(uint4*)(Asl + wA0) = al0; *(uint4*)(Asl + wA1) = al1;
        *(uint4*)(Bsh + wB0) = bh0;
        *(uint4*)(Bsl + wB0) = bl0;
        __syncthreads();
        f16x8 afh[4], afl[4], bfh[2], bfl[2];
#pragma unroll
        for (int m = 0; m < 4; ++m) {
            afh[m] = *(const f16x8*)(Ash + aoff[m]);
            afl[m] = *(const f16x8*)(Asl + aoff[m]);
        }
#pragma unroll
        for (int n = 0; n < 2; ++n) {
            bfh[n] = *(const f16x8*)(Bsh + boff[n]);
            bfl[n] = *(const f16x8*)(Bsl + boff[n]);
        }
#pragma unroll
        for (int m = 0; m < 4; ++m)
#pragma unroll
            for (int n = 0; n < 2; ++n) {
                accH[m][n] = __builtin_amdgcn_mfma_f32_16x16x32_f16(afh[m], bfh[n], accH[m][n], 0, 0, 0);
                accL[m][n] = __builtin_amdgcn_mfma_f32_16x16x32_f16(afh[m], bfl[n], accL[m][n], 0, 0, 0);
                accL[m][n] = __builtin_amdgcn_mfma_f32_16x16x32_f16(afl[m], bfh[n], accL[m][n], 0, 0, 0);
            }
    }

#pragma unroll
    for (int m = 0; m < 4; ++m) {
        int row0 = rb + wr + m * 16 + kh * 4;
#pragma unroll
        for (int n = 0; n < 2; ++n) {
            int col = cb + wc + n * 16 + lr;
            float bv = bias_eff ? bias_eff[col] : 0.f;
#pragma unroll
            for (int r = 0; r < 4; ++r) {
                float v = (accH[m][n][r] + accL[m][n][r] * (1.f / 2048.f)) * scale + bv;
                if (relu) v = fmaxf(v, 0.f);
                Cf[(long)(row0 + r) * N + col] = v;
            }
        }
    }
}

// ---------------------------------------------------------------------------
// Split-fp16 MFMA GEMM, 128x128 tile, 8 waves (2x4), wave = 64x32.
// 512 threads; 4x16B staged loads per thread per K-step; 24 wave-MFMA/K-step.
// Outputs fp16 hi/lo split (Chh/Cll) with optional bias+relu.
// ---------------------------------------------------------------------------
__global__ __launch_bounds__(512) void hgemm8(
    const ushort* __restrict__ Ah, const ushort* __restrict__ Al,
    const ushort* __restrict__ Bh, const ushort* __restrict__ Bl,
    ushort* __restrict__ Chh, ushort* __restrict__ Cll,
    int M, int N, int K_stride,
    float scale, const float* __restrict__ bias, int relu)
{
    __shared__ ushort Ash[128 * 40];
    __shared__ ushort Asl[128 * 40];
    __shared__ ushort Bsh[128 * 40];
    __shared__ ushort Bsl[128 * 40];
    const int tid  = threadIdx.x;
    const int rb   = blockIdx.y * 128;
    const int cb   = blockIdx.x * 128;
    const int wave = tid >> 6, lane = tid & 63;
    const int wr   = (wave >> 2) * 64;
    const int wc   = (wave & 3) * 32;
    const int lr   = lane & 15;
    const int kh   = lane >> 4;

    const int srow = tid >> 2;          // 0..127
    const int sk   = (tid & 3) * 8;     // 0,8,16,24
    const ushort* pAh = Ah + (long)(rb + srow) * K_stride + sk;
    const ushort* pAl = Al + (long)(rb + srow) * K_stride + sk;
    const ushort* pBh = Bh + (long)(cb + srow) * K_stride + sk;
    const ushort* pBl = Bl + (long)(cb + srow) * K_stride + sk;
    const int woff = srow * 40 + sk;

    int aoff[4], boff[2];
#pragma unroll
    for (int m = 0; m < 4; ++m) aoff[m] = (wr + m * 16 + lr) * 40 + kh * 8;
#pragma unroll
    for (int n = 0; n < 2; ++n) boff[n] = (wc + n * 16 + lr) * 40 + kh * 8;

    f32x4 accH[4][2], accL[4][2];
#pragma unroll
    for (int m = 0; m < 4; ++m)
#pragma unroll
        for (int n = 0; n < 2; ++n) {
            accH[m][n] = (f32x4){0.f, 0.f, 0.f, 0.f};
            accL[m][n] = (f32x4){0.f, 0.f, 0.f, 0.f};
        }

    for (int k0 = 0; k0 < K_stride; k0 += 32) {
        uint4 ah = *(const uint4*)(pAh + k0);
        uint4 al = *(const uint4*)(pAl + k0);
        uint4 bh = *(const uint4*)(pBh + k0);
        uint4 bl = *(const uint4*)(pBl + k0);
        __syncthreads();
        *(uint4*)(Ash + woff) = ah;
        *(uint4*)(Asl + woff) = al;
        *(uint4*)(Bsh + woff) = bh;
        *(uint4*)(Bsl + woff) = bl;
        __syncthreads();
        f16x8 afh[4], afl[4], bfh[2], bfl[2];
#pragma unroll
        for (int m = 0; m < 4; ++m) {
            afh[m] = *(const f16x8*)(Ash + aoff[m]);
            afl[m] = *(const f16x8*)(Asl + aoff[m]);
        }
#pragma unroll
        for (int n = 0; n < 2; ++n) {
            bfh[n] = *(const f16x8*)(Bsh + boff[n]);
            bfl[n] = *(const f16x8*)(Bsl + boff[n]);
        }
#pragma unroll
        for (int m = 0; m < 4; ++m)
#pragma unroll
            for (int n = 0; n < 2; ++n) {
                accH[m][n] = __builtin_amdgcn_mfma_f32_16x16x32_f16(afh[m], bfh[n], accH[m][n], 0, 0, 0);
                accL[m][n] = __builtin_amdgcn_mfma_f32_16x16x32_f16(afh[m], bfl[n], accL[m][n], 0, 0, 0);
                accL[m][n] = __builtin_amdgcn_mfma_f32_16x16x32_f16(afl[m], bfh[n], accL[m][n], 0, 0, 0);
            }
    }

#pragma unroll
    for (int m = 0; m < 4; ++m) {
        int row0 = rb + wr + m * 16 + kh * 4;
#pragma unroll
        for (int n = 0; n < 2; ++n) {
            int col = cb + wc + n * 16 + lr;
            float bv = bias ? bias[col] : 0.f;
#pragma unroll
            for (int r = 0; r < 4; ++r) {
                float v = (accH[m][n][r] + accL[m][n][r] * (1.f / 2048.f)) * scale + bv;
                if (relu) v = fmaxf(v, 0.f);
                long idx = (long)(row0 + r) * N + col;
                ushort hb, lb; split16(v, hb, lb);
                Chh[idx] = hb; Cll[idx] = lb;
            }
        }
    }
}

// ---------------------------------------------------------------------------
// MFMA flash attention. Q from split-K f32 pair (qa+qb), K from fused kv
// buffer (row stride kstr), V^T split-fp16. f32 online softmax.
// Block = (qt, h, b): 64 q-rows, 4 waves x 16 rows.
// ---------------------------------------------------------------------------
__global__ __launch_bounds__(256) void fattn_mfma(
    const float* __restrict__ qa, const float* __restrict__ qb,
    const ushort* __restrict__ kbh, const ushort* __restrict__ kbl, int kstr,
    const ushort* __restrict__ vth, const ushort* __restrict__ vtl,
    ushort* __restrict__ oh, ushort* __restrict__ ol)
{
    __shared__ __align__(16) ushort ksh[64 * 72];   // K tile / P_hi overlay
    __shared__ __align__(16) ushort ksl[64 * 72];
    __shared__ __align__(16) ushort vsh[64 * 72];   // V^T tile [d][krow]
    __shared__ __align__(16) ushort vsl[64 * 72];
    const int qt = blockIdx.x, h = blockIdx.y, b = blockIdx.z;
    const int tid = threadIdx.x;
    const int wave = tid >> 6, lane = tid & 63;
    const int lr = lane & 15, kg4 = lane >> 4;
    const int qbase = b * WINN + qt * 64;

    // Q A-frags: sum split-K halves in f32, then split to fp16 hi/lo
    f16x8 qfh[2], qfl[2];
#pragma unroll
    for (int c = 0; c < 2; ++c) {
        long ga = (long)(qbase + wave * 16 + lr) * HID + h * HD + c * 32 + kg4 * 8;
        float4 a0 = *(const float4*)(qa + ga);
        float4 a1 = *(const float4*)(qa + ga + 4);
        float4 b0 = *(const float4*)(qb + ga);
        float4 b1 = *(const float4*)(qb + ga + 4);
        float qv[8] = {a0.x + b0.x, a0.y + b0.y, a0.z + b0.z, a0.w + b0.w,
                       a1.x + b1.x, a1.y + b1.y, a1.z + b1.z, a1.w + b1.w};
        ushort uh[8], ul[8];
#pragma unroll
        for (int j = 0; j < 8; ++j) split16(qv[j], uh[j], ul[j]);
        qfh[c] = *(const f16x8*)uh;
        qfl[c] = *(const f16x8*)ul;
    }

    f32x4 accOH[4], accOL[4];
#pragma unroll
    for (int d = 0; d < 4; ++d) {
        accOH[d] = (f32x4){0.f, 0.f, 0.f, 0.f};
        accOL[d] = (f32x4){0.f, 0.f, 0.f, 0.f};
    }
    float mrow[4], lrow[4];
#pragma unroll
    for (int r = 0; r < 4; ++r) { mrow[r] = -3.0e38f; lrow[r] = 0.f; }

    const int sr = tid >> 2;
    const int sd = (tid & 3) * 16;

    const int ktmax = 9 + qt;
    for (int kt = 0; kt < ktmax; ++kt) {
        __syncthreads();
        {
            long gk = (long)(b * TT + kt * 64 + sr) * kstr + h * HD + sd;
            uint4 h0 = *(const uint4*)(kbh + gk);
            uint4 h1 = *(const uint4*)(kbh + gk + 8);
            uint4 l0 = *(const uint4*)(kbl + gk);
            uint4 l1 = *(const uint4*)(kbl + gk + 8);
            long gv = (long)(h * HD + sr) * (NB * TT) + b * TT + kt * 64 + sd;
            uint4 vh0 = *(const uint4*)(vth + gv);
            uint4 vh1 = *(const uint4*)(vth + gv + 8);
            uint4 vl0 = *(const uint4*)(vtl + gv);
            uint4 vl1 = *(const uint4*)(vtl + gv + 8);
            *(uint4*)(ksh + sr * 72 + sd) = h0;
            *(uint4*)(ksh + sr * 72 + sd + 8) = h1;
            *(uint4*)(ksl + sr * 72 + sd) = l0;
            *(uint4*)(ksl + sr * 72 + sd + 8) = l1;
            *(uint4*)(vsh + sr * 72 + sd) = vh0;
            *(uint4*)(vsh + sr * 72 + sd + 8) = vh1;
            *(uint4*)(vsl + sr * 72 + sd) = vl0;
            *(uint4*)(vsl + sr * 72 + sd + 8) = vl1;
        }
        __syncthreads();

        f32x4 sH[4], sL[4];
#pragma unroll
        for (int n = 0; n < 4; ++n) {
            sH[n] = (f32x4){0.f, 0.f, 0.f, 0.f};
            sL[n] = (f32x4){0.f, 0.f, 0.f, 0.f};
        }
#pragma unroll
        for (int c = 0; c < 2; ++c) {
#pragma unroll
            for (int n = 0; n < 4; ++n) {
                int ad = (n * 16 + lr) * 72 + c * 32 + kg4 * 8;
                f16x8 bh = *(const f16x8*)(ksh + ad);
                f16x8 bl = *(const f16x8*)(ksl + ad);
                sH[n] = __builtin_amdgcn_mfma_f32_16x16x32_f16(qfh[c], bh, sH[n], 0, 0, 0);
                sL[n] = __builtin_amdgcn_mfma_f32_16x16x32_f16(qfh[c], bl, sL[n], 0, 0, 0);
                sL[n] = __builtin_amdgcn_mfma_f32_16x16x32_f16(qfl[c], bh, sL[n], 0, 0, 0);
            }
        }
        float S[4][4];
#pragma unroll
        for (int n = 0; n < 4; ++n)
#pragma unroll
            for (int r = 0; r < 4; ++r)
                S[n][r] = sH[n][r] + sL[n][r] * (1.f / 2048.f);

        if (kt == ktmax - 1) {
#pragma unroll
            for (int r = 0; r < 4; ++r) {
                int qi = WINN + qt * 64 + wave * 16 + kg4 * 4 + r;
#pragma unroll
                for (int n = 0; n < 4; ++n) {
                    int kg = kt * 64 + n * 16 + lr;
                    if (kg > qi) S[n][r] = -1e9f;
                }
            }
        }

#pragma unroll
        for (int r = 0; r < 4; ++r) {
            float mx = fmaxf(fmaxf(S[0][r], S[1][r]), fmaxf(S[2][r], S[3][r]));
            mx = fmaxf(mx, __shfl_xor(mx, 1));
            mx = fmaxf(mx, __shfl_xor(mx, 2));
            mx = fmaxf(mx, __shfl_xor(mx, 4));
            mx = fmaxf(mx, __shfl_xor(mx, 8));
            float mnew = fmaxf(mrow[r], mx);
            float alpha = __expf(mrow[r] - mnew);
            float rs = 0.f;
#pragma unroll
            for (int n = 0; n < 4; ++n) { S[n][r] = __expf(S[n][r] - mnew); rs += S[n][r]; }
            rs += __shfl_xor(rs, 1);
            rs += __shfl_xor(rs, 2);
            rs += __shfl_xor(rs, 4);
            rs += __shfl_xor(rs, 8);
            lrow[r] = lrow[r] * alpha + rs;
            mrow[r] = mnew;
#pragma unroll
            for (int d = 0; d < 4; ++d) { accOH[d][r] *= alpha; accOL[d][r] *= alpha; }
        }

        __syncthreads();
#pragma unroll
        for (int n = 0; n < 4; ++n)
#pragma unroll
            for (int r = 0; r < 4; ++r) {
                ushort hb, lb;
                split16(S[n][r], hb, lb);
                int ad = (wave * 16 + kg4 * 4 + r) * 72 + n * 16 + lr;
                ksh[ad] = hb;
                ksl[ad] = lb;
            }
        f16x8 pfh[2], pfl[2];
#pragma unroll
        for (int c = 0; c < 2; ++c) {
            int ad = (wave * 16 + lr) * 72 + c * 32 + kg4 * 8;
            pfh[c] = *(const f16x8*)(ksh + ad);
            pfl[c] = *(const f16x8*)(ksl + ad);
        }
#pragma unroll
        for (int c = 0; c < 2; ++c) {
#pragma unroll
            for (int d = 0; d < 4; ++d) {
                int ad = (d * 16 + lr) * 72 + c * 32 + kg4 * 8;
                f16x8 vh = *(const f16x8*)(vsh + ad);
                f16x8 vl = *(const f16x8*)(vsl + ad);
                accOH[d] = __builtin_amdgcn_mfma_f32_16x16x32_f16(pfh[c], vh, accOH[d], 0, 0, 0);
                accOL[d] = __builtin_amdgcn_mfma_f32_16x16x32_f16(pfh[c], vl, accOL[d], 0, 0, 0);
                accOL[d] = __builtin_amdgcn_mfma_f32_16x16x32_f16(pfl[c], vh, accOL[d], 0, 0, 0);
            }
        }
    }

#pragma unroll
    for (int r = 0; r < 4; ++r) {
        float inv = 1.f / lrow[r];
        long rowb = (long)(qbase + wave * 16 + kg4 * 4 + r) * HID + h * HD + lr;
#pragma unroll
        for (int d = 0; d < 4; ++d) {
            float v = (accOH[d][r] + accOL[d][r] * (1.f / 2048.f)) * inv;
            ushort hb, lb;
            split16(v, hb, lb);
            oh[rowb + d * 16] = hb;
            ol[rowb + d * 16] = lb;
        }
    }
}

// ---------------------------------------------------------------------------
// Transpose+convert (bf16, logits W)
// ---------------------------------------------------------------------------
__global__ __launch_bounds__(256) void transp_kernel(
    const float* __restrict__ W, ushort* __restrict__ Wt, int K, int N)
{
    __shared__ float ts[32][33];
    int n0 = blockIdx.x * 32, k0 = blockIdx.y * 32;
    int tr = threadIdx.x >> 5, tc = threadIdx.x & 31;
#pragma unroll
    for (int j = 0; j < 4; ++j)
        ts[tr + j * 8][tc] = W[(long)(k0 + tr + j * 8) * N + n0 + tc];
    __syncthreads();
#pragma unroll
    for (int j = 0; j < 4; ++j) {
        int n = tr + j * 8;
        Wt[(long)(n0 + n) * K + k0 + tc] = f2b(ts[tc][n]);
    }
}

// ---------------------------------------------------------------------------
// bf16 MFMA GEMM (logits only), bijective XCD-aware block swizzle.
// ---------------------------------------------------------------------------
__global__ __launch_bounds__(256) void mfma_gemm(
    const ushort* __restrict__ A, const ushort* __restrict__ Bt,
    float* __restrict__ Cf, int M, int N, int K)
{
    __shared__ ushort As[128 * 40];
    __shared__ ushort Bs[128 * 40];
    const int tid  = threadIdx.x;
    // XCD swizzle: grid is 4000 blocks (divisible by 8) -> contiguous chunks per XCD
    const int nbx = gridDim.x;
    const int nwg = nbx * gridDim.y;
    const int bid = blockIdx.y * nbx + blockIdx.x;
    const int cpx = nwg >> 3;
    const int swz = (bid & 7) * cpx + (bid >> 3);
    const int rb  = (swz / nbx) * 128;
    const int cb  = (swz % nbx) * 128;
    const int wave = tid >> 6, lane = tid & 63;
    const int wr   = (wave >> 1) * 64;
    const int wc   = (wave & 1) * 64;
    const int lr   = lane & 15;
    const int kh   = lane >> 4;

    const int srow = tid >> 1;
    const int kc0  = (tid & 1) * 2;
    const ushort* aptr = A + (long)(rb + srow) * K + kc0 * 8;
    const ushort* bptr = Bt + (long)(cb + srow) * K + kc0 * 8;
    const int woff0 = srow * 40 + kc0 * 8;
    const int woff1 = srow * 40 + (kc0 + 1) * 8;

    int aoff[4], boff[4];
#pragma unroll
    for (int m = 0; m < 4; ++m) aoff[m] = (wr + m * 16 + lr) * 40 + kh * 8;
#pragma unroll
    for (int n = 0; n < 4; ++n) boff[n] = (wc + n * 16 + lr) * 40 + kh * 8;

    f32x4 acc[4][4];
#pragma unroll
    for (int m = 0; m < 4; ++m)
#pragma unroll
        for (int n = 0; n < 4; ++n)
            acc[m][n] = (f32x4){0.f, 0.f, 0.f, 0.f};

    for (int k0 = 0; k0 < K; k0 += 32) {
        uint4 a0 = *(const uint4*)(aptr + k0);
        uint4 a1 = *(const uint4*)(aptr + k0 + 8);
        uint4 b0 = *(const uint4*)(bptr + k0);
        uint4 b1 = *(const uint4*)(bptr + k0 + 8);
        __syncthreads();
        *(uint4*)(As + woff0) = a0;
        *(uint4*)(As + woff1) = a1;
        *(uint4*)(Bs + woff0) = b0;
        *(uint4*)(Bs + woff1) = b1;
        __syncthreads();
        b16x8 af[4], bfr[4];
#pragma unroll
        for (int m = 0; m < 4; ++m) af[m] = *(const b16x8*)(As + aoff[m]);
#pragma unroll
        for (int n = 0; n < 4; ++n) bfr[n] = *(const b16x8*)(Bs + boff[n]);
#pragma unroll
        for (int m = 0; m < 4; ++m)
#pragma unroll
            for (int n = 0; n < 4; ++n)
                acc[m][n] = __builtin_amdgcn_mfma_f32_16x16x32_bf16(af[m], bfr[n], acc[m][n], 0, 0, 0);
    }

#pragma unroll
    for (int m = 0; m < 4; ++m) {
        int row0 = rb + wr + m * 16 + kh * 4;
#pragma unroll
        for (int n = 0; n < 4; ++n) {
            int col = cb + wc + n * 16 + lr;
#pragma unroll
            for (int r = 0; r < 4; ++r)
                Cf[(long)(row0 + r) * N + col] = acc[m][n][r];
        }
    }
}

// ---------------------------------------------------------------------------
// out = res[r'] + LN(t (+t2))*scale + bias; outputs f32 / fp16-split / bf16
// ---------------------------------------------------------------------------
__global__ __launch_bounds__(256) void ln_res_kernel(
    const float* __restrict__ t, const float* __restrict__ t2,
    const float* __restrict__ res, float* __restrict__ out,
    ushort* __restrict__ outh, ushort* __restrict__ outl, ushort* __restrict__ outb,
    const float* __restrict__ bias, const float* __restrict__ scale, int res_map)
{
    int r = blockIdx.x;
    int tid = threadIdx.x;
    long rr = res_map ? (long)((r >> 9) * 1024 + 512 + (r & 511)) : (long)r;
    float4 v = ((const float4*)(t + (long)r * HID))[tid];
    if (t2) {
        float4 w = ((const float4*)(t2 + (long)r * HID))[tid];
        v.x += w.x; v.y += w.y; v.z += w.z; v.w += w.w;
    }
    __shared__ float red[4];
    float s = v.x + v.y + v.z + v.w;
    for (int off = 32; off > 0; off >>= 1) s += __shfl_xor(s, off);
    if ((tid & 63) == 0) red[tid >> 6] = s;
    __syncthreads();
    float mean = (red[0] + red[1] + red[2] + red[3]) * (1.f / HID);
    __syncthreads();
    float dx = v.x - mean, dy = v.y - mean, dz = v.z - mean, dw = v.w - mean;
    float qs = dx * dx + dy * dy + dz * dz + dw * dw;
    for (int off = 32; off > 0; off >>= 1) qs += __shfl_xor(qs, off);
    if ((tid & 63) == 0) red[tid >> 6] = qs;
    __syncthreads();
    float var = (red[0] + red[1] + red[2] + red[3]) * (1.f / HID);
    float rs = rsqrtf(var + 1e-6f);
    float4 rv = ((const float4*)(res + rr * HID))[tid];
    float4 sc4 = ((const float4*)scale)[tid];
    float4 b4  = ((const float4*)bias)[tid];
    float4 o4;
    o4.x = rv.x + dx * rs * sc4.x + b4.x;
    o4.y = rv.y + dy * rs * sc4.y + b4.y;
    o4.z = rv.z + dz * rs * sc4.z + b4.z;
    o4.w = rv.w + dw * rs * sc4.w + b4.w;
    ((float4*)(out + (long)r * HID))[tid] = o4;
    if (outh) {
        ushort4 uh, ul;
        split16(o4.x, uh.x, ul.x); split16(o4.y, uh.y, ul.y);
        split16(o4.z, uh.z, ul.z); split16(o4.w, uh.w, ul.w);
        ((ushort4*)(outh + (long)r * HID))[tid] = uh;
        ((ushort4*)(outl + (long)r * HID))[tid] = ul;
    }
    if (outb) {
        ushort4 u; u.x = f2b(o4.x); u.y = f2b(o4.y); u.z = f2b(o4.z); u.w = f2b(o4.w);
        ((ushort4*)(outb + (long)r * HID))[tid] = u;
    }
}

// ---------------------------------------------------------------------------
// Workspace (168 MiB = 176,160,768 B; == R7's proven-safe footprint):
//  [0,16M)    x_f
//  [16,24M)   x_hi  [24,32M) x_lo
//  [32,48M)   kv_hi [48,64M) kv_lo      (K cols 0-1023, V cols 1024-2047)
//             (ff1_hi/ff1_lo overlay 32-64M post-fattn)
//  [64,72M)   vt_hi [72,80M) vt_lo
//  [80,84M)   o_hi  [84,88M) o_lo       (decb overlays 80-84M at l5)
//  [88,96M)   t0a (=h0 =qa)  [96,104M)  t0b (=qb)
//  [104,112M) xs  [112,116M) xs_hi [116,120M) xs_lo
//  [120M..)   weight splits: wq 2+2, wkv 4+4, wc 2+2, wf1 8+8, wf2 8+8
//  wdect overlay [0,62.5M) post-loop.
// ---------------------------------------------------------------------------
extern "C" void kernel_launch(void* const* d_in, const int* in_sizes, int n_in,
                              void* d_out, int out_size, void* d_ws, size_t ws_size,
                              hipStream_t stream)
{
    const int*   x_input = (const int*)  d_in[0];
    const float* prev    = (const float*)d_in[1];
    const float* Wemb    = (const float*)d_in[2];
    const float* Wlin    = (const float*)d_in[3];
    const float* pdec    = (const float*)d_in[4];
    const float* pq      = (const float*)d_in[5];
    const float* pk      = (const float*)d_in[6];
    const float* pv      = (const float*)d_in[7];
    const float* pc      = (const float*)d_in[8];
    const float* pf1     = (const float*)d_in[9];
    const float* pf2     = (const float*)d_in[10];
    const float* bf1     = (const float*)d_in[11];
    const float* bf2     = (const float*)d_in[12];
    const float* b1      = (const float*)d_in[13];
    const float* b2      = (const float*)d_in[14];
    const float* s1      = (const float*)d_in[15];
    const float* s2      = (const float*)d_in[16];
    const float* pos     = (const float*)d_in[17];

    float* outp   = (float*)d_out;
    float* logits = outp;
    float* dec    = outp + (long)2048 * VOC;

    char* base = (char*)d_ws;
    float*  x_f   = (float*) (base + 0);
    ushort* x_hi  = (ushort*)(base + 16777216);
    ushort* x_lo  = (ushort*)(base + 25165824);
    ushort* kv_hi = (ushort*)(base + 33554432);
    ushort* kv_lo = (ushort*)(base + 50331648);
    ushort* vt_hi = (ushort*)(base + 67108864);
    ushort* vt_lo = (ushort*)(base + 75497472);
    ushort* o_hi  = (ushort*)(base + 83886080);
    ushort* o_lo  = (ushort*)(base + 88080384);
    float*  t0a   = (float*) (base + 92274688);
    float*  h0    = t0a;
    float*  qa    = t0a;
    float*  t0b   = (float*) (base + 100663296);
    float*  qb    = t0b;
    float*  xs    = (float*) (base + 109051904);
    ushort* xs_hi = (ushort*)(base + 117440512);
    ushort* xs_lo = (ushort*)(base + 121634816);
    ushort* wq_hi = (ushort*)(base + 125829120);
    ushort* wq_lo = (ushort*)(base + 127926272);
    ushort* wkv_hi= (ushort*)(base + 130023424);
    ushort* wkv_lo= (ushort*)(base + 134217728);
    ushort* wc_hi = (ushort*)(base + 138412032);
    ushort* wc_lo = (ushort*)(base + 140509184);
    ushort* wf1_hi= (ushort*)(base + 142606336);
    ushort* wf1_lo= (ushort*)(base + 150994944);
    ushort* wf2_hi= (ushort*)(base + 159383552);
    ushort* wf2_lo= (ushort*)(base + 167772160);   // ends 176,160,768
    // overlays
    ushort* ff1_hi= (ushort*)(base + 33554432);    // kv_hi region, post-fattn
    ushort* ff1_lo= (ushort*)(base + 50331648);    // kv_lo region, post-fattn
    ushort* decb  = (ushort*)(base + 83886080);    // o_hi region, l5 ln2
    ushort* wdect = (ushort*)(base + 0);           // post-loop overlay

    embed_kernel<<<NB * WINN, 256, 0, stream>>>(x_input, Wemb, Wlin, h0);

    for (int l = 0; l < NL; ++l) {
        const float* cur = (l == 0) ? h0 : (dec + (long)(l - 1) * 2097152);
        build_x_kernel<<<(NB * TT * HID / 4) / 256, 256, 0, stream>>>(
            pos + (long)l * TT * HID, prev + (long)l * NB * WINN * HID, cur,
            x_f, x_hi, x_lo);

        wsplit_kernel<<<dim3(32, 32), 256, 0, stream>>>(pq + (long)l * HID * HID, wq_hi, wq_lo, HID, HID);
        wsplit_kernel<<<dim3(32, 32), 256, 0, stream>>>(pk + (long)l * HID * HID, wkv_hi, wkv_lo, HID, HID);
        wsplit_kernel<<<dim3(32, 32), 256, 0, stream>>>(pv + (long)l * HID * HID,
                                                        wkv_hi + (size_t)1024 * 1024,
                                                        wkv_lo + (size_t)1024 * 1024, HID, HID);
        wsplit_kernel<<<dim3(32, 32), 256, 0, stream>>>(pc + (long)l * HID * HID, wc_hi, wc_lo, HID, HID);
        wsplit_kernel<<<dim3(FFW / 32, HID / 32), 256, 0, stream>>>(
            pf1 + (long)l * HID * FFW, wf1_hi, wf1_lo, HID, FFW);
        wsplit_kernel<<<dim3(HID / 32, FFW / 32), 256, 0, stream>>>(
            pf2 + (long)l * FFW * HID, wf2_hi, wf2_lo, FFW, HID);

        // Fused K+V projection: [4096,1024] @ [1024,2048] -> kv split
        hgemm8<<<dim3(2048 / 128, (NB * TT) / 128), 512, 0, stream>>>(
            x_hi, x_lo, wkv_hi, wkv_lo, kv_hi, kv_lo,
            NB * TT, 2048, HID, 1.f, nullptr, 0);
        // Q projection: split-K2 in one launch -> qa, qb (f32)
        hgemm<<<dim3(HID / 64, (NB * WINN) / 128, 2), 256, 0, stream>>>(
            x_hi, x_lo, wq_hi, wq_lo, qa, qb,
            NB * WINN, HID, HID, 512, 0.125f, nullptr, 0, 1);
        vtrans_kernel<<<dim3(HID / 32, (NB * TT) / 32), 256, 0, stream>>>(
            kv_hi + 1024, kv_lo + 1024, vt_hi, vt_lo, 2048);

        fattn_mfma<<<dim3(WINN / 64, NH, NB), 256, 0, stream>>>(
            qa, qb, kv_hi, kv_lo, 2048, vt_hi, vt_lo, o_hi, o_lo);

        // C-proj: split-K2 -> t0a, t0b (summed in ln_res)
        hgemm<<<dim3(HID / 64, (NB * WINN) / 128, 2), 256, 0, stream>>>(
            o_hi, o_lo, wc_hi, wc_lo, t0a, t0b,
            NB * WINN, HID, HID, 512, 1.f, nullptr, 0, 0);
        ln_res_kernel<<<NB * WINN, 256, 0, stream>>>(
            t0a, t0b, x_f, xs, xs_hi, xs_lo, nullptr,
            b1 + l * HID, s1 + l * HID, 1);

        hgemm8<<<dim3(FFW / 128, (NB * WINN) / 128), 512, 0, stream>>>(
            xs_hi, xs_lo, wf1_hi, wf1_lo, ff1_hi, ff1_lo,
            NB * WINN, FFW, HID, 1.f, bf1 + l * FFW, 1);
        // FF2: split-K2 in one launch -> t0a, t0b
        hgemm<<<dim3(HID / 64, (NB * WINN) / 128, 2), 256, 0, stream>>>(
            ff1_hi, ff1_lo, wf2_hi, wf2_lo, t0a, t0b,
            NB * WINN, HID, FFW, 2048, 1.f, bf2 + l * HID, 0, 0);
        ln_res_kernel<<<NB * WINN, 256, 0, stream>>>(
            t0a, t0b, xs, dec + (long)l * 2097152, nullptr, nullptr,
            (l == NL - 1) ? decb : nullptr, b2 + l * HID, s2 + l * HID, 0);
    }

    transp_kernel<<<dim3(VOC / 32, HID / 32), 256, 0, stream>>>(pdec, wdect, HID, VOC);
    mfma_gemm<<<dim3(VOC / 128, (NB * WINN) / 128), 256, 0, stream>>>(
        decb, wdect, logits, NB * WINN, VOC, HID);
}

// Round 10
// 2547.971 us; speedup vs baseline: 4.8576x; 1.0243x over previous
//
#include <hip/hip_runtime.h>
#include <hip/hip_bf16.h>

#define NL   6
#define NH   16
#define HID  1024
#define HD   64
#define FFW  4096
#define VOC  32000
#define WINN 512
#define EMB  128
#define NB   4
#define TT   1024   // WIN + WIN

typedef __attribute__((ext_vector_type(8))) _Float16 f16x8;
typedef __attribute__((ext_vector_type(8))) short    b16x8;
typedef __attribute__((ext_vector_type(4))) float    f32x4;

__device__ __forceinline__ ushort f2b(float f) {
    __hip_bfloat16 h = __float2bfloat16(f);
    return *reinterpret_cast<ushort*>(&h);
}
// split f32 into fp16 hi/lo:  f ~= hi + lo * 2^-11  (error ~ |f|*2^-22)
__device__ __forceinline__ void split16(float f, ushort& hb, ushort& lb) {
    _Float16 h = (_Float16)f;
    _Float16 l = (_Float16)((f - (float)h) * 2048.0f);
    hb = __builtin_bit_cast(ushort, h);
    lb = __builtin_bit_cast(ushort, l);
}
// async global->LDS, 16B per lane: LDS dest = (wave-uniform base) + lane*16
__device__ __forceinline__ void gload16(const void* g, void* l) {
    __builtin_amdgcn_global_load_lds(
        (const __attribute__((address_space(1))) unsigned int*)g,
        (__attribute__((address_space(3))) unsigned int*)l, 16, 0, 0);
}

// ---------------------------------------------------------------------------
// Embed (f32)
// ---------------------------------------------------------------------------
__global__ __launch_bounds__(256) void embed_kernel(
    const int* __restrict__ xin, const float* __restrict__ Wemb,
    const float* __restrict__ Wlin, float* __restrict__ h0)
{
    int row = blockIdx.x;
    int tok = xin[row];
    __shared__ float tk[EMB];
    if (threadIdx.x < EMB) tk[threadIdx.x] = Wemb[tok * EMB + threadIdx.x] * 0.03125f;
    __syncthreads();
    for (int j = 0; j < 4; ++j) {
        int c = threadIdx.x + 256 * j;
        float acc = 0.f;
        for (int e = 0; e < EMB; ++e) acc += tk[e] * Wlin[e * HID + c];
        h0[(long)row * HID + c] = acc;
    }
}

// ---------------------------------------------------------------------------
// x = pos + concat(prev, cur); outputs f32 + fp16 hi/lo split
// ---------------------------------------------------------------------------
__global__ __launch_bounds__(256) void build_x_kernel(
    const float* __restrict__ pos, const float* __restrict__ prev,
    const float* __restrict__ cur, float* __restrict__ x,
    ushort* __restrict__ xh, ushort* __restrict__ xl)
{
    int i4 = blockIdx.x * blockDim.x + threadIdx.x;
    if (i4 >= NB * TT * HID / 4) return;
    int h4 = i4 % (HID / 4);
    int bt = i4 / (HID / 4);
    int t = bt % TT, b = bt / TT;
    float4 p = ((const float4*)pos)[t * (HID / 4) + h4];
    float4 s;
    if (t < WINN) s = ((const float4*)prev)[(long)(b * WINN + t) * (HID / 4) + h4];
    else          s = ((const float4*)cur)[(long)(b * WINN + (t - WINN)) * (HID / 4) + h4];
    float4 r; r.x = p.x + s.x; r.y = p.y + s.y; r.z = p.z + s.z; r.w = p.w + s.w;
    ((float4*)x)[i4] = r;
    ushort4 uh, ul;
    split16(r.x, uh.x, ul.x); split16(r.y, uh.y, ul.y);
    split16(r.z, uh.z, ul.z); split16(r.w, uh.w, ul.w);
    ((ushort4*)xh)[i4] = uh;
    ((ushort4*)xl)[i4] = ul;
}

// ---------------------------------------------------------------------------
// Weight transpose + fp16 split: W f32 [K,N] -> Wt_hi/Wt_lo fp16 [N,K]
// ---------------------------------------------------------------------------
__global__ __launch_bounds__(256) void wsplit_kernel(
    const float* __restrict__ W, ushort* __restrict__ Wth, ushort* __restrict__ Wtl,
    int K, int N)
{
    __shared__ float ts[32][33];
    int n0 = blockIdx.x * 32, k0 = blockIdx.y * 32;
    int tr = threadIdx.x >> 5, tc = threadIdx.x & 31;
#pragma unroll
    for (int j = 0; j < 4; ++j)
        ts[tr + j * 8][tc] = W[(long)(k0 + tr + j * 8) * N + n0 + tc];
    __syncthreads();
#pragma unroll
    for (int j = 0; j < 4; ++j) {
        int n = tr + j * 8;
        ushort hb, lb;
        split16(ts[tc][n], hb, lb);
        long idx = (long)(n0 + n) * K + k0 + tc;
        Wth[idx] = hb;
        Wtl[idx] = lb;
    }
}

// ---------------------------------------------------------------------------
// ushort-pair transpose with source row stride
// ---------------------------------------------------------------------------
__global__ __launch_bounds__(256) void vtrans_kernel(
    const ushort* __restrict__ vh, const ushort* __restrict__ vl,
    ushort* __restrict__ vth, ushort* __restrict__ vtl, int src_stride)
{
    __shared__ ushort th[32][33], tl[32][33];
    int n0 = blockIdx.x * 32, r0 = blockIdx.y * 32;
    int tr = threadIdx.x >> 5, tc = threadIdx.x & 31;
#pragma unroll
    for (int j = 0; j < 4; ++j) {
        long g = (long)(r0 + tr + j * 8) * src_stride + n0 + tc;
        th[tr + j * 8][tc] = vh[g];
        tl[tr + j * 8][tc] = vl[g];
    }
    __syncthreads();
#pragma unroll
    for (int j = 0; j < 4; ++j) {
        long g = (long)(n0 + tr + j * 8) * (NB * TT) + r0 + tc;
        vth[g] = th[tc][tr + j * 8];
        vtl[g] = tl[tc][tr + j * 8];
    }
}

// ---------------------------------------------------------------------------
// Split-fp16 MFMA GEMM, 128x64 tile, 4 waves, f32 out, gridDim.z split-K.
// global_load_lds staging, linear LDS (stride 32 ushorts).
// ---------------------------------------------------------------------------
__global__ __launch_bounds__(256) void hgemm(
    const ushort* __restrict__ Ah, const ushort* __restrict__ Al,
    const ushort* __restrict__ Bh, const ushort* __restrict__ Bl,
    float* __restrict__ Cf0, float* __restrict__ Cf1,
    int M, int N, int K_stride, int Ksub,
    float scale, const float* __restrict__ bias, int relu, int amap)
{
    __shared__ __align__(16) ushort Ash[128 * 32];
    __shared__ __align__(16) ushort Asl[128 * 32];
    __shared__ __align__(16) ushort Bsh[64 * 32];
    __shared__ __align__(16) ushort Bsl[64 * 32];
    const int tid  = threadIdx.x;
    const int rb   = blockIdx.y * 128;
    const int cb   = blockIdx.x * 64;
    const int z    = blockIdx.z;
    const int k_off = z * Ksub;
    float* __restrict__ Cf = z ? Cf1 : Cf0;
    const float* bias_eff = (z == 0) ? bias : nullptr;
    const int wave = tid >> 6, lane = tid & 63;
    const int wr   = (wave >> 1) * 64;
    const int wc   = (wave & 1) * 32;
    const int lr   = lane & 15;
    const int kh   = lane >> 4;

    // staging: wave covers A rows [w*32, w*32+32) (2 chunks x hi/lo) and
    // B rows [w*16, w*16+16) (1 chunk x hi/lo). lane -> row base+(lane>>2),
    // k-chunk (lane&3)*8.
    const int lrow = lane >> 2;
    const int lkc  = (lane & 3) * 8;
    int ga0 = rb + wave * 32 + lrow;
    int ga1 = ga0 + 16;
    long ma0 = amap ? (long)((ga0 >> 9) * 1024 + 512 + (ga0 & 511)) : (long)ga0;
    long ma1 = amap ? (long)((ga1 >> 9) * 1024 + 512 + (ga1 & 511)) : (long)ga1;
    const ushort* gAh0 = Ah + ma0 * K_stride + k_off + lkc;
    const ushort* gAh1 = Ah + ma1 * K_stride + k_off + lkc;
    const ushort* gAl0 = Al + ma0 * K_stride + k_off + lkc;
    const ushort* gAl1 = Al + ma1 * K_stride + k_off + lkc;
    const ushort* gBh0 = Bh + (long)(cb + wave * 16 + lrow) * K_stride + k_off + lkc;
    const ushort* gBl0 = Bl + (long)(cb + wave * 16 + lrow) * K_stride + k_off + lkc;
    ushort* lAh0 = Ash + wave * 1024;
    ushort* lAh1 = Ash + wave * 1024 + 512;
    ushort* lAl0 = Asl + wave * 1024;
    ushort* lAl1 = Asl + wave * 1024 + 512;
    ushort* lBh0 = Bsh + wave * 512;
    ushort* lBl0 = Bsl + wave * 512;

    int aoff[4], boff[2];
#pragma unroll
    for (int m = 0; m < 4; ++m) aoff[m] = (wr + m * 16 + lr) * 32 + kh * 8;
#pragma unroll
    for (int n = 0; n < 2; ++n) boff[n] = (wc + n * 16 + lr) * 32 + kh * 8;

    f32x4 accH[4][2], accL[4][2];
#pragma unroll
    for (int m = 0; m < 4; ++m)
#pragma unroll
        for (int n = 0; n < 2; ++n) {
            accH[m][n] = (f32x4){0.f, 0.f, 0.f, 0.f};
            accL[m][n] = (f32x4){0.f, 0.f, 0.f, 0.f};
        }

    for (int k0 = 0; k0 < Ksub; k0 += 32) {
        __syncthreads();
        gload16(gAh0 + k0, lAh0);
        gload16(gAh1 + k0, lAh1);
        gload16(gAl0 + k0, lAl0);
        gload16(gAl1 + k0, lAl1);
        gload16(gBh0 + k0, lBh0);
        gload16(gBl0 + k0, lBl0);
        __syncthreads();
        f16x8 afh[4], afl[4], bfh[2], bfl[2];
#pragma unroll
        for (int m = 0; m < 4; ++m) {
            afh[m] = *(const f16x8*)(Ash + aoff[m]);
            afl[m] = *(const f16x8*)(Asl + aoff[m]);
        }
#pragma unroll
        for (int n = 0; n < 2; ++n) {
            bfh[n] = *(const f16x8*)(Bsh + boff[n]);
            bfl[n] = *(const f16x8*)(Bsl + boff[n]);
        }
#pragma unroll
        for (int m = 0; m < 4; ++m)
#pragma unroll
            for (int n = 0; n < 2; ++n) {
                accH[m][n] = __builtin_amdgcn_mfma_f32_16x16x32_f16(afh[m], bfh[n], accH[m][n], 0, 0, 0);
                accL[m][n] = __builtin_amdgcn_mfma_f32_16x16x32_f16(afh[m], bfl[n], accL[m][n], 0, 0, 0);
                accL[m][n] = __builtin_amdgcn_mfma_f32_16x16x32_f16(afl[m], bfh[n], accL[m][n], 0, 0, 0);
            }
    }

#pragma unroll
    for (int m = 0; m < 4; ++m) {
        int row0 = rb + wr + m * 16 + kh * 4;
#pragma unroll
        for (int n = 0; n < 2; ++n) {
            int col = cb + wc + n * 16 + lr;
            float bv = bias_eff ? bias_eff[col] : 0.f;
#pragma unroll
            for (int r = 0; r < 4; ++r) {
                float v = (accH[m][n][r] + accL[m][n][r] * (1.f / 2048.f)) * scale + bv;
                if (relu) v = fmaxf(v, 0.f);
                Cf[(long)(row0 + r) * N + col] = v;
            }
        }
    }
}

// ---------------------------------------------------------------------------
// Split-fp16 MFMA GEMM, 128x128 tile, 8 waves (2x4), wave = 64x32.
// global_load_lds staging, linear LDS. Outputs fp16 hi/lo split.
// ---------------------------------------------------------------------------
__global__ __launch_bounds__(512) void hgemm8(
    const ushort* __restrict__ Ah, const ushort* __restrict__ Al,
    const ushort* __restrict__ Bh, const ushort* __restrict__ Bl,
    ushort* __restrict__ Chh, ushort* __restrict__ Cll,
    int M, int N, int K_stride,
    float scale, const float* __restrict__ bias, int relu)
{
    __shared__ __align__(16) ushort Ash[128 * 32];
    __shared__ __align__(16) ushort Asl[128 * 32];
    __shared__ __align__(16) ushort Bsh[128 * 32];
    __shared__ __align__(16) ushort Bsl[128 * 32];
    const int tid  = threadIdx.x;
    const int rb   = blockIdx.y * 128;
    const int cb   = blockIdx.x * 128;
    const int wave = tid >> 6, lane = tid & 63;
    const int wr   = (wave >> 2) * 64;
    const int wc   = (wave & 3) * 32;
    const int lr   = lane & 15;
    const int kh   = lane >> 4;

    // staging: wave covers rows [w*16, w*16+16) of each of the 4 buffers.
    const int lrow = lane >> 2;
    const int lkc  = (lane & 3) * 8;
    const ushort* gA_h = Ah + (long)(rb + wave * 16 + lrow) * K_stride + lkc;
    const ushort* gA_l = Al + (long)(rb + wave * 16 + lrow) * K_stride + lkc;
    const ushort* gB_h = Bh + (long)(cb + wave * 16 + lrow) * K_stride + lkc;
    const ushort* gB_l = Bl + (long)(cb + wave * 16 + lrow) * K_stride + lkc;
    ushort* lA_h = Ash + wave * 512;
    ushort* lA_l = Asl + wave * 512;
    ushort* lB_h = Bsh + wave * 512;
    ushort* lB_l = Bsl + wave * 512;

    int aoff[4], boff[2];
#pragma unroll
    for (int m = 0; m < 4; ++m) aoff[m] = (wr + m * 16 + lr) * 32 + kh * 8;
#pragma unroll
    for (int n = 0; n < 2; ++n) boff[n] = (wc + n * 16 + lr) * 32 + kh * 8;

    f32x4 accH[4][2], accL[4][2];
#pragma unroll
    for (int m = 0; m < 4; ++m)
#pragma unroll
        for (int n = 0; n < 2; ++n) {
            accH[m][n] = (f32x4){0.f, 0.f, 0.f, 0.f};
            accL[m][n] = (f32x4){0.f, 0.f, 0.f, 0.f};
        }

    for (int k0 = 0; k0 < K_stride; k0 += 32) {
        __syncthreads();
        gload16(gA_h + k0, lA_h);
        gload16(gA_l + k0, lA_l);
        gload16(gB_h + k0, lB_h);
        gload16(gB_l + k0, lB_l);
        __syncthreads();
        f16x8 afh[4], afl[4], bfh[2], bfl[2];
#pragma unroll
        for (int m = 0; m < 4; ++m) {
            afh[m] = *(const f16x8*)(Ash + aoff[m]);
            afl[m] = *(const f16x8*)(Asl + aoff[m]);
        }
#pragma unroll
        for (int n = 0; n < 2; ++n) {
            bfh[n] = *(const f16x8*)(Bsh + boff[n]);
            bfl[n] = *(const f16x8*)(Bsl + boff[n]);
        }
#pragma unroll
        for (int m = 0; m < 4; ++m)
#pragma unroll
            for (int n = 0; n < 2; ++n) {
                accH[m][n] = __builtin_amdgcn_mfma_f32_16x16x32_f16(afh[m], bfh[n], accH[m][n], 0, 0, 0);
                accL[m][n] = __builtin_amdgcn_mfma_f32_16x16x32_f16(afh[m], bfl[n], accL[m][n], 0, 0, 0);
                accL[m][n] = __builtin_amdgcn_mfma_f32_16x16x32_f16(afl[m], bfh[n], accL[m][n], 0, 0, 0);
            }
    }

#pragma unroll
    for (int m = 0; m < 4; ++m) {
        int row0 = rb + wr + m * 16 + kh * 4;
#pragma unroll
        for (int n = 0; n < 2; ++n) {
            int col = cb + wc + n * 16 + lr;
            float bv = bias ? bias[col] : 0.f;
#pragma unroll
            for (int r = 0; r < 4; ++r) {
                float v = (accH[m][n][r] + accL[m][n][r] * (1.f / 2048.f)) * scale + bv;
                if (relu) v = fmaxf(v, 0.f);
                long idx = (long)(row0 + r) * N + col;
                ushort hb, lb; split16(v, hb, lb);
                Chh[idx] = hb; Cll[idx] = lb;
            }
        }
    }
}

// ---------------------------------------------------------------------------
// MFMA flash attention (unchanged from R9).
// ---------------------------------------------------------------------------
__global__ __launch_bounds__(256) void fattn_mfma(
    const float* __restrict__ qa, const float* __restrict__ qb,
    const ushort* __restrict__ kbh, const ushort* __restrict__ kbl, int kstr,
    const ushort* __restrict__ vth, const ushort* __restrict__ vtl,
    ushort* __restrict__ oh, ushort* __restrict__ ol)
{
    __shared__ __align__(16) ushort ksh[64 * 72];
    __shared__ __align__(16) ushort ksl[64 * 72];
    __shared__ __align__(16) ushort vsh[64 * 72];
    __shared__ __align__(16) ushort vsl[64 * 72];
    const int qt = blockIdx.x, h = blockIdx.y, b = blockIdx.z;
    const int tid = threadIdx.x;
    const int wave = tid >> 6, lane = tid & 63;
    const int lr = lane & 15, kg4 = lane >> 4;
    const int qbase = b * WINN + qt * 64;

    f16x8 qfh[2], qfl[2];
#pragma unroll
    for (int c = 0; c < 2; ++c) {
        long ga = (long)(qbase + wave * 16 + lr) * HID + h * HD + c * 32 + kg4 * 8;
        float4 a0 = *(const float4*)(qa + ga);
        float4 a1 = *(const float4*)(qa + ga + 4);
        float4 b0 = *(const float4*)(qb + ga);
        float4 b1 = *(const float4*)(qb + ga + 4);
        float qv[8] = {a0.x + b0.x, a0.y + b0.y, a0.z + b0.z, a0.w + b0.w,
                       a1.x + b1.x, a1.y + b1.y, a1.z + b1.z, a1.w + b1.w};
        ushort uh[8], ul[8];
#pragma unroll
        for (int j = 0; j < 8; ++j) split16(qv[j], uh[j], ul[j]);
        qfh[c] = *(const f16x8*)uh;
        qfl[c] = *(const f16x8*)ul;
    }

    f32x4 accOH[4], accOL[4];
#pragma unroll
    for (int d = 0; d < 4; ++d) {
        accOH[d] = (f32x4){0.f, 0.f, 0.f, 0.f};
        accOL[d] = (f32x4){0.f, 0.f, 0.f, 0.f};
    }
    float mrow[4], lrow[4];
#pragma unroll
    for (int r = 0; r < 4; ++r) { mrow[r] = -3.0e38f; lrow[r] = 0.f; }

    const int sr = tid >> 2;
    const int sd = (tid & 3) * 16;

    const int ktmax = 9 + qt;
    for (int kt = 0; kt < ktmax; ++kt) {
        __syncthreads();
        {
            long gk = (long)(b * TT + kt * 64 + sr) * kstr + h * HD + sd;
            uint4 h0 = *(const uint4*)(kbh + gk);
            uint4 h1 = *(const uint4*)(kbh + gk + 8);
            uint4 l0 = *(const uint4*)(kbl + gk);
            uint4 l1 = *(const uint4*)(kbl + gk + 8);
            long gv = (long)(h * HD + sr) * (NB * TT) + b * TT + kt * 64 + sd;
            uint4 vh0 = *(const uint4*)(vth + gv);
            uint4 vh1 = *(const uint4*)(vth + gv + 8);
            uint4 vl0 = *(const uint4*)(vtl + gv);
            uint4 vl1 = *(const uint4*)(vtl + gv + 8);
            *(uint4*)(ksh + sr * 72 + sd) = h0;
            *(uint4*)(ksh + sr * 72 + sd + 8) = h1;
            *(uint4*)(ksl + sr * 72 + sd) = l0;
            *(uint4*)(ksl + sr * 72 + sd + 8) = l1;
            *(uint4*)(vsh + sr * 72 + sd) = vh0;
            *(uint4*)(vsh + sr * 72 + sd + 8) = vh1;
            *(uint4*)(vsl + sr * 72 + sd) = vl0;
            *(uint4*)(vsl + sr * 72 + sd + 8) = vl1;
        }
        __syncthreads();

        f32x4 sH[4], sL[4];
#pragma unroll
        for (int n = 0; n < 4; ++n) {
            sH[n] = (f32x4){0.f, 0.f, 0.f, 0.f};
            sL[n] = (f32x4){0.f, 0.f, 0.f, 0.f};
        }
#pragma unroll
        for (int c = 0; c < 2; ++c) {
#pragma unroll
            for (int n = 0; n < 4; ++n) {
                int ad = (n * 16 + lr) * 72 + c * 32 + kg4 * 8;
                f16x8 bh = *(const f16x8*)(ksh + ad);
                f16x8 bl = *(const f16x8*)(ksl + ad);
                sH[n] = __builtin_amdgcn_mfma_f32_16x16x32_f16(qfh[c], bh, sH[n], 0, 0, 0);
                sL[n] = __builtin_amdgcn_mfma_f32_16x16x32_f16(qfh[c], bl, sL[n], 0, 0, 0);
                sL[n] = __builtin_amdgcn_mfma_f32_16x16x32_f16(qfl[c], bh, sL[n], 0, 0, 0);
            }
        }
        float S[4][4];
#pragma unroll
        for (int n = 0; n < 4; ++n)
#pragma unroll
            for (int r = 0; r < 4; ++r)
                S[n][r] = sH[n][r] + sL[n][r] * (1.f / 2048.f);

        if (kt == ktmax - 1) {
#pragma unroll
            for (int r = 0; r < 4; ++r) {
                int qi = WINN + qt * 64 + wave * 16 + kg4 * 4 + r;
#pragma unroll
                for (int n = 0; n < 4; ++n) {
                    int kg = kt * 64 + n * 16 + lr;
                    if (kg > qi) S[n][r] = -1e9f;
                }
            }
        }

#pragma unroll
        for (int r = 0; r < 4; ++r) {
            float mx = fmaxf(fmaxf(S[0][r], S[1][r]), fmaxf(S[2][r], S[3][r]));
            mx = fmaxf(mx, __shfl_xor(mx, 1));
            mx = fmaxf(mx, __shfl_xor(mx, 2));
            mx = fmaxf(mx, __shfl_xor(mx, 4));
            mx = fmaxf(mx, __shfl_xor(mx, 8));
            float mnew = fmaxf(mrow[r], mx);
            float alpha = __expf(mrow[r] - mnew);
            float rs = 0.f;
#pragma unroll
            for (int n = 0; n < 4; ++n) { S[n][r] = __expf(S[n][r] - mnew); rs += S[n][r]; }
            rs += __shfl_xor(rs, 1);
            rs += __shfl_xor(rs, 2);
            rs += __shfl_xor(rs, 4);
            rs += __shfl_xor(rs, 8);
            lrow[r] = lrow[r] * alpha + rs;
            mrow[r] = mnew;
#pragma unroll
            for (int d = 0; d < 4; ++d) { accOH[d][r] *= alpha; accOL[d][r] *= alpha; }
        }

        __syncthreads();
#pragma unroll
        for (int n = 0; n < 4; ++n)
#pragma unroll
            for (int r = 0; r < 4; ++r) {
                ushort hb, lb;
                split16(S[n][r], hb, lb);
                int ad = (wave * 16 + kg4 * 4 + r) * 72 + n * 16 + lr;
                ksh[ad] = hb;
                ksl[ad] = lb;
            }
        f16x8 pfh[2], pfl[2];
#pragma unroll
        for (int c = 0; c < 2; ++c) {
            int ad = (wave * 16 + lr) * 72 + c * 32 + kg4 * 8;
            pfh[c] = *(const f16x8*)(ksh + ad);
            pfl[c] = *(const f16x8*)(ksl + ad);
        }
#pragma unroll
        for (int c = 0; c < 2; ++c) {
#pragma unroll
            for (int d = 0; d < 4; ++d) {
                int ad = (d * 16 + lr) * 72 + c * 32 + kg4 * 8;
                f16x8 vh = *(const f16x8*)(vsh + ad);
                f16x8 vl = *(const f16x8*)(vsl + ad);
                accOH[d] = __builtin_amdgcn_mfma_f32_16x16x32_f16(pfh[c], vh, accOH[d], 0, 0, 0);
                accOL[d] = __builtin_amdgcn_mfma_f32_16x16x32_f16(pfh[c], vl, accOL[d], 0, 0, 0);
                accOL[d] = __builtin_amdgcn_mfma_f32_16x16x32_f16(pfl[c], vh, accOL[d], 0, 0, 0);
            }
        }
    }

#pragma unroll
    for (int r = 0; r < 4; ++r) {
        float inv = 1.f / lrow[r];
        long rowb = (long)(qbase + wave * 16 + kg4 * 4 + r) * HID + h * HD + lr;
#pragma unroll
        for (int d = 0; d < 4; ++d) {
            float v = (accOH[d][r] + accOL[d][r] * (1.f / 2048.f)) * inv;
            ushort hb, lb;
            split16(v, hb, lb);
            oh[rowb + d * 16] = hb;
            ol[rowb + d * 16] = lb;
        }
    }
}

// ---------------------------------------------------------------------------
// Transpose+convert (bf16, logits W)
// ---------------------------------------------------------------------------
__global__ __launch_bounds__(256) void transp_kernel(
    const float* __restrict__ W, ushort* __restrict__ Wt, int K, int N)
{
    __shared__ float ts[32][33];
    int n0 = blockIdx.x * 32, k0 = blockIdx.y * 32;
    int tr = threadIdx.x >> 5, tc = threadIdx.x & 31;
#pragma unroll
    for (int j = 0; j < 4; ++j)
        ts[tr + j * 8][tc] = W[(long)(k0 + tr + j * 8) * N + n0 + tc];
    __syncthreads();
#pragma unroll
    for (int j = 0; j < 4; ++j) {
        int n = tr + j * 8;
        Wt[(long)(n0 + n) * K + k0 + tc] = f2b(ts[tc][n]);
    }
}

// ---------------------------------------------------------------------------
// bf16 MFMA GEMM (logits). B-reuse-ordered XCD swizzle + global_load_lds.
// Grid (N/128, M/128); M/128 must be 16, grid total divisible by 8.
// ---------------------------------------------------------------------------
__global__ __launch_bounds__(256) void mfma_gemm(
    const ushort* __restrict__ A, const ushort* __restrict__ Bt,
    float* __restrict__ Cf, int M, int N, int K)
{
    __shared__ __align__(16) ushort As[128 * 32];
    __shared__ __align__(16) ushort Bs[128 * 32];
    const int tid  = threadIdx.x;
    const int ntm  = M >> 7;                 // row tiles (16)
    const int nbx  = gridDim.x;
    const int nwg  = nbx * gridDim.y;
    const int bid  = blockIdx.y * nbx + blockIdx.x;
    const int cpx  = nwg >> 3;
    const int swz  = (bid & 7) * cpx + (bid >> 3);
    const int rb   = (swz % ntm) * 128;      // rb fastest: consecutive blocks
    const int cb   = (swz / ntm) * 128;      // share the same B tile
    const int wave = tid >> 6, lane = tid & 63;
    const int wr   = (wave >> 1) * 64;
    const int wc   = (wave & 1) * 64;
    const int lr   = lane & 15;
    const int kh   = lane >> 4;

    // staging: wave covers A rows [w*32,w*32+32) and B rows [w*32,w*32+32)
    const int lrow = lane >> 2;
    const int lkc  = (lane & 3) * 8;
    const ushort* gA0 = A + (long)(rb + wave * 32 + lrow) * K + lkc;
    const ushort* gA1 = A + (long)(rb + wave * 32 + 16 + lrow) * K + lkc;
    const ushort* gB0 = Bt + (long)(cb + wave * 32 + lrow) * K + lkc;
    const ushort* gB1 = Bt + (long)(cb + wave * 32 + 16 + lrow) * K + lkc;
    ushort* lA0 = As + wave * 1024;
    ushort* lA1 = As + wave * 1024 + 512;
    ushort* lB0 = Bs + wave * 1024;
    ushort* lB1 = Bs + wave * 1024 + 512;

    int aoff[4], boff[4];
#pragma unroll
    for (int m = 0; m < 4; ++m) aoff[m] = (wr + m * 16 + lr) * 32 + kh * 8;
#pragma unroll
    for (int n = 0; n < 4; ++n) boff[n] = (wc + n * 16 + lr) * 32 + kh * 8;

    f32x4 acc[4][4];
#pragma unroll
    for (int m = 0; m < 4; ++m)
#pragma unroll
        for (int n = 0; n < 4; ++n)
            acc[m][n] = (f32x4){0.f, 0.f, 0.f, 0.f};

    for (int k0 = 0; k0 < K; k0 += 32) {
        __syncthreads();
        gload16(gA0 + k0, lA0);
        gload16(gA1 + k0, lA1);
        gload16(gB0 + k0, lB0);
        gload16(gB1 + k0, lB1);
        __syncthreads();
        b16x8 af[4], bfr[4];
#pragma unroll
        for (int m = 0; m < 4; ++m) af[m] = *(const b16x8*)(As + aoff[m]);
#pragma unroll
        for (int n = 0; n < 4; ++n) bfr[n] = *(const b16x8*)(Bs + boff[n]);
#pragma unroll
        for (int m = 0; m < 4; ++m)
#pragma unroll
            for (int n = 0; n < 4; ++n)
                acc[m][n] = __builtin_amdgcn_mfma_f32_16x16x32_bf16(af[m], bfr[n], acc[m][n], 0, 0, 0);
    }

#pragma unroll
    for (int m = 0; m < 4; ++m) {
        int row0 = rb + wr + m * 16 + kh * 4;
#pragma unroll
        for (int n = 0; n < 4; ++n) {
            int col = cb + wc + n * 16 + lr;
#pragma unroll
            for (int r = 0; r < 4; ++r)
                Cf[(long)(row0 + r) * N + col] = acc[m][n][r];
        }
    }
}

// ---------------------------------------------------------------------------
// out = res[r'] + LN(t (+t2))*scale + bias; outputs f32 / fp16-split / bf16
// ---------------------------------------------------------------------------
__global__ __launch_bounds__(256) void ln_res_kernel(
    const float* __restrict__ t, const float* __restrict__ t2,
    const float* __restrict__ res, float* __restrict__ out,
    ushort* __restrict__ outh, ushort* __restrict__ outl, ushort* __restrict__ outb,
    const float* __restrict__ bias, const float* __restrict__ scale, int res_map)
{
    int r = blockIdx.x;
    int tid = threadIdx.x;
    long rr = res_map ? (long)((r >> 9) * 1024 + 512 + (r & 511)) : (long)r;
    float4 v = ((const float4*)(t + (long)r * HID))[tid];
    if (t2) {
        float4 w = ((const float4*)(t2 + (long)r * HID))[tid];
        v.x += w.x; v.y += w.y; v.z += w.z; v.w += w.w;
    }
    __shared__ float red[4];
    float s = v.x + v.y + v.z + v.w;
    for (int off = 32; off > 0; off >>= 1) s += __shfl_xor(s, off);
    if ((tid & 63) == 0) red[tid >> 6] = s;
    __syncthreads();
    float mean = (red[0] + red[1] + red[2] + red[3]) * (1.f / HID);
    __syncthreads();
    float dx = v.x - mean, dy = v.y - mean, dz = v.z - mean, dw = v.w - mean;
    float qs = dx * dx + dy * dy + dz * dz + dw * dw;
    for (int off = 32; off > 0; off >>= 1) qs += __shfl_xor(qs, off);
    if ((tid & 63) == 0) red[tid >> 6] = qs;
    __syncthreads();
    float var = (red[0] + red[1] + red[2] + red[3]) * (1.f / HID);
    float rs = rsqrtf(var + 1e-6f);
    float4 rv = ((const float4*)(res + rr * HID))[tid];
    float4 sc4 = ((const float4*)scale)[tid];
    float4 b4  = ((const float4*)bias)[tid];
    float4 o4;
    o4.x = rv.x + dx * rs * sc4.x + b4.x;
    o4.y = rv.y + dy * rs * sc4.y + b4.y;
    o4.z = rv.z + dz * rs * sc4.z + b4.z;
    o4.w = rv.w + dw * rs * sc4.w + b4.w;
    ((float4*)(out + (long)r * HID))[tid] = o4;
    if (outh) {
        ushort4 uh, ul;
        split16(o4.x, uh.x, ul.x); split16(o4.y, uh.y, ul.y);
        split16(o4.z, uh.z, ul.z); split16(o4.w, uh.w, ul.w);
        ((ushort4*)(outh + (long)r * HID))[tid] = uh;
        ((ushort4*)(outl + (long)r * HID))[tid] = ul;
    }
    if (outb) {
        ushort4 u; u.x = f2b(o4.x); u.y = f2b(o4.y); u.z = f2b(o4.z); u.w = f2b(o4.w);
        ((ushort4*)(outb + (long)r * HID))[tid] = u;
    }
}

// ---------------------------------------------------------------------------
// Workspace layout identical to R9 (168 MiB, proven safe).
// ---------------------------------------------------------------------------
extern "C" void kernel_launch(void* const* d_in, const int* in_sizes, int n_in,
                              void* d_out, int out_size, void* d_ws, size_t ws_size,
                              hipStream_t stream)
{
    const int*   x_input = (const int*)  d_in[0];
    const float* prev    = (const float*)d_in[1];
    const float* Wemb    = (const float*)d_in[2];
    const float* Wlin    = (const float*)d_in[3];
    const float* pdec    = (const float*)d_in[4];
    const float* pq      = (const float*)d_in[5];
    const float* pk      = (const float*)d_in[6];
    const float* pv      = (const float*)d_in[7];
    const float* pc      = (const float*)d_in[8];
    const float* pf1     = (const float*)d_in[9];
    const float* pf2     = (const float*)d_in[10];
    const float* bf1     = (const float*)d_in[11];
    const float* bf2     = (const float*)d_in[12];
    const float* b1      = (const float*)d_in[13];
    const float* b2      = (const float*)d_in[14];
    const float* s1      = (const float*)d_in[15];
    const float* s2      = (const float*)d_in[16];
    const float* pos     = (const float*)d_in[17];

    float* outp   = (float*)d_out;
    float* logits = outp;
    float* dec    = outp + (long)2048 * VOC;

    char* base = (char*)d_ws;
    float*  x_f   = (float*) (base + 0);
    ushort* x_hi  = (ushort*)(base + 16777216);
    ushort* x_lo  = (ushort*)(base + 25165824);
    ushort* kv_hi = (ushort*)(base + 33554432);
    ushort* kv_lo = (ushort*)(base + 50331648);
    ushort* vt_hi = (ushort*)(base + 67108864);
    ushort* vt_lo = (ushort*)(base + 75497472);
    ushort* o_hi  = (ushort*)(base + 83886080);
    ushort* o_lo  = (ushort*)(base + 88080384);
    float*  t0a   = (float*) (base + 92274688);
    float*  h0    = t0a;
    float*  qa    = t0a;
    float*  t0b   = (float*) (base + 100663296);
    float*  qb    = t0b;
    float*  xs    = (float*) (base + 109051904);
    ushort* xs_hi = (ushort*)(base + 117440512);
    ushort* xs_lo = (ushort*)(base + 121634816);
    ushort* wq_hi = (ushort*)(base + 125829120);
    ushort* wq_lo = (ushort*)(base + 127926272);
    ushort* wkv_hi= (ushort*)(base + 130023424);
    ushort* wkv_lo= (ushort*)(base + 134217728);
    ushort* wc_hi = (ushort*)(base + 138412032);
    ushort* wc_lo = (ushort*)(base + 140509184);
    ushort* wf1_hi= (ushort*)(base + 142606336);
    ushort* wf1_lo= (ushort*)(base + 150994944);
    ushort* wf2_hi= (ushort*)(base + 159383552);
    ushort* wf2_lo= (ushort*)(base + 167772160);   // ends 176,160,768
    // overlays
    ushort* ff1_hi= (ushort*)(base + 33554432);
    ushort* ff1_lo= (ushort*)(base + 50331648);
    ushort* decb  = (ushort*)(base + 83886080);
    ushort* wdect = (ushort*)(base + 0);

    embed_kernel<<<NB * WINN, 256, 0, stream>>>(x_input, Wemb, Wlin, h0);

    for (int l = 0; l < NL; ++l) {
        const float* cur = (l == 0) ? h0 : (dec + (long)(l - 1) * 2097152);
        build_x_kernel<<<(NB * TT * HID / 4) / 256, 256, 0, stream>>>(
            pos + (long)l * TT * HID, prev + (long)l * NB * WINN * HID, cur,
            x_f, x_hi, x_lo);

        wsplit_kernel<<<dim3(32, 32), 256, 0, stream>>>(pq + (long)l * HID * HID, wq_hi, wq_lo, HID, HID);
        wsplit_kernel<<<dim3(32, 32), 256, 0, stream>>>(pk + (long)l * HID * HID, wkv_hi, wkv_lo, HID, HID);
        wsplit_kernel<<<dim3(32, 32), 256, 0, stream>>>(pv + (long)l * HID * HID,
                                                        wkv_hi + (size_t)1024 * 1024,
                                                        wkv_lo + (size_t)1024 * 1024, HID, HID);
        wsplit_kernel<<<dim3(32, 32), 256, 0, stream>>>(pc + (long)l * HID * HID, wc_hi, wc_lo, HID, HID);
        wsplit_kernel<<<dim3(FFW / 32, HID / 32), 256, 0, stream>>>(
            pf1 + (long)l * HID * FFW, wf1_hi, wf1_lo, HID, FFW);
        wsplit_kernel<<<dim3(HID / 32, FFW / 32), 256, 0, stream>>>(
            pf2 + (long)l * FFW * HID, wf2_hi, wf2_lo, FFW, HID);

        hgemm8<<<dim3(2048 / 128, (NB * TT) / 128), 512, 0, stream>>>(
            x_hi, x_lo, wkv_hi, wkv_lo, kv_hi, kv_lo,
            NB * TT, 2048, HID, 1.f, nullptr, 0);
        hgemm<<<dim3(HID / 64, (NB * WINN) / 128, 2), 256, 0, stream>>>(
            x_hi, x_lo, wq_hi, wq_lo, qa, qb,
            NB * WINN, HID, HID, 512, 0.125f, nullptr, 0, 1);
        vtrans_kernel<<<dim3(HID / 32, (NB * TT) / 32), 256, 0, stream>>>(
            kv_hi + 1024, kv_lo + 1024, vt_hi, vt_lo, 2048);

        fattn_mfma<<<dim3(WINN / 64, NH, NB), 256, 0, stream>>>(
            qa, qb, kv_hi, kv_lo, 2048, vt_hi, vt_lo, o_hi, o_lo);

        hgemm<<<dim3(HID / 64, (NB * WINN) / 128, 2), 256, 0, stream>>>(
            o_hi, o_lo, wc_hi, wc_lo, t0a, t0b,
            NB * WINN, HID, HID, 512, 1.f, nullptr, 0, 0);
        ln_res_kernel<<<NB * WINN, 256, 0, stream>>>(
            t0a, t0b, x_f, xs, xs_hi, xs_lo, nullptr,
            b1 + l * HID, s1 + l * HID, 1);

        hgemm8<<<dim3(FFW / 128, (NB * WINN) / 128), 512, 0, stream>>>(
            xs_hi, xs_lo, wf1_hi, wf1_lo, ff1_hi, ff1_lo,
            NB * WINN, FFW, HID, 1.f, bf1 + l * FFW, 1);
        hgemm<<<dim3(HID / 64, (NB * WINN) / 128, 2), 256, 0, stream>>>(
            ff1_hi, ff1_lo, wf2_hi, wf2_lo, t0a, t0b,
            NB * WINN, HID, FFW, 2048, 1.f, bf2 + l * HID, 0, 0);
        ln_res_kernel<<<NB * WINN, 256, 0, stream>>>(
            t0a, t0b, xs, dec + (long)l * 2097152, nullptr, nullptr,
            (l == NL - 1) ? decb : nullptr, b2 + l * HID, s2 + l * HID, 0);
    }

    transp_kernel<<<dim3(VOC / 32, HID / 32), 256, 0, stream>>>(pdec, wdect, HID, VOC);
    mfma_gemm<<<dim3(VOC / 128, (NB * WINN) / 128), 256, 0, stream>>>(
        decb, wdect, logits, NB * WINN, VOC, HID);
}

// Round 11
// 2527.918 us; speedup vs baseline: 4.8961x; 1.0079x over previous
//
#include <hip/hip_runtime.h>
#include <hip/hip_bf16.h>

#define NL   6
#define NH   16
#define HID  1024
#define HD   64
#define FFW  4096
#define VOC  32000
#define WINN 512
#define EMB  128
#define NB   4
#define TT   1024   // WIN + WIN

typedef __attribute__((ext_vector_type(8))) _Float16 f16x8;
typedef __attribute__((ext_vector_type(8))) short    b16x8;
typedef __attribute__((ext_vector_type(4))) float    f32x4;

__device__ __forceinline__ ushort f2b(float f) {
    __hip_bfloat16 h = __float2bfloat16(f);
    return *reinterpret_cast<ushort*>(&h);
}
// split f32 into fp16 hi/lo:  f ~= hi + lo * 2^-11  (error ~ |f|*2^-22)
__device__ __forceinline__ void split16(float f, ushort& hb, ushort& lb) {
    _Float16 h = (_Float16)f;
    _Float16 l = (_Float16)((f - (float)h) * 2048.0f);
    hb = __builtin_bit_cast(ushort, h);
    lb = __builtin_bit_cast(ushort, l);
}
// async global->LDS, 16B per lane: LDS dest = (wave-uniform base) + lane*16
__device__ __forceinline__ void gload16(const void* g, void* l) {
    __builtin_amdgcn_global_load_lds(
        (const __attribute__((address_space(1))) unsigned int*)g,
        (__attribute__((address_space(3))) unsigned int*)l, 16, 0, 0);
}

// ---------------------------------------------------------------------------
// Embed (f32)
// ---------------------------------------------------------------------------
__global__ __launch_bounds__(256) void embed_kernel(
    const int* __restrict__ xin, const float* __restrict__ Wemb,
    const float* __restrict__ Wlin, float* __restrict__ h0)
{
    int row = blockIdx.x;
    int tok = xin[row];
    __shared__ float tk[EMB];
    if (threadIdx.x < EMB) tk[threadIdx.x] = Wemb[tok * EMB + threadIdx.x] * 0.03125f;
    __syncthreads();
    for (int j = 0; j < 4; ++j) {
        int c = threadIdx.x + 256 * j;
        float acc = 0.f;
        for (int e = 0; e < EMB; ++e) acc += tk[e] * Wlin[e * HID + c];
        h0[(long)row * HID + c] = acc;
    }
}

// ---------------------------------------------------------------------------
// x = pos + concat(prev, cur); outputs f32 + fp16 hi/lo split
// ---------------------------------------------------------------------------
__global__ __launch_bounds__(256) void build_x_kernel(
    const float* __restrict__ pos, const float* __restrict__ prev,
    const float* __restrict__ cur, float* __restrict__ x,
    ushort* __restrict__ xh, ushort* __restrict__ xl)
{
    int i4 = blockIdx.x * blockDim.x + threadIdx.x;
    if (i4 >= NB * TT * HID / 4) return;
    int h4 = i4 % (HID / 4);
    int bt = i4 / (HID / 4);
    int t = bt % TT, b = bt / TT;
    float4 p = ((const float4*)pos)[t * (HID / 4) + h4];
    float4 s;
    if (t < WINN) s = ((const float4*)prev)[(long)(b * WINN + t) * (HID / 4) + h4];
    else          s = ((const float4*)cur)[(long)(b * WINN + (t - WINN)) * (HID / 4) + h4];
    float4 r; r.x = p.x + s.x; r.y = p.y + s.y; r.z = p.z + s.z; r.w = p.w + s.w;
    ((float4*)x)[i4] = r;
    ushort4 uh, ul;
    split16(r.x, uh.x, ul.x); split16(r.y, uh.y, ul.y);
    split16(r.z, uh.z, ul.z); split16(r.w, uh.w, ul.w);
    ((ushort4*)xh)[i4] = uh;
    ((ushort4*)xl)[i4] = ul;
}

// ---------------------------------------------------------------------------
// Weight transpose + fp16 split: W f32 [K,N] -> Wt_hi/Wt_lo fp16 [N,K]
// ---------------------------------------------------------------------------
__global__ __launch_bounds__(256) void wsplit_kernel(
    const float* __restrict__ W, ushort* __restrict__ Wth, ushort* __restrict__ Wtl,
    int K, int N)
{
    __shared__ float ts[32][33];
    int n0 = blockIdx.x * 32, k0 = blockIdx.y * 32;
    int tr = threadIdx.x >> 5, tc = threadIdx.x & 31;
#pragma unroll
    for (int j = 0; j < 4; ++j)
        ts[tr + j * 8][tc] = W[(long)(k0 + tr + j * 8) * N + n0 + tc];
    __syncthreads();
#pragma unroll
    for (int j = 0; j < 4; ++j) {
        int n = tr + j * 8;
        ushort hb, lb;
        split16(ts[tc][n], hb, lb);
        long idx = (long)(n0 + n) * K + k0 + tc;
        Wth[idx] = hb;
        Wtl[idx] = lb;
    }
}

// ---------------------------------------------------------------------------
// Fused QKVC weight split: z picks {Q,K,V,C}; all 1024x1024.
// ---------------------------------------------------------------------------
__global__ __launch_bounds__(256) void wsplit4_kernel(
    const float* __restrict__ pq, const float* __restrict__ pk,
    const float* __restrict__ pv, const float* __restrict__ pc,
    ushort* __restrict__ wq_h, ushort* __restrict__ wq_l,
    ushort* __restrict__ wkv_h, ushort* __restrict__ wkv_l,
    ushort* __restrict__ wc_h, ushort* __restrict__ wc_l)
{
    const float* src; ushort* dh; ushort* dl;
    switch (blockIdx.z) {
        case 0:  src = pq; dh = wq_h;            dl = wq_l;            break;
        case 1:  src = pk; dh = wkv_h;           dl = wkv_l;           break;
        case 2:  src = pv; dh = wkv_h + 1048576; dl = wkv_l + 1048576; break;
        default: src = pc; dh = wc_h;            dl = wc_l;            break;
    }
    __shared__ float ts[32][33];
    int n0 = blockIdx.x * 32, k0 = blockIdx.y * 32;
    int tr = threadIdx.x >> 5, tc = threadIdx.x & 31;
#pragma unroll
    for (int j = 0; j < 4; ++j)
        ts[tr + j * 8][tc] = src[(long)(k0 + tr + j * 8) * HID + n0 + tc];
    __syncthreads();
#pragma unroll
    for (int j = 0; j < 4; ++j) {
        int n = tr + j * 8;
        ushort hb, lb;
        split16(ts[tc][n], hb, lb);
        long idx = (long)(n0 + n) * HID + k0 + tc;
        dh[idx] = hb;
        dl[idx] = lb;
    }
}

// ---------------------------------------------------------------------------
// ushort-pair transpose with source row stride
// ---------------------------------------------------------------------------
__global__ __launch_bounds__(256) void vtrans_kernel(
    const ushort* __restrict__ vh, const ushort* __restrict__ vl,
    ushort* __restrict__ vth, ushort* __restrict__ vtl, int src_stride)
{
    __shared__ ushort th[32][33], tl[32][33];
    int n0 = blockIdx.x * 32, r0 = blockIdx.y * 32;
    int tr = threadIdx.x >> 5, tc = threadIdx.x & 31;
#pragma unroll
    for (int j = 0; j < 4; ++j) {
        long g = (long)(r0 + tr + j * 8) * src_stride + n0 + tc;
        th[tr + j * 8][tc] = vh[g];
        tl[tr + j * 8][tc] = vl[g];
    }
    __syncthreads();
#pragma unroll
    for (int j = 0; j < 4; ++j) {
        long g = (long)(n0 + tr + j * 8) * (NB * TT) + r0 + tc;
        vth[g] = th[tc][tr + j * 8];
        vtl[g] = tl[tc][tr + j * 8];
    }
}

// ---------------------------------------------------------------------------
// Unified split-fp16 MFMA GEMM: 128x128 tile, 8 waves (2x4), wave = 64x32,
// BK=32, global_load_lds staging, linear LDS. gridDim.z split-K (k_off=z*Ksub).
// Output modes: Cf0/Cf1 f32 by z (bias only z==0), else Chh/Cll fp16 split.
// amap remaps A rows: r -> (r>>9)*1024 + 512 + (r&511).
// ---------------------------------------------------------------------------
__global__ __launch_bounds__(512) void hgemm8(
    const ushort* __restrict__ Ah, const ushort* __restrict__ Al,
    const ushort* __restrict__ Bh, const ushort* __restrict__ Bl,
    ushort* __restrict__ Chh, ushort* __restrict__ Cll,
    float* __restrict__ Cf0, float* __restrict__ Cf1,
    int M, int N, int K_stride, int Ksub,
    float scale, const float* __restrict__ bias, int relu, int amap)
{
    __shared__ __align__(16) ushort Ash[128 * 32];
    __shared__ __align__(16) ushort Asl[128 * 32];
    __shared__ __align__(16) ushort Bsh[128 * 32];
    __shared__ __align__(16) ushort Bsl[128 * 32];
    const int tid  = threadIdx.x;
    const int rb   = blockIdx.y * 128;
    const int cb   = blockIdx.x * 128;
    const int z    = blockIdx.z;
    const int k_off = z * Ksub;
    const int wave = tid >> 6, lane = tid & 63;
    const int wr   = (wave >> 2) * 64;
    const int wc   = (wave & 3) * 32;
    const int lr   = lane & 15;
    const int kh   = lane >> 4;

    // staging: wave covers rows [w*16, w*16+16) of each of the 4 buffers.
    const int lrow = lane >> 2;
    const int lkc  = (lane & 3) * 8;
    int gra = rb + wave * 16 + lrow;
    long marow = amap ? (long)((gra >> 9) * 1024 + 512 + (gra & 511)) : (long)gra;
    const ushort* gA_h = Ah + marow * K_stride + k_off + lkc;
    const ushort* gA_l = Al + marow * K_stride + k_off + lkc;
    const ushort* gB_h = Bh + (long)(cb + wave * 16 + lrow) * K_stride + k_off + lkc;
    const ushort* gB_l = Bl + (long)(cb + wave * 16 + lrow) * K_stride + k_off + lkc;
    ushort* lA_h = Ash + wave * 512;
    ushort* lA_l = Asl + wave * 512;
    ushort* lB_h = Bsh + wave * 512;
    ushort* lB_l = Bsl + wave * 512;

    int aoff[4], boff[2];
#pragma unroll
    for (int m = 0; m < 4; ++m) aoff[m] = (wr + m * 16 + lr) * 32 + kh * 8;
#pragma unroll
    for (int n = 0; n < 2; ++n) boff[n] = (wc + n * 16 + lr) * 32 + kh * 8;

    f32x4 accH[4][2], accL[4][2];
#pragma unroll
    for (int m = 0; m < 4; ++m)
#pragma unroll
        for (int n = 0; n < 2; ++n) {
            accH[m][n] = (f32x4){0.f, 0.f, 0.f, 0.f};
            accL[m][n] = (f32x4){0.f, 0.f, 0.f, 0.f};
        }

    for (int k0 = 0; k0 < Ksub; k0 += 32) {
        __syncthreads();
        gload16(gA_h + k0, lA_h);
        gload16(gA_l + k0, lA_l);
        gload16(gB_h + k0, lB_h);
        gload16(gB_l + k0, lB_l);
        __syncthreads();
        f16x8 afh[4], afl[4], bfh[2], bfl[2];
#pragma unroll
        for (int m = 0; m < 4; ++m) {
            afh[m] = *(const f16x8*)(Ash + aoff[m]);
            afl[m] = *(const f16x8*)(Asl + aoff[m]);
        }
#pragma unroll
        for (int n = 0; n < 2; ++n) {
            bfh[n] = *(const f16x8*)(Bsh + boff[n]);
            bfl[n] = *(const f16x8*)(Bsl + boff[n]);
        }
#pragma unroll
        for (int m = 0; m < 4; ++m)
#pragma unroll
            for (int n = 0; n < 2; ++n) {
                accH[m][n] = __builtin_amdgcn_mfma_f32_16x16x32_f16(afh[m], bfh[n], accH[m][n], 0, 0, 0);
                accL[m][n] = __builtin_amdgcn_mfma_f32_16x16x32_f16(afh[m], bfl[n], accL[m][n], 0, 0, 0);
                accL[m][n] = __builtin_amdgcn_mfma_f32_16x16x32_f16(afl[m], bfh[n], accL[m][n], 0, 0, 0);
            }
    }

    if (Cf0) {
        float* __restrict__ Cf = z ? Cf1 : Cf0;
        const float* bias_eff = (z == 0) ? bias : nullptr;
#pragma unroll
        for (int m = 0; m < 4; ++m) {
            int row0 = rb + wr + m * 16 + kh * 4;
#pragma unroll
            for (int n = 0; n < 2; ++n) {
                int col = cb + wc + n * 16 + lr;
                float bv = bias_eff ? bias_eff[col] : 0.f;
#pragma unroll
                for (int r = 0; r < 4; ++r) {
                    float v = (accH[m][n][r] + accL[m][n][r] * (1.f / 2048.f)) * scale + bv;
                    if (relu) v = fmaxf(v, 0.f);
                    Cf[(long)(row0 + r) * N + col] = v;
                }
            }
        }
    } else {
#pragma unroll
        for (int m = 0; m < 4; ++m) {
            int row0 = rb + wr + m * 16 + kh * 4;
#pragma unroll
            for (int n = 0; n < 2; ++n) {
                int col = cb + wc + n * 16 + lr;
                float bv = bias ? bias[col] : 0.f;
#pragma unroll
                for (int r = 0; r < 4; ++r) {
                    float v = (accH[m][n][r] + accL[m][n][r] * (1.f / 2048.f)) * scale + bv;
                    if (relu) v = fmaxf(v, 0.f);
                    long idx = (long)(row0 + r) * N + col;
                    ushort hb, lb; split16(v, hb, lb);
                    Chh[idx] = hb; Cll[idx] = lb;
                }
            }
        }
    }
}

// ---------------------------------------------------------------------------
// MFMA flash attention with T14 async-STAGE: tile kt+1's global loads are
// issued right after the S-phase MFMAs so HBM latency hides under
// softmax+PV; LDS write happens after the next barrier.
// ---------------------------------------------------------------------------
__global__ __launch_bounds__(256) void fattn_mfma(
    const float* __restrict__ qa, const float* __restrict__ qb,
    const ushort* __restrict__ kbh, const ushort* __restrict__ kbl, int kstr,
    const ushort* __restrict__ vth, const ushort* __restrict__ vtl,
    ushort* __restrict__ oh, ushort* __restrict__ ol)
{
    __shared__ __align__(16) ushort ksh[64 * 72];
    __shared__ __align__(16) ushort ksl[64 * 72];
    __shared__ __align__(16) ushort vsh[64 * 72];
    __shared__ __align__(16) ushort vsl[64 * 72];
    const int qt = blockIdx.x, h = blockIdx.y, b = blockIdx.z;
    const int tid = threadIdx.x;
    const int wave = tid >> 6, lane = tid & 63;
    const int lr = lane & 15, kg4 = lane >> 4;
    const int qbase = b * WINN + qt * 64;

    f16x8 qfh[2], qfl[2];
#pragma unroll
    for (int c = 0; c < 2; ++c) {
        long ga = (long)(qbase + wave * 16 + lr) * HID + h * HD + c * 32 + kg4 * 8;
        float4 a0 = *(const float4*)(qa + ga);
        float4 a1 = *(const float4*)(qa + ga + 4);
        float4 b0 = *(const float4*)(qb + ga);
        float4 b1 = *(const float4*)(qb + ga + 4);
        float qv[8] = {a0.x + b0.x, a0.y + b0.y, a0.z + b0.z, a0.w + b0.w,
                       a1.x + b1.x, a1.y + b1.y, a1.z + b1.z, a1.w + b1.w};
        ushort uh[8], ul[8];
#pragma unroll
        for (int j = 0; j < 8; ++j) split16(qv[j], uh[j], ul[j]);
        qfh[c] = *(const f16x8*)uh;
        qfl[c] = *(const f16x8*)ul;
    }

    f32x4 accOH[4], accOL[4];
#pragma unroll
    for (int d = 0; d < 4; ++d) {
        accOH[d] = (f32x4){0.f, 0.f, 0.f, 0.f};
        accOL[d] = (f32x4){0.f, 0.f, 0.f, 0.f};
    }
    float mrow[4], lrow[4];
#pragma unroll
    for (int r = 0; r < 4; ++r) { mrow[r] = -3.0e38f; lrow[r] = 0.f; }

    const int sr = tid >> 2;
    const int sd = (tid & 3) * 16;

    uint4 rk0, rk1, rk2, rk3, rv0, rv1, rv2, rv3;
    {   // prologue: tile 0 -> regs
        long gk = (long)(b * TT + sr) * kstr + h * HD + sd;
        rk0 = *(const uint4*)(kbh + gk); rk1 = *(const uint4*)(kbh + gk + 8);
        rk2 = *(const uint4*)(kbl + gk); rk3 = *(const uint4*)(kbl + gk + 8);
        long gv = (long)(h * HD + sr) * (NB * TT) + b * TT + sd;
        rv0 = *(const uint4*)(vth + gv); rv1 = *(const uint4*)(vth + gv + 8);
        rv2 = *(const uint4*)(vtl + gv); rv3 = *(const uint4*)(vtl + gv + 8);
    }

    const int ktmax = 9 + qt;
    for (int kt = 0; kt < ktmax; ++kt) {
        __syncthreads();   // prev iteration's LDS reads complete
        *(uint4*)(ksh + sr * 72 + sd) = rk0;
        *(uint4*)(ksh + sr * 72 + sd + 8) = rk1;
        *(uint4*)(ksl + sr * 72 + sd) = rk2;
        *(uint4*)(ksl + sr * 72 + sd + 8) = rk3;
        *(uint4*)(vsh + sr * 72 + sd) = rv0;
        *(uint4*)(vsh + sr * 72 + sd + 8) = rv1;
        *(uint4*)(vsl + sr * 72 + sd) = rv2;
        *(uint4*)(vsl + sr * 72 + sd + 8) = rv3;
        __syncthreads();

        // S = Q @ K^T
        f32x4 sH[4], sL[4];
#pragma unroll
        for (int n = 0; n < 4; ++n) {
            sH[n] = (f32x4){0.f, 0.f, 0.f, 0.f};
            sL[n] = (f32x4){0.f, 0.f, 0.f, 0.f};
        }
#pragma unroll
        for (int c = 0; c < 2; ++c) {
#pragma unroll
            for (int n = 0; n < 4; ++n) {
                int ad = (n * 16 + lr) * 72 + c * 32 + kg4 * 8;
                f16x8 bh = *(const f16x8*)(ksh + ad);
                f16x8 bl = *(const f16x8*)(ksl + ad);
                sH[n] = __builtin_amdgcn_mfma_f32_16x16x32_f16(qfh[c], bh, sH[n], 0, 0, 0);
                sL[n] = __builtin_amdgcn_mfma_f32_16x16x32_f16(qfh[c], bl, sL[n], 0, 0, 0);
                sL[n] = __builtin_amdgcn_mfma_f32_16x16x32_f16(qfl[c], bh, sL[n], 0, 0, 0);
            }
        }

        // T14: issue next tile's global loads now; latency hides under
        // softmax + PV. Regs are free (already written to LDS above).
        if (kt + 1 < ktmax) {
            long gk = (long)(b * TT + (kt + 1) * 64 + sr) * kstr + h * HD + sd;
            rk0 = *(const uint4*)(kbh + gk); rk1 = *(const uint4*)(kbh + gk + 8);
            rk2 = *(const uint4*)(kbl + gk); rk3 = *(const uint4*)(kbl + gk + 8);
            long gv = (long)(h * HD + sr) * (NB * TT) + b * TT + (kt + 1) * 64 + sd;
            rv0 = *(const uint4*)(vth + gv); rv1 = *(const uint4*)(vth + gv + 8);
            rv2 = *(const uint4*)(vtl + gv); rv3 = *(const uint4*)(vtl + gv + 8);
        }

        float S[4][4];
#pragma unroll
        for (int n = 0; n < 4; ++n)
#pragma unroll
            for (int r = 0; r < 4; ++r)
                S[n][r] = sH[n][r] + sL[n][r] * (1.f / 2048.f);

        if (kt == ktmax - 1) {
#pragma unroll
            for (int r = 0; r < 4; ++r) {
                int qi = WINN + qt * 64 + wave * 16 + kg4 * 4 + r;
#pragma unroll
                for (int n = 0; n < 4; ++n) {
                    int kg = kt * 64 + n * 16 + lr;
                    if (kg > qi) S[n][r] = -1e9f;
                }
            }
        }

#pragma unroll
        for (int r = 0; r < 4; ++r) {
            float mx = fmaxf(fmaxf(S[0][r], S[1][r]), fmaxf(S[2][r], S[3][r]));
            mx = fmaxf(mx, __shfl_xor(mx, 1));
            mx = fmaxf(mx, __shfl_xor(mx, 2));
            mx = fmaxf(mx, __shfl_xor(mx, 4));
            mx = fmaxf(mx, __shfl_xor(mx, 8));
            float mnew = fmaxf(mrow[r], mx);
            float alpha = __expf(mrow[r] - mnew);
            float rs = 0.f;
#pragma unroll
            for (int n = 0; n < 4; ++n) { S[n][r] = __expf(S[n][r] - mnew); rs += S[n][r]; }
            rs += __shfl_xor(rs, 1);
            rs += __shfl_xor(rs, 2);
            rs += __shfl_xor(rs, 4);
            rs += __shfl_xor(rs, 8);
            lrow[r] = lrow[r] * alpha + rs;
            mrow[r] = mnew;
#pragma unroll
            for (int d = 0; d < 4; ++d) { accOH[d][r] *= alpha; accOL[d][r] *= alpha; }
        }

        __syncthreads();   // all waves done reading ksh/ksl as K
#pragma unroll
        for (int n = 0; n < 4; ++n)
#pragma unroll
            for (int r = 0; r < 4; ++r) {
                ushort hb, lb;
                split16(S[n][r], hb, lb);
                int ad = (wave * 16 + kg4 * 4 + r) * 72 + n * 16 + lr;
                ksh[ad] = hb;
                ksl[ad] = lb;
            }
        f16x8 pfh[2], pfl[2];
#pragma unroll
        for (int c = 0; c < 2; ++c) {
            int ad = (wave * 16 + lr) * 72 + c * 32 + kg4 * 8;
            pfh[c] = *(const f16x8*)(ksh + ad);
            pfl[c] = *(const f16x8*)(ksl + ad);
        }
#pragma unroll
        for (int c = 0; c < 2; ++c) {
#pragma unroll
            for (int d = 0; d < 4; ++d) {
                int ad = (d * 16 + lr) * 72 + c * 32 + kg4 * 8;
                f16x8 vh = *(const f16x8*)(vsh + ad);
                f16x8 vl = *(const f16x8*)(vsl + ad);
                accOH[d] = __builtin_amdgcn_mfma_f32_16x16x32_f16(pfh[c], vh, accOH[d], 0, 0, 0);
                accOL[d] = __builtin_amdgcn_mfma_f32_16x16x32_f16(pfh[c], vl, accOL[d], 0, 0, 0);
                accOL[d] = __builtin_amdgcn_mfma_f32_16x16x32_f16(pfl[c], vh, accOL[d], 0, 0, 0);
            }
        }
    }

#pragma unroll
    for (int r = 0; r < 4; ++r) {
        float inv = 1.f / lrow[r];
        long rowb = (long)(qbase + wave * 16 + kg4 * 4 + r) * HID + h * HD + lr;
#pragma unroll
        for (int d = 0; d < 4; ++d) {
            float v = (accOH[d][r] + accOL[d][r] * (1.f / 2048.f)) * inv;
            ushort hb, lb;
            split16(v, hb, lb);
            oh[rowb + d * 16] = hb;
            ol[rowb + d * 16] = lb;
        }
    }
}

// ---------------------------------------------------------------------------
// Transpose+convert (bf16, logits W)
// ---------------------------------------------------------------------------
__global__ __launch_bounds__(256) void transp_kernel(
    const float* __restrict__ W, ushort* __restrict__ Wt, int K, int N)
{
    __shared__ float ts[32][33];
    int n0 = blockIdx.x * 32, k0 = blockIdx.y * 32;
    int tr = threadIdx.x >> 5, tc = threadIdx.x & 31;
#pragma unroll
    for (int j = 0; j < 4; ++j)
        ts[tr + j * 8][tc] = W[(long)(k0 + tr + j * 8) * N + n0 + tc];
    __syncthreads();
#pragma unroll
    for (int j = 0; j < 4; ++j) {
        int n = tr + j * 8;
        Wt[(long)(n0 + n) * K + k0 + tc] = f2b(ts[tc][n]);
    }
}

// ---------------------------------------------------------------------------
// bf16 MFMA GEMM (logits). B-reuse-ordered XCD swizzle + global_load_lds.
// ---------------------------------------------------------------------------
__global__ __launch_bounds__(256) void mfma_gemm(
    const ushort* __restrict__ A, const ushort* __restrict__ Bt,
    float* __restrict__ Cf, int M, int N, int K)
{
    __shared__ __align__(16) ushort As[128 * 32];
    __shared__ __align__(16) ushort Bs[128 * 32];
    const int tid  = threadIdx.x;
    const int ntm  = M >> 7;
    const int nbx  = gridDim.x;
    const int nwg  = nbx * gridDim.y;
    const int bid  = blockIdx.y * nbx + blockIdx.x;
    const int cpx  = nwg >> 3;
    const int swz  = (bid & 7) * cpx + (bid >> 3);
    const int rb   = (swz % ntm) * 128;
    const int cb   = (swz / ntm) * 128;
    const int wave = tid >> 6, lane = tid & 63;
    const int wr   = (wave >> 1) * 64;
    const int wc   = (wave & 1) * 64;
    const int lr   = lane & 15;
    const int kh   = lane >> 4;

    const int lrow = lane >> 2;
    const int lkc  = (lane & 3) * 8;
    const ushort* gA0 = A + (long)(rb + wave * 32 + lrow) * K + lkc;
    const ushort* gA1 = A + (long)(rb + wave * 32 + 16 + lrow) * K + lkc;
    const ushort* gB0 = Bt + (long)(cb + wave * 32 + lrow) * K + lkc;
    const ushort* gB1 = Bt + (long)(cb + wave * 32 + 16 + lrow) * K + lkc;
    ushort* lA0 = As + wave * 1024;
    ushort* lA1 = As + wave * 1024 + 512;
    ushort* lB0 = Bs + wave * 1024;
    ushort* lB1 = Bs + wave * 1024 + 512;

    int aoff[4], boff[4];
#pragma unroll
    for (int m = 0; m < 4; ++m) aoff[m] = (wr + m * 16 + lr) * 32 + kh * 8;
#pragma unroll
    for (int n = 0; n < 4; ++n) boff[n] = (wc + n * 16 + lr) * 32 + kh * 8;

    f32x4 acc[4][4];
#pragma unroll
    for (int m = 0; m < 4; ++m)
#pragma unroll
        for (int n = 0; n < 4; ++n)
            acc[m][n] = (f32x4){0.f, 0.f, 0.f, 0.f};

    for (int k0 = 0; k0 < K; k0 += 32) {
        __syncthreads();
        gload16(gA0 + k0, lA0);
        gload16(gA1 + k0, lA1);
        gload16(gB0 + k0, lB0);
        gload16(gB1 + k0, lB1);
        __syncthreads();
        b16x8 af[4], bfr[4];
#pragma unroll
        for (int m = 0; m < 4; ++m) af[m] = *(const b16x8*)(As + aoff[m]);
#pragma unroll
        for (int n = 0; n < 4; ++n) bfr[n] = *(const b16x8*)(Bs + boff[n]);
#pragma unroll
        for (int m = 0; m < 4; ++m)
#pragma unroll
            for (int n = 0; n < 4; ++n)
                acc[m][n] = __builtin_amdgcn_mfma_f32_16x16x32_bf16(af[m], bfr[n], acc[m][n], 0, 0, 0);
    }

#pragma unroll
    for (int m = 0; m < 4; ++m) {
        int row0 = rb + wr + m * 16 + kh * 4;
#pragma unroll
        for (int n = 0; n < 4; ++n) {
            int col = cb + wc + n * 16 + lr;
#pragma unroll
            for (int r = 0; r < 4; ++r)
                Cf[(long)(row0 + r) * N + col] = acc[m][n][r];
        }
    }
}

// ---------------------------------------------------------------------------
// out = res[r'] + LN(t (+t2))*scale + bias; outputs f32 / fp16-split / bf16
// ---------------------------------------------------------------------------
__global__ __launch_bounds__(256) void ln_res_kernel(
    const float* __restrict__ t, const float* __restrict__ t2,
    const float* __restrict__ res, float* __restrict__ out,
    ushort* __restrict__ outh, ushort* __restrict__ outl, ushort* __restrict__ outb,
    const float* __restrict__ bias, const float* __restrict__ scale, int res_map)
{
    int r = blockIdx.x;
    int tid = threadIdx.x;
    long rr = res_map ? (long)((r >> 9) * 1024 + 512 + (r & 511)) : (long)r;
    float4 v = ((const float4*)(t + (long)r * HID))[tid];
    if (t2) {
        float4 w = ((const float4*)(t2 + (long)r * HID))[tid];
        v.x += w.x; v.y += w.y; v.z += w.z; v.w += w.w;
    }
    __shared__ float red[4];
    float s = v.x + v.y + v.z + v.w;
    for (int off = 32; off > 0; off >>= 1) s += __shfl_xor(s, off);
    if ((tid & 63) == 0) red[tid >> 6] = s;
    __syncthreads();
    float mean = (red[0] + red[1] + red[2] + red[3]) * (1.f / HID);
    __syncthreads();
    float dx = v.x - mean, dy = v.y - mean, dz = v.z - mean, dw = v.w - mean;
    float qs = dx * dx + dy * dy + dz * dz + dw * dw;
    for (int off = 32; off > 0; off >>= 1) qs += __shfl_xor(qs, off);
    if ((tid & 63) == 0) red[tid >> 6] = qs;
    __syncthreads();
    float var = (red[0] + red[1] + red[2] + red[3]) * (1.f / HID);
    float rs = rsqrtf(var + 1e-6f);
    float4 rv = ((const float4*)(res + rr * HID))[tid];
    float4 sc4 = ((const float4*)scale)[tid];
    float4 b4  = ((const float4*)bias)[tid];
    float4 o4;
    o4.x = rv.x + dx * rs * sc4.x + b4.x;
    o4.y = rv.y + dy * rs * sc4.y + b4.y;
    o4.z = rv.z + dz * rs * sc4.z + b4.z;
    o4.w = rv.w + dw * rs * sc4.w + b4.w;
    ((float4*)(out + (long)r * HID))[tid] = o4;
    if (outh) {
        ushort4 uh, ul;
        split16(o4.x, uh.x, ul.x); split16(o4.y, uh.y, ul.y);
        split16(o4.z, uh.z, ul.z); split16(o4.w, uh.w, ul.w);
        ((ushort4*)(outh + (long)r * HID))[tid] = uh;
        ((ushort4*)(outl + (long)r * HID))[tid] = ul;
    }
    if (outb) {
        ushort4 u; u.x = f2b(o4.x); u.y = f2b(o4.y); u.z = f2b(o4.z); u.w = f2b(o4.w);
        ((ushort4*)(outb + (long)r * HID))[tid] = u;
    }
}

// ---------------------------------------------------------------------------
// Workspace layout identical to R9/R10 (168 MiB, proven safe).
// ---------------------------------------------------------------------------
extern "C" void kernel_launch(void* const* d_in, const int* in_sizes, int n_in,
                              void* d_out, int out_size, void* d_ws, size_t ws_size,
                              hipStream_t stream)
{
    const int*   x_input = (const int*)  d_in[0];
    const float* prev    = (const float*)d_in[1];
    const float* Wemb    = (const float*)d_in[2];
    const float* Wlin    = (const float*)d_in[3];
    const float* pdec    = (const float*)d_in[4];
    const float* pq      = (const float*)d_in[5];
    const float* pk      = (const float*)d_in[6];
    const float* pv      = (const float*)d_in[7];
    const float* pc      = (const float*)d_in[8];
    const float* pf1     = (const float*)d_in[9];
    const float* pf2     = (const float*)d_in[10];
    const float* bf1     = (const float*)d_in[11];
    const float* bf2     = (const float*)d_in[12];
    const float* b1      = (const float*)d_in[13];
    const float* b2      = (const float*)d_in[14];
    const float* s1      = (const float*)d_in[15];
    const float* s2      = (const float*)d_in[16];
    const float* pos     = (const float*)d_in[17];

    float* outp   = (float*)d_out;
    float* logits = outp;
    float* dec    = outp + (long)2048 * VOC;

    char* base = (char*)d_ws;
    float*  x_f   = (float*) (base + 0);
    ushort* x_hi  = (ushort*)(base + 16777216);
    ushort* x_lo  = (ushort*)(base + 25165824);
    ushort* kv_hi = (ushort*)(base + 33554432);
    ushort* kv_lo = (ushort*)(base + 50331648);
    ushort* vt_hi = (ushort*)(base + 67108864);
    ushort* vt_lo = (ushort*)(base + 75497472);
    ushort* o_hi  = (ushort*)(base + 83886080);
    ushort* o_lo  = (ushort*)(base + 88080384);
    float*  t0a   = (float*) (base + 92274688);
    float*  h0    = t0a;
    float*  qa    = t0a;
    float*  t0b   = (float*) (base + 100663296);
    float*  qb    = t0b;
    float*  xs    = (float*) (base + 109051904);
    ushort* xs_hi = (ushort*)(base + 117440512);
    ushort* xs_lo = (ushort*)(base + 121634816);
    ushort* wq_hi = (ushort*)(base + 125829120);
    ushort* wq_lo = (ushort*)(base + 127926272);
    ushort* wkv_hi= (ushort*)(base + 130023424);
    ushort* wkv_lo= (ushort*)(base + 134217728);
    ushort* wc_hi = (ushort*)(base + 138412032);
    ushort* wc_lo = (ushort*)(base + 140509184);
    ushort* wf1_hi= (ushort*)(base + 142606336);
    ushort* wf1_lo= (ushort*)(base + 150994944);
    ushort* wf2_hi= (ushort*)(base + 159383552);
    ushort* wf2_lo= (ushort*)(base + 167772160);   // ends 176,160,768
    // overlays
    ushort* ff1_hi= (ushort*)(base + 33554432);
    ushort* ff1_lo= (ushort*)(base + 50331648);
    ushort* decb  = (ushort*)(base + 83886080);
    ushort* wdect = (ushort*)(base + 0);

    embed_kernel<<<NB * WINN, 256, 0, stream>>>(x_input, Wemb, Wlin, h0);

    for (int l = 0; l < NL; ++l) {
        const float* cur = (l == 0) ? h0 : (dec + (long)(l - 1) * 2097152);
        build_x_kernel<<<(NB * TT * HID / 4) / 256, 256, 0, stream>>>(
            pos + (long)l * TT * HID, prev + (long)l * NB * WINN * HID, cur,
            x_f, x_hi, x_lo);

        wsplit4_kernel<<<dim3(32, 32, 4), 256, 0, stream>>>(
            pq + (long)l * HID * HID, pk + (long)l * HID * HID,
            pv + (long)l * HID * HID, pc + (long)l * HID * HID,
            wq_hi, wq_lo, wkv_hi, wkv_lo, wc_hi, wc_lo);
        wsplit_kernel<<<dim3(FFW / 32, HID / 32), 256, 0, stream>>>(
            pf1 + (long)l * HID * FFW, wf1_hi, wf1_lo, HID, FFW);
        wsplit_kernel<<<dim3(HID / 32, FFW / 32), 256, 0, stream>>>(
            pf2 + (long)l * FFW * HID, wf2_hi, wf2_lo, FFW, HID);

        // Fused K+V projection
        hgemm8<<<dim3(2048 / 128, (NB * TT) / 128, 1), 512, 0, stream>>>(
            x_hi, x_lo, wkv_hi, wkv_lo, kv_hi, kv_lo, nullptr, nullptr,
            NB * TT, 2048, HID, HID, 1.f, nullptr, 0, 0);
        // Q projection: split-K2 -> qa, qb (f32)
        hgemm8<<<dim3(HID / 128, (NB * WINN) / 128, 2), 512, 0, stream>>>(
            x_hi, x_lo, wq_hi, wq_lo, nullptr, nullptr, qa, qb,
            NB * WINN, HID, HID, 512, 0.125f, nullptr, 0, 1);
        vtrans_kernel<<<dim3(HID / 32, (NB * TT) / 32), 256, 0, stream>>>(
            kv_hi + 1024, kv_lo + 1024, vt_hi, vt_lo, 2048);

        fattn_mfma<<<dim3(WINN / 64, NH, NB), 256, 0, stream>>>(
            qa, qb, kv_hi, kv_lo, 2048, vt_hi, vt_lo, o_hi, o_lo);

        // C-proj: split-K2 -> t0a, t0b
        hgemm8<<<dim3(HID / 128, (NB * WINN) / 128, 2), 512, 0, stream>>>(
            o_hi, o_lo, wc_hi, wc_lo, nullptr, nullptr, t0a, t0b,
            NB * WINN, HID, HID, 512, 1.f, nullptr, 0, 0);
        ln_res_kernel<<<NB * WINN, 256, 0, stream>>>(
            t0a, t0b, x_f, xs, xs_hi, xs_lo, nullptr,
            b1 + l * HID, s1 + l * HID, 1);

        hgemm8<<<dim3(FFW / 128, (NB * WINN) / 128, 1), 512, 0, stream>>>(
            xs_hi, xs_lo, wf1_hi, wf1_lo, ff1_hi, ff1_lo, nullptr, nullptr,
            NB * WINN, FFW, HID, HID, 1.f, bf1 + l * FFW, 1, 0);
        // FF2: split-K2 -> t0a, t0b
        hgemm8<<<dim3(HID / 128, (NB * WINN) / 128, 2), 512, 0, stream>>>(
            ff1_hi, ff1_lo, wf2_hi, wf2_lo, nullptr, nullptr, t0a, t0b,
            NB * WINN, HID, FFW, 2048, 1.f, bf2 + l * HID, 0, 0);
        ln_res_kernel<<<NB * WINN, 256, 0, stream>>>(
            t0a, t0b, xs, dec + (long)l * 2097152, nullptr, nullptr,
            (l == NL - 1) ? decb : nullptr, b2 + l * HID, s2 + l * HID, 0);
    }

    transp_kernel<<<dim3(VOC / 32, HID / 32), 256, 0, stream>>>(pdec, wdect, HID, VOC);
    mfma_gemm<<<dim3(VOC / 128, (NB * WINN) / 128), 256, 0, stream>>>(
        decb, wdect, logits, NB * WINN, VOC, HID);
}

// Round 12
// 2391.746 us; speedup vs baseline: 5.1749x; 1.0569x over previous
//
#include <hip/hip_runtime.h>
#include <hip/hip_bf16.h>

#define NL   6
#define NH   16
#define HID  1024
#define HD   64
#define FFW  4096
#define VOC  32000
#define WINN 512
#define EMB  128
#define NB   4
#define TT   1024   // WIN + WIN

typedef __attribute__((ext_vector_type(8))) _Float16 f16x8;
typedef __attribute__((ext_vector_type(8))) short    b16x8;
typedef __attribute__((ext_vector_type(4))) float    f32x4;

__device__ __forceinline__ ushort f2b(float f) {
    __hip_bfloat16 h = __float2bfloat16(f);
    return *reinterpret_cast<ushort*>(&h);
}
// split f32 into fp16 hi/lo:  f ~= hi + lo * 2^-11  (error ~ |f|*2^-22)
__device__ __forceinline__ void split16(float f, ushort& hb, ushort& lb) {
    _Float16 h = (_Float16)f;
    _Float16 l = (_Float16)((f - (float)h) * 2048.0f);
    hb = __builtin_bit_cast(ushort, h);
    lb = __builtin_bit_cast(ushort, l);
}
// async global->LDS, 16B per lane: LDS dest = (wave-uniform base) + lane*16
__device__ __forceinline__ void gload16(const void* g, void* l) {
    __builtin_amdgcn_global_load_lds(
        (const __attribute__((address_space(1))) unsigned int*)g,
        (__attribute__((address_space(3))) unsigned int*)l, 16, 0, 0);
}

// ---------------------------------------------------------------------------
// Embed (f32)
// ---------------------------------------------------------------------------
__global__ __launch_bounds__(256) void embed_kernel(
    const int* __restrict__ xin, const float* __restrict__ Wemb,
    const float* __restrict__ Wlin, float* __restrict__ h0)
{
    int row = blockIdx.x;
    int tok = xin[row];
    __shared__ float tk[EMB];
    if (threadIdx.x < EMB) tk[threadIdx.x] = Wemb[tok * EMB + threadIdx.x] * 0.03125f;
    __syncthreads();
    for (int j = 0; j < 4; ++j) {
        int c = threadIdx.x + 256 * j;
        float acc = 0.f;
        for (int e = 0; e < EMB; ++e) acc += tk[e] * Wlin[e * HID + c];
        h0[(long)row * HID + c] = acc;
    }
}

// ---------------------------------------------------------------------------
// x = pos + concat(prev, cur); outputs f32 + fp16 hi/lo split
// ---------------------------------------------------------------------------
__global__ __launch_bounds__(256) void build_x_kernel(
    const float* __restrict__ pos, const float* __restrict__ prev,
    const float* __restrict__ cur, float* __restrict__ x,
    ushort* __restrict__ xh, ushort* __restrict__ xl)
{
    int i4 = blockIdx.x * blockDim.x + threadIdx.x;
    if (i4 >= NB * TT * HID / 4) return;
    int h4 = i4 % (HID / 4);
    int bt = i4 / (HID / 4);
    int t = bt % TT, b = bt / TT;
    float4 p = ((const float4*)pos)[t * (HID / 4) + h4];
    float4 s;
    if (t < WINN) s = ((const float4*)prev)[(long)(b * WINN + t) * (HID / 4) + h4];
    else          s = ((const float4*)cur)[(long)(b * WINN + (t - WINN)) * (HID / 4) + h4];
    float4 r; r.x = p.x + s.x; r.y = p.y + s.y; r.z = p.z + s.z; r.w = p.w + s.w;
    ((float4*)x)[i4] = r;
    ushort4 uh, ul;
    split16(r.x, uh.x, ul.x); split16(r.y, uh.y, ul.y);
    split16(r.z, uh.z, ul.z); split16(r.w, uh.w, ul.w);
    ((ushort4*)xh)[i4] = uh;
    ((ushort4*)xl)[i4] = ul;
}

// ---------------------------------------------------------------------------
// Weight transpose + fp16 split: W f32 [K,N] -> Wt_hi/Wt_lo fp16 [N,K]
// ---------------------------------------------------------------------------
__global__ __launch_bounds__(256) void wsplit_kernel(
    const float* __restrict__ W, ushort* __restrict__ Wth, ushort* __restrict__ Wtl,
    int K, int N)
{
    __shared__ float ts[32][33];
    int n0 = blockIdx.x * 32, k0 = blockIdx.y * 32;
    int tr = threadIdx.x >> 5, tc = threadIdx.x & 31;
#pragma unroll
    for (int j = 0; j < 4; ++j)
        ts[tr + j * 8][tc] = W[(long)(k0 + tr + j * 8) * N + n0 + tc];
    __syncthreads();
#pragma unroll
    for (int j = 0; j < 4; ++j) {
        int n = tr + j * 8;
        ushort hb, lb;
        split16(ts[tc][n], hb, lb);
        long idx = (long)(n0 + n) * K + k0 + tc;
        Wth[idx] = hb;
        Wtl[idx] = lb;
    }
}

// ---------------------------------------------------------------------------
// Fused QKVC weight split: z picks {Q,K,V,C}; all 1024x1024.
// ---------------------------------------------------------------------------
__global__ __launch_bounds__(256) void wsplit4_kernel(
    const float* __restrict__ pq, const float* __restrict__ pk,
    const float* __restrict__ pv, const float* __restrict__ pc,
    ushort* __restrict__ wq_h, ushort* __restrict__ wq_l,
    ushort* __restrict__ wkv_h, ushort* __restrict__ wkv_l,
    ushort* __restrict__ wc_h, ushort* __restrict__ wc_l)
{
    const float* src; ushort* dh; ushort* dl;
    switch (blockIdx.z) {
        case 0:  src = pq; dh = wq_h;            dl = wq_l;            break;
        case 1:  src = pk; dh = wkv_h;           dl = wkv_l;           break;
        case 2:  src = pv; dh = wkv_h + 1048576; dl = wkv_l + 1048576; break;
        default: src = pc; dh = wc_h;            dl = wc_l;            break;
    }
    __shared__ float ts[32][33];
    int n0 = blockIdx.x * 32, k0 = blockIdx.y * 32;
    int tr = threadIdx.x >> 5, tc = threadIdx.x & 31;
#pragma unroll
    for (int j = 0; j < 4; ++j)
        ts[tr + j * 8][tc] = src[(long)(k0 + tr + j * 8) * HID + n0 + tc];
    __syncthreads();
#pragma unroll
    for (int j = 0; j < 4; ++j) {
        int n = tr + j * 8;
        ushort hb, lb;
        split16(ts[tc][n], hb, lb);
        long idx = (long)(n0 + n) * HID + k0 + tc;
        dh[idx] = hb;
        dl[idx] = lb;
    }
}

// ---------------------------------------------------------------------------
// ushort-pair transpose with source row stride
// ---------------------------------------------------------------------------
__global__ __launch_bounds__(256) void vtrans_kernel(
    const ushort* __restrict__ vh, const ushort* __restrict__ vl,
    ushort* __restrict__ vth, ushort* __restrict__ vtl, int src_stride)
{
    __shared__ ushort th[32][33], tl[32][33];
    int n0 = blockIdx.x * 32, r0 = blockIdx.y * 32;
    int tr = threadIdx.x >> 5, tc = threadIdx.x & 31;
#pragma unroll
    for (int j = 0; j < 4; ++j) {
        long g = (long)(r0 + tr + j * 8) * src_stride + n0 + tc;
        th[tr + j * 8][tc] = vh[g];
        tl[tr + j * 8][tc] = vl[g];
    }
    __syncthreads();
#pragma unroll
    for (int j = 0; j < 4; ++j) {
        long g = (long)(n0 + tr + j * 8) * (NB * TT) + r0 + tc;
        vth[g] = th[tc][tr + j * 8];
        vtl[g] = tl[tc][tr + j * 8];
    }
}

// ---------------------------------------------------------------------------
// Unified split-fp16 MFMA GEMM: 128x128 tile, 8 waves (2x4), wave = 64x32,
// BK=32, global_load_lds staging, linear LDS. gridDim.z split-K (k_off=z*Ksub).
// f32 mode (Cf0 != null): block z writes Cf[z], bias only on z==0.
// fp16-split mode: writes Chh/Cll. amap remaps A rows.
// ---------------------------------------------------------------------------
__global__ __launch_bounds__(512) void hgemm8(
    const ushort* __restrict__ Ah, const ushort* __restrict__ Al,
    const ushort* __restrict__ Bh, const ushort* __restrict__ Bl,
    ushort* __restrict__ Chh, ushort* __restrict__ Cll,
    float* __restrict__ Cf0, float* __restrict__ Cf1,
    float* __restrict__ Cf2, float* __restrict__ Cf3,
    int M, int N, int K_stride, int Ksub,
    float scale, const float* __restrict__ bias, int relu, int amap)
{
    __shared__ __align__(16) ushort Ash[128 * 32];
    __shared__ __align__(16) ushort Asl[128 * 32];
    __shared__ __align__(16) ushort Bsh[128 * 32];
    __shared__ __align__(16) ushort Bsl[128 * 32];
    const int tid  = threadIdx.x;
    const int rb   = blockIdx.y * 128;
    const int cb   = blockIdx.x * 128;
    const int z    = blockIdx.z;
    const int k_off = z * Ksub;
    const int wave = tid >> 6, lane = tid & 63;
    const int wr   = (wave >> 2) * 64;
    const int wc   = (wave & 3) * 32;
    const int lr   = lane & 15;
    const int kh   = lane >> 4;

    const int lrow = lane >> 2;
    const int lkc  = (lane & 3) * 8;
    int gra = rb + wave * 16 + lrow;
    long marow = amap ? (long)((gra >> 9) * 1024 + 512 + (gra & 511)) : (long)gra;
    const ushort* gA_h = Ah + marow * K_stride + k_off + lkc;
    const ushort* gA_l = Al + marow * K_stride + k_off + lkc;
    const ushort* gB_h = Bh + (long)(cb + wave * 16 + lrow) * K_stride + k_off + lkc;
    const ushort* gB_l = Bl + (long)(cb + wave * 16 + lrow) * K_stride + k_off + lkc;
    ushort* lA_h = Ash + wave * 512;
    ushort* lA_l = Asl + wave * 512;
    ushort* lB_h = Bsh + wave * 512;
    ushort* lB_l = Bsl + wave * 512;

    int aoff[4], boff[2];
#pragma unroll
    for (int m = 0; m < 4; ++m) aoff[m] = (wr + m * 16 + lr) * 32 + kh * 8;
#pragma unroll
    for (int n = 0; n < 2; ++n) boff[n] = (wc + n * 16 + lr) * 32 + kh * 8;

    f32x4 accH[4][2], accL[4][2];
#pragma unroll
    for (int m = 0; m < 4; ++m)
#pragma unroll
        for (int n = 0; n < 2; ++n) {
            accH[m][n] = (f32x4){0.f, 0.f, 0.f, 0.f};
            accL[m][n] = (f32x4){0.f, 0.f, 0.f, 0.f};
        }

    for (int k0 = 0; k0 < Ksub; k0 += 32) {
        __syncthreads();
        gload16(gA_h + k0, lA_h);
        gload16(gA_l + k0, lA_l);
        gload16(gB_h + k0, lB_h);
        gload16(gB_l + k0, lB_l);
        __syncthreads();
        f16x8 afh[4], afl[4], bfh[2], bfl[2];
#pragma unroll
        for (int m = 0; m < 4; ++m) {
            afh[m] = *(const f16x8*)(Ash + aoff[m]);
            afl[m] = *(const f16x8*)(Asl + aoff[m]);
        }
#pragma unroll
        for (int n = 0; n < 2; ++n) {
            bfh[n] = *(const f16x8*)(Bsh + boff[n]);
            bfl[n] = *(const f16x8*)(Bsl + boff[n]);
        }
#pragma unroll
        for (int m = 0; m < 4; ++m)
#pragma unroll
            for (int n = 0; n < 2; ++n) {
                accH[m][n] = __builtin_amdgcn_mfma_f32_16x16x32_f16(afh[m], bfh[n], accH[m][n], 0, 0, 0);
                accL[m][n] = __builtin_amdgcn_mfma_f32_16x16x32_f16(afh[m], bfl[n], accL[m][n], 0, 0, 0);
                accL[m][n] = __builtin_amdgcn_mfma_f32_16x16x32_f16(afl[m], bfh[n], accL[m][n], 0, 0, 0);
            }
    }

    if (Cf0) {
        float* __restrict__ Cf = (z == 0) ? Cf0 : (z == 1) ? Cf1 : (z == 2) ? Cf2 : Cf3;
        const float* bias_eff = (z == 0) ? bias : nullptr;
#pragma unroll
        for (int m = 0; m < 4; ++m) {
            int row0 = rb + wr + m * 16 + kh * 4;
#pragma unroll
            for (int n = 0; n < 2; ++n) {
                int col = cb + wc + n * 16 + lr;
                float bv = bias_eff ? bias_eff[col] : 0.f;
#pragma unroll
                for (int r = 0; r < 4; ++r) {
                    float v = (accH[m][n][r] + accL[m][n][r] * (1.f / 2048.f)) * scale + bv;
                    if (relu) v = fmaxf(v, 0.f);
                    Cf[(long)(row0 + r) * N + col] = v;
                }
            }
        }
    } else {
#pragma unroll
        for (int m = 0; m < 4; ++m) {
            int row0 = rb + wr + m * 16 + kh * 4;
#pragma unroll
            for (int n = 0; n < 2; ++n) {
                int col = cb + wc + n * 16 + lr;
                float bv = bias ? bias[col] : 0.f;
#pragma unroll
                for (int r = 0; r < 4; ++r) {
                    float v = (accH[m][n][r] + accL[m][n][r] * (1.f / 2048.f)) * scale + bv;
                    if (relu) v = fmaxf(v, 0.f);
                    long idx = (long)(row0 + r) * N + col;
                    ushort hb, lb; split16(v, hb, lb);
                    Chh[idx] = hb; Cll[idx] = lb;
                }
            }
        }
    }
}

// ---------------------------------------------------------------------------
// MFMA flash attention with T14 async-STAGE. Q = qa+qb+qc+qd (f32 partials).
// ---------------------------------------------------------------------------
__global__ __launch_bounds__(256) void fattn_mfma(
    const float* __restrict__ qa, const float* __restrict__ qb,
    const float* __restrict__ qc, const float* __restrict__ qd,
    const ushort* __restrict__ kbh, const ushort* __restrict__ kbl, int kstr,
    const ushort* __restrict__ vth, const ushort* __restrict__ vtl,
    ushort* __restrict__ oh, ushort* __restrict__ ol)
{
    __shared__ __align__(16) ushort ksh[64 * 72];
    __shared__ __align__(16) ushort ksl[64 * 72];
    __shared__ __align__(16) ushort vsh[64 * 72];
    __shared__ __align__(16) ushort vsl[64 * 72];
    const int qt = blockIdx.x, h = blockIdx.y, b = blockIdx.z;
    const int tid = threadIdx.x;
    const int wave = tid >> 6, lane = tid & 63;
    const int lr = lane & 15, kg4 = lane >> 4;
    const int qbase = b * WINN + qt * 64;

    f16x8 qfh[2], qfl[2];
#pragma unroll
    for (int c = 0; c < 2; ++c) {
        long ga = (long)(qbase + wave * 16 + lr) * HID + h * HD + c * 32 + kg4 * 8;
        float4 a0 = *(const float4*)(qa + ga);
        float4 a1 = *(const float4*)(qa + ga + 4);
        float4 b0 = *(const float4*)(qb + ga);
        float4 b1 = *(const float4*)(qb + ga + 4);
        float4 c0 = *(const float4*)(qc + ga);
        float4 c1 = *(const float4*)(qc + ga + 4);
        float4 d0 = *(const float4*)(qd + ga);
        float4 d1 = *(const float4*)(qd + ga + 4);
        float qv[8] = {a0.x + b0.x + c0.x + d0.x, a0.y + b0.y + c0.y + d0.y,
                       a0.z + b0.z + c0.z + d0.z, a0.w + b0.w + c0.w + d0.w,
                       a1.x + b1.x + c1.x + d1.x, a1.y + b1.y + c1.y + d1.y,
                       a1.z + b1.z + c1.z + d1.z, a1.w + b1.w + c1.w + d1.w};
        ushort uh[8], ul[8];
#pragma unroll
        for (int j = 0; j < 8; ++j) split16(qv[j], uh[j], ul[j]);
        qfh[c] = *(const f16x8*)uh;
        qfl[c] = *(const f16x8*)ul;
    }

    f32x4 accOH[4], accOL[4];
#pragma unroll
    for (int d = 0; d < 4; ++d) {
        accOH[d] = (f32x4){0.f, 0.f, 0.f, 0.f};
        accOL[d] = (f32x4){0.f, 0.f, 0.f, 0.f};
    }
    float mrow[4], lrow[4];
#pragma unroll
    for (int r = 0; r < 4; ++r) { mrow[r] = -3.0e38f; lrow[r] = 0.f; }

    const int sr = tid >> 2;
    const int sd = (tid & 3) * 16;

    uint4 rk0, rk1, rk2, rk3, rv0, rv1, rv2, rv3;
    {   // prologue: tile 0 -> regs
        long gk = (long)(b * TT + sr) * kstr + h * HD + sd;
        rk0 = *(const uint4*)(kbh + gk); rk1 = *(const uint4*)(kbh + gk + 8);
        rk2 = *(const uint4*)(kbl + gk); rk3 = *(const uint4*)(kbl + gk + 8);
        long gv = (long)(h * HD + sr) * (NB * TT) + b * TT + sd;
        rv0 = *(const uint4*)(vth + gv); rv1 = *(const uint4*)(vth + gv + 8);
        rv2 = *(const uint4*)(vtl + gv); rv3 = *(const uint4*)(vtl + gv + 8);
    }

    const int ktmax = 9 + qt;
    for (int kt = 0; kt < ktmax; ++kt) {
        __syncthreads();
        *(uint4*)(ksh + sr * 72 + sd) = rk0;
        *(uint4*)(ksh + sr * 72 + sd + 8) = rk1;
        *(uint4*)(ksl + sr * 72 + sd) = rk2;
        *(uint4*)(ksl + sr * 72 + sd + 8) = rk3;
        *(uint4*)(vsh + sr * 72 + sd) = rv0;
        *(uint4*)(vsh + sr * 72 + sd + 8) = rv1;
        *(uint4*)(vsl + sr * 72 + sd) = rv2;
        *(uint4*)(vsl + sr * 72 + sd + 8) = rv3;
        __syncthreads();

        f32x4 sH[4], sL[4];
#pragma unroll
        for (int n = 0; n < 4; ++n) {
            sH[n] = (f32x4){0.f, 0.f, 0.f, 0.f};
            sL[n] = (f32x4){0.f, 0.f, 0.f, 0.f};
        }
#pragma unroll
        for (int c = 0; c < 2; ++c) {
#pragma unroll
            for (int n = 0; n < 4; ++n) {
                int ad = (n * 16 + lr) * 72 + c * 32 + kg4 * 8;
                f16x8 bh = *(const f16x8*)(ksh + ad);
                f16x8 bl = *(const f16x8*)(ksl + ad);
                sH[n] = __builtin_amdgcn_mfma_f32_16x16x32_f16(qfh[c], bh, sH[n], 0, 0, 0);
                sL[n] = __builtin_amdgcn_mfma_f32_16x16x32_f16(qfh[c], bl, sL[n], 0, 0, 0);
                sL[n] = __builtin_amdgcn_mfma_f32_16x16x32_f16(qfl[c], bh, sL[n], 0, 0, 0);
            }
        }

        // T14: next tile's global loads issue here; latency hides under
        // softmax + PV.
        if (kt + 1 < ktmax) {
            long gk = (long)(b * TT + (kt + 1) * 64 + sr) * kstr + h * HD + sd;
            rk0 = *(const uint4*)(kbh + gk); rk1 = *(const uint4*)(kbh + gk + 8);
            rk2 = *(const uint4*)(kbl + gk); rk3 = *(const uint4*)(kbl + gk + 8);
            long gv = (long)(h * HD + sr) * (NB * TT) + b * TT + (kt + 1) * 64 + sd;
            rv0 = *(const uint4*)(vth + gv); rv1 = *(const uint4*)(vth + gv + 8);
            rv2 = *(const uint4*)(vtl + gv); rv3 = *(const uint4*)(vtl + gv + 8);
        }

        float S[4][4];
#pragma unroll
        for (int n = 0; n < 4; ++n)
#pragma unroll
            for (int r = 0; r < 4; ++r)
                S[n][r] = sH[n][r] + sL[n][r] * (1.f / 2048.f);

        if (kt == ktmax - 1) {
#pragma unroll
            for (int r = 0; r < 4; ++r) {
                int qi = WINN + qt * 64 + wave * 16 + kg4 * 4 + r;
#pragma unroll
                for (int n = 0; n < 4; ++n) {
                    int kg = kt * 64 + n * 16 + lr;
                    if (kg > qi) S[n][r] = -1e9f;
                }
            }
        }

#pragma unroll
        for (int r = 0; r < 4; ++r) {
            float mx = fmaxf(fmaxf(S[0][r], S[1][r]), fmaxf(S[2][r], S[3][r]));
            mx = fmaxf(mx, __shfl_xor(mx, 1));
            mx = fmaxf(mx, __shfl_xor(mx, 2));
            mx = fmaxf(mx, __shfl_xor(mx, 4));
            mx = fmaxf(mx, __shfl_xor(mx, 8));
            float mnew = fmaxf(mrow[r], mx);
            float alpha = __expf(mrow[r] - mnew);
            float rs = 0.f;
#pragma unroll
            for (int n = 0; n < 4; ++n) { S[n][r] = __expf(S[n][r] - mnew); rs += S[n][r]; }
            rs += __shfl_xor(rs, 1);
            rs += __shfl_xor(rs, 2);
            rs += __shfl_xor(rs, 4);
            rs += __shfl_xor(rs, 8);
            lrow[r] = lrow[r] * alpha + rs;
            mrow[r] = mnew;
#pragma unroll
            for (int d = 0; d < 4; ++d) { accOH[d][r] *= alpha; accOL[d][r] *= alpha; }
        }

        __syncthreads();
#pragma unroll
        for (int n = 0; n < 4; ++n)
#pragma unroll
            for (int r = 0; r < 4; ++r) {
                ushort hb, lb;
                split16(S[n][r], hb, lb);
                int ad = (wave * 16 + kg4 * 4 + r) * 72 + n * 16 + lr;
                ksh[ad] = hb;
                ksl[ad] = lb;
            }
        f16x8 pfh[2], pfl[2];
#pragma unroll
        for (int c = 0; c < 2; ++c) {
            int ad = (wave * 16 + lr) * 72 + c * 32 + kg4 * 8;
            pfh[c] = *(const f16x8*)(ksh + ad);
            pfl[c] = *(const f16x8*)(ksl + ad);
        }
#pragma unroll
        for (int c = 0; c < 2; ++c) {
#pragma unroll
            for (int d = 0; d < 4; ++d) {
                int ad = (d * 16 + lr) * 72 + c * 32 + kg4 * 8;
                f16x8 vh = *(const f16x8*)(vsh + ad);
                f16x8 vl = *(const f16x8*)(vsl + ad);
                accOH[d] = __builtin_amdgcn_mfma_f32_16x16x32_f16(pfh[c], vh, accOH[d], 0, 0, 0);
                accOL[d] = __builtin_amdgcn_mfma_f32_16x16x32_f16(pfh[c], vl, accOL[d], 0, 0, 0);
                accOL[d] = __builtin_amdgcn_mfma_f32_16x16x32_f16(pfl[c], vh, accOL[d], 0, 0, 0);
            }
        }
    }

#pragma unroll
    for (int r = 0; r < 4; ++r) {
        float inv = 1.f / lrow[r];
        long rowb = (long)(qbase + wave * 16 + kg4 * 4 + r) * HID + h * HD + lr;
#pragma unroll
        for (int d = 0; d < 4; ++d) {
            float v = (accOH[d][r] + accOL[d][r] * (1.f / 2048.f)) * inv;
            ushort hb, lb;
            split16(v, hb, lb);
            oh[rowb + d * 16] = hb;
            ol[rowb + d * 16] = lb;
        }
    }
}

// ---------------------------------------------------------------------------
// Transpose+convert (bf16, logits W)
// ---------------------------------------------------------------------------
__global__ __launch_bounds__(256) void transp_kernel(
    const float* __restrict__ W, ushort* __restrict__ Wt, int K, int N)
{
    __shared__ float ts[32][33];
    int n0 = blockIdx.x * 32, k0 = blockIdx.y * 32;
    int tr = threadIdx.x >> 5, tc = threadIdx.x & 31;
#pragma unroll
    for (int j = 0; j < 4; ++j)
        ts[tr + j * 8][tc] = W[(long)(k0 + tr + j * 8) * N + n0 + tc];
    __syncthreads();
#pragma unroll
    for (int j = 0; j < 4; ++j) {
        int n = tr + j * 8;
        Wt[(long)(n0 + n) * K + k0 + tc] = f2b(ts[tc][n]);
    }
}

// ---------------------------------------------------------------------------
// bf16 MFMA GEMM (logits). B-reuse-ordered XCD swizzle + global_load_lds.
// ---------------------------------------------------------------------------
__global__ __launch_bounds__(256) void mfma_gemm(
    const ushort* __restrict__ A, const ushort* __restrict__ Bt,
    float* __restrict__ Cf, int M, int N, int K)
{
    __shared__ __align__(16) ushort As[128 * 32];
    __shared__ __align__(16) ushort Bs[128 * 32];
    const int tid  = threadIdx.x;
    const int ntm  = M >> 7;
    const int nbx  = gridDim.x;
    const int nwg  = nbx * gridDim.y;
    const int bid  = blockIdx.y * nbx + blockIdx.x;
    const int cpx  = nwg >> 3;
    const int swz  = (bid & 7) * cpx + (bid >> 3);
    const int rb   = (swz % ntm) * 128;
    const int cb   = (swz / ntm) * 128;
    const int wave = tid >> 6, lane = tid & 63;
    const int wr   = (wave >> 1) * 64;
    const int wc   = (wave & 1) * 64;
    const int lr   = lane & 15;
    const int kh   = lane >> 4;

    const int lrow = lane >> 2;
    const int lkc  = (lane & 3) * 8;
    const ushort* gA0 = A + (long)(rb + wave * 32 + lrow) * K + lkc;
    const ushort* gA1 = A + (long)(rb + wave * 32 + 16 + lrow) * K + lkc;
    const ushort* gB0 = Bt + (long)(cb + wave * 32 + lrow) * K + lkc;
    const ushort* gB1 = Bt + (long)(cb + wave * 32 + 16 + lrow) * K + lkc;
    ushort* lA0 = As + wave * 1024;
    ushort* lA1 = As + wave * 1024 + 512;
    ushort* lB0 = Bs + wave * 1024;
    ushort* lB1 = Bs + wave * 1024 + 512;

    int aoff[4], boff[4];
#pragma unroll
    for (int m = 0; m < 4; ++m) aoff[m] = (wr + m * 16 + lr) * 32 + kh * 8;
#pragma unroll
    for (int n = 0; n < 4; ++n) boff[n] = (wc + n * 16 + lr) * 32 + kh * 8;

    f32x4 acc[4][4];
#pragma unroll
    for (int m = 0; m < 4; ++m)
#pragma unroll
        for (int n = 0; n < 4; ++n)
            acc[m][n] = (f32x4){0.f, 0.f, 0.f, 0.f};

    for (int k0 = 0; k0 < K; k0 += 32) {
        __syncthreads();
        gload16(gA0 + k0, lA0);
        gload16(gA1 + k0, lA1);
        gload16(gB0 + k0, lB0);
        gload16(gB1 + k0, lB1);
        __syncthreads();
        b16x8 af[4], bfr[4];
#pragma unroll
        for (int m = 0; m < 4; ++m) af[m] = *(const b16x8*)(As + aoff[m]);
#pragma unroll
        for (int n = 0; n < 4; ++n) bfr[n] = *(const b16x8*)(Bs + boff[n]);
#pragma unroll
        for (int m = 0; m < 4; ++m)
#pragma unroll
            for (int n = 0; n < 4; ++n)
                acc[m][n] = __builtin_amdgcn_mfma_f32_16x16x32_bf16(af[m], bfr[n], acc[m][n], 0, 0, 0);
    }

#pragma unroll
    for (int m = 0; m < 4; ++m) {
        int row0 = rb + wr + m * 16 + kh * 4;
#pragma unroll
        for (int n = 0; n < 4; ++n) {
            int col = cb + wc + n * 16 + lr;
#pragma unroll
            for (int r = 0; r < 4; ++r)
                Cf[(long)(row0 + r) * N + col] = acc[m][n][r];
        }
    }
}

// ---------------------------------------------------------------------------
// out = res[r'] + LN(t + t2 + t3 + t4)*scale + bias (t2..t4 optional);
// outputs f32 / fp16-split / bf16 mirrors.
// ---------------------------------------------------------------------------
__global__ __launch_bounds__(256) void ln_res_kernel(
    const float* __restrict__ t, const float* __restrict__ t2,
    const float* __restrict__ t3, const float* __restrict__ t4,
    const float* __restrict__ res, float* __restrict__ out,
    ushort* __restrict__ outh, ushort* __restrict__ outl, ushort* __restrict__ outb,
    const float* __restrict__ bias, const float* __restrict__ scale, int res_map)
{
    int r = blockIdx.x;
    int tid = threadIdx.x;
    long rr = res_map ? (long)((r >> 9) * 1024 + 512 + (r & 511)) : (long)r;
    float4 v = ((const float4*)(t + (long)r * HID))[tid];
    if (t2) {
        float4 w = ((const float4*)(t2 + (long)r * HID))[tid];
        v.x += w.x; v.y += w.y; v.z += w.z; v.w += w.w;
    }
    if (t3) {
        float4 w = ((const float4*)(t3 + (long)r * HID))[tid];
        v.x += w.x; v.y += w.y; v.z += w.z; v.w += w.w;
    }
    if (t4) {
        float4 w = ((const float4*)(t4 + (long)r * HID))[tid];
        v.x += w.x; v.y += w.y; v.z += w.z; v.w += w.w;
    }
    __shared__ float red[4];
    float s = v.x + v.y + v.z + v.w;
    for (int off = 32; off > 0; off >>= 1) s += __shfl_xor(s, off);
    if ((tid & 63) == 0) red[tid >> 6] = s;
    __syncthreads();
    float mean = (red[0] + red[1] + red[2] + red[3]) * (1.f / HID);
    __syncthreads();
    float dx = v.x - mean, dy = v.y - mean, dz = v.z - mean, dw = v.w - mean;
    float qs = dx * dx + dy * dy + dz * dz + dw * dw;
    for (int off = 32; off > 0; off >>= 1) qs += __shfl_xor(qs, off);
    if ((tid & 63) == 0) red[tid >> 6] = qs;
    __syncthreads();
    float var = (red[0] + red[1] + red[2] + red[3]) * (1.f / HID);
    float rs = rsqrtf(var + 1e-6f);
    float4 rv = ((const float4*)(res + rr * HID))[tid];
    float4 sc4 = ((const float4*)scale)[tid];
    float4 b4  = ((const float4*)bias)[tid];
    float4 o4;
    o4.x = rv.x + dx * rs * sc4.x + b4.x;
    o4.y = rv.y + dy * rs * sc4.y + b4.y;
    o4.z = rv.z + dz * rs * sc4.z + b4.z;
    o4.w = rv.w + dw * rs * sc4.w + b4.w;
    ((float4*)(out + (long)r * HID))[tid] = o4;
    if (outh) {
        ushort4 uh, ul;
        split16(o4.x, uh.x, ul.x); split16(o4.y, uh.y, ul.y);
        split16(o4.z, uh.z, ul.z); split16(o4.w, uh.w, ul.w);
        ((ushort4*)(outh + (long)r * HID))[tid] = uh;
        ((ushort4*)(outl + (long)r * HID))[tid] = ul;
    }
    if (outb) {
        ushort4 u; u.x = f2b(o4.x); u.y = f2b(o4.y); u.z = f2b(o4.z); u.w = f2b(o4.w);
        ((ushort4*)(outb + (long)r * HID))[tid] = u;
    }
}

// ---------------------------------------------------------------------------
// Workspace (168 MiB, proven safe). New overlays for z=4 split-K:
//   t0c = vt_hi region, t0d = vt_lo region (dead when C-proj/FF2 write them)
//   qc  = xs region, qd = xs_hi+xs_lo region (dead during Q-proj..fattn)
// ---------------------------------------------------------------------------
extern "C" void kernel_launch(void* const* d_in, const int* in_sizes, int n_in,
                              void* d_out, int out_size, void* d_ws, size_t ws_size,
                              hipStream_t stream)
{
    const int*   x_input = (const int*)  d_in[0];
    const float* prev    = (const float*)d_in[1];
    const float* Wemb    = (const float*)d_in[2];
    const float* Wlin    = (const float*)d_in[3];
    const float* pdec    = (const float*)d_in[4];
    const float* pq      = (const float*)d_in[5];
    const float* pk      = (const float*)d_in[6];
    const float* pv      = (const float*)d_in[7];
    const float* pc      = (const float*)d_in[8];
    const float* pf1     = (const float*)d_in[9];
    const float* pf2     = (const float*)d_in[10];
    const float* bf1     = (const float*)d_in[11];
    const float* bf2     = (const float*)d_in[12];
    const float* b1      = (const float*)d_in[13];
    const float* b2      = (const float*)d_in[14];
    const float* s1      = (const float*)d_in[15];
    const float* s2      = (const float*)d_in[16];
    const float* pos     = (const float*)d_in[17];

    float* outp   = (float*)d_out;
    float* logits = outp;
    float* dec    = outp + (long)2048 * VOC;

    char* base = (char*)d_ws;
    float*  x_f   = (float*) (base + 0);
    ushort* x_hi  = (ushort*)(base + 16777216);
    ushort* x_lo  = (ushort*)(base + 25165824);
    ushort* kv_hi = (ushort*)(base + 33554432);
    ushort* kv_lo = (ushort*)(base + 50331648);
    ushort* vt_hi = (ushort*)(base + 67108864);
    ushort* vt_lo = (ushort*)(base + 75497472);
    ushort* o_hi  = (ushort*)(base + 83886080);
    ushort* o_lo  = (ushort*)(base + 88080384);
    float*  t0a   = (float*) (base + 92274688);
    float*  h0    = t0a;
    float*  qa    = t0a;
    float*  t0b   = (float*) (base + 100663296);
    float*  qb    = t0b;
    float*  xs    = (float*) (base + 109051904);
    ushort* xs_hi = (ushort*)(base + 117440512);
    ushort* xs_lo = (ushort*)(base + 121634816);
    ushort* wq_hi = (ushort*)(base + 125829120);
    ushort* wq_lo = (ushort*)(base + 127926272);
    ushort* wkv_hi= (ushort*)(base + 130023424);
    ushort* wkv_lo= (ushort*)(base + 134217728);
    ushort* wc_hi = (ushort*)(base + 138412032);
    ushort* wc_lo = (ushort*)(base + 140509184);
    ushort* wf1_hi= (ushort*)(base + 142606336);
    ushort* wf1_lo= (ushort*)(base + 150994944);
    ushort* wf2_hi= (ushort*)(base + 159383552);
    ushort* wf2_lo= (ushort*)(base + 167772160);   // ends 176,160,768
    // overlays
    float*  t0c   = (float*) (base + 67108864);    // vt_hi region (post-fattn)
    float*  t0d   = (float*) (base + 75497472);    // vt_lo region (post-fattn)
    float*  qc    = (float*) (base + 109051904);   // xs region (pre-ln1)
    float*  qd    = (float*) (base + 117440512);   // xs_hi+xs_lo region (pre-ln1)
    ushort* ff1_hi= (ushort*)(base + 33554432);
    ushort* ff1_lo= (ushort*)(base + 50331648);
    ushort* decb  = (ushort*)(base + 83886080);
    ushort* wdect = (ushort*)(base + 0);

    embed_kernel<<<NB * WINN, 256, 0, stream>>>(x_input, Wemb, Wlin, h0);

    for (int l = 0; l < NL; ++l) {
        const float* cur = (l == 0) ? h0 : (dec + (long)(l - 1) * 2097152);
        build_x_kernel<<<(NB * TT * HID / 4) / 256, 256, 0, stream>>>(
            pos + (long)l * TT * HID, prev + (long)l * NB * WINN * HID, cur,
            x_f, x_hi, x_lo);

        wsplit4_kernel<<<dim3(32, 32, 4), 256, 0, stream>>>(
            pq + (long)l * HID * HID, pk + (long)l * HID * HID,
            pv + (long)l * HID * HID, pc + (long)l * HID * HID,
            wq_hi, wq_lo, wkv_hi, wkv_lo, wc_hi, wc_lo);
        wsplit_kernel<<<dim3(FFW / 32, HID / 32), 256, 0, stream>>>(
            pf1 + (long)l * HID * FFW, wf1_hi, wf1_lo, HID, FFW);
        wsplit_kernel<<<dim3(HID / 32, FFW / 32), 256, 0, stream>>>(
            pf2 + (long)l * FFW * HID, wf2_hi, wf2_lo, FFW, HID);

        // Fused K+V projection
        hgemm8<<<dim3(2048 / 128, (NB * TT) / 128, 1), 512, 0, stream>>>(
            x_hi, x_lo, wkv_hi, wkv_lo, kv_hi, kv_lo,
            nullptr, nullptr, nullptr, nullptr,
            NB * TT, 2048, HID, HID, 1.f, nullptr, 0, 0);
        // Q projection: split-K4 -> qa..qd (f32)
        hgemm8<<<dim3(HID / 128, (NB * WINN) / 128, 4), 512, 0, stream>>>(
            x_hi, x_lo, wq_hi, wq_lo, nullptr, nullptr, qa, qb, qc, qd,
            NB * WINN, HID, HID, 256, 0.125f, nullptr, 0, 1);
        vtrans_kernel<<<dim3(HID / 32, (NB * TT) / 32), 256, 0, stream>>>(
            kv_hi + 1024, kv_lo + 1024, vt_hi, vt_lo, 2048);

        fattn_mfma<<<dim3(WINN / 64, NH, NB), 256, 0, stream>>>(
            qa, qb, qc, qd, kv_hi, kv_lo, 2048, vt_hi, vt_lo, o_hi, o_lo);

        // C-proj: split-K4 -> t0a..t0d
        hgemm8<<<dim3(HID / 128, (NB * WINN) / 128, 4), 512, 0, stream>>>(
            o_hi, o_lo, wc_hi, wc_lo, nullptr, nullptr, t0a, t0b, t0c, t0d,
            NB * WINN, HID, HID, 256, 1.f, nullptr, 0, 0);
        ln_res_kernel<<<NB * WINN, 256, 0, stream>>>(
            t0a, t0b, t0c, t0d, x_f, xs, xs_hi, xs_lo, nullptr,
            b1 + l * HID, s1 + l * HID, 1);

        hgemm8<<<dim3(FFW / 128, (NB * WINN) / 128, 1), 512, 0, stream>>>(
            xs_hi, xs_lo, wf1_hi, wf1_lo, ff1_hi, ff1_lo,
            nullptr, nullptr, nullptr, nullptr,
            NB * WINN, FFW, HID, HID, 1.f, bf1 + l * FFW, 1, 0);
        // FF2: split-K4 -> t0a..t0d
        hgemm8<<<dim3(HID / 128, (NB * WINN) / 128, 4), 512, 0, stream>>>(
            ff1_hi, ff1_lo, wf2_hi, wf2_lo, nullptr, nullptr, t0a, t0b, t0c, t0d,
            NB * WINN, HID, FFW, 1024, 1.f, bf2 + l * HID, 0, 0);
        ln_res_kernel<<<NB * WINN, 256, 0, stream>>>(
            t0a, t0b, t0c, t0d, xs, dec + (long)l * 2097152, nullptr, nullptr,
            (l == NL - 1) ? decb : nullptr, b2 + l * HID, s2 + l * HID, 0);
    }

    transp_kernel<<<dim3(VOC / 32, HID / 32), 256, 0, stream>>>(pdec, wdect, HID, VOC);
    mfma_gemm<<<dim3(VOC / 128, (NB * WINN) / 128), 256, 0, stream>>>(
        decb, wdect, logits, NB * WINN, VOC, HID);
}